// Round 11
// baseline (180.467 us; speedup 1.0000x reference)
//
#include <hip/hip_runtime.h>
#include <hip/hip_bf16.h>
#include <cstdint>

typedef __attribute__((ext_vector_type(8))) short short8;
typedef __attribute__((ext_vector_type(4))) float f32x4;
typedef __attribute__((ext_vector_type(16))) float f32x16;
typedef __attribute__((ext_vector_type(4))) unsigned uint4v;

#define DEV static __device__ __forceinline__

DEV f32x4 mfma16(short8 a, short8 b, f32x4 c) {
    return __builtin_amdgcn_mfma_f32_16x16x32_bf16(a, b, c, 0, 0, 0);
}
DEV f32x16 mfma32(short8 a, short8 b, f32x16 c) {
    return __builtin_amdgcn_mfma_f32_32x32x16_bf16(a, b, c, 0, 0, 0);
}

DEV unsigned short f2bf(float f) {
    __hip_bfloat16 h = __float2bfloat16(f);
    return __builtin_bit_cast(unsigned short, h);
}

// pack two f32 -> two bf16 in a u32 (lo = first arg), RNE
DEV unsigned cvtpk(float lo, float hi) {
    unsigned r;
    asm("v_cvt_pk_bf16_f32 %0, %1, %2" : "=v"(r) : "v"(lo), "v"(hi));
    return r;
}
// vdst_hi <-> vsrc_lo swap: after, a = {a_lo, b_lo}, b = {a_hi, b_hi}
DEV void plswap(unsigned& a, unsigned& b) {
    asm volatile("v_permlane32_swap_b32 %0, %1" : "+v"(a), "+v"(b));
}

// global -> LDS direct load, 16B per lane. Dest: wave-uniform base + lane*16.
#define GLOAD16(gp, lp)                                                        \
    __builtin_amdgcn_global_load_lds(                                          \
        (const __attribute__((address_space(1))) unsigned int*)(uintptr_t)(gp),\
        (__attribute__((address_space(3))) unsigned int*)(uintptr_t)(lp),      \
        16, 0, 0)

// ---------------- prep kernels ----------------

__global__ void pe_kernel(float* __restrict__ pe) {
    int i = threadIdx.x;
    if (i >= 512) return;
    float div = expf((float)(2 * i) * (-9.210340371976184f / 1024.0f));
    pe[2 * i]          = 0.0f;      // sin(0*div)
    pe[2 * i + 1]      = 1.0f;      // cos(0*div)
    pe[1024 + 2 * i]     = sinf(div);
    pe[1024 + 2 * i + 1] = cosf(div);
}

// fused f32->bf16 conversion of x, qkv_w, fc_w (one launch). 2097152 float4s total.
__global__ void cvt3(const float* __restrict__ x, const float* __restrict__ wq,
                     const float* __restrict__ wf, unsigned short* __restrict__ xb,
                     unsigned short* __restrict__ wqb, unsigned short* __restrict__ wfb) {
    int i = blockIdx.x * blockDim.x + threadIdx.x;   // 0..2097151
    const float* src; unsigned short* dst; int off;
    if (i < 1048576)      { src = x;  dst = xb;  off = i; }
    else if (i < 1835008) { src = wq; dst = wqb; off = i - 1048576; }
    else                  { src = wf; dst = wfb; off = i - 1835008; }
    float4 v = ((const float4*)src)[off];
    ushort4 o;
    o.x = f2bf(v.x); o.y = f2bf(v.y); o.z = f2bf(v.z); o.w = f2bf(v.w);
    ((ushort4*)dst)[off] = o;
}

// mask [2048,2048] int32 (0/1) -> TRANSPOSED bit-words wT[kb][row] (kb 0..63, row 0..2047)
__global__ void pack_mask(const int* __restrict__ mask, unsigned int* __restrict__ wT) {
    int o = blockIdx.x * blockDim.x + threadIdx.x;   // 0..131071
    int kb = o >> 11, row = o & 2047;
    const int4* m4 = (const int4*)(mask + (size_t)row * 2048 + kb * 32);
    unsigned int bits = 0;
#pragma unroll
    for (int j = 0; j < 8; j++) {
        int4 v = m4[j];
        bits |= (unsigned)(v.x & 1) << (4 * j);
        bits |= (unsigned)(v.y & 1) << (4 * j + 1);
        bits |= (unsigned)(v.z & 1) << (4 * j + 2);
        bits |= (unsigned)(v.w & 1) << (4 * j + 3);
    }
    wT[o] = bits;
}

// ------- GEMM mainloop: 128x128 tile, BK=32, double-buffered LDS, swizzled reads -------
// (R9-proven.) Pre-swizzled SOURCE chunk + linear LDS dest; reads XOR the chunk slot.
// One barrier per K-step; STAGE(next) gets a full iteration of ds_read+MFMA to land.
DEV void gemm_mainloop(const unsigned short* __restrict__ A,
                       const unsigned short* __restrict__ Bm,
                       int m0, int n0, f32x4 (&acc)[4][4],
                       unsigned short* As, unsigned short* Bs) {   // each [2*4096]
    const int t = threadIdx.x;
    const int w = t >> 6;
    const int l = t & 63, lr = l & 15, lg = l >> 4;
    const int wr = w >> 1, wc = w & 1;
    const int srow = t >> 2;
    const int scg = ((t & 3) ^ ((t >> 3) & 3)) * 8;   // pre-swizzled source chunk
#pragma unroll
    for (int i = 0; i < 4; i++)
#pragma unroll
        for (int j = 0; j < 4; j++) acc[i][j] = f32x4{0.f, 0.f, 0.f, 0.f};

    const unsigned short* Ap = A + (size_t)(m0 + srow) * 1024 + scg;
    const unsigned short* Bp = Bm + (size_t)(n0 + srow) * 1024 + scg;
    unsigned short* dA = As + w * 512;
    unsigned short* dB = Bs + w * 512;

    // swizzled read bases (loop-invariant): slot = lg ^ ((lr>>1)&3)
    const int slot = (lg ^ ((lr >> 1) & 3)) * 8;
    const unsigned short* Ar = As + (wr * 64 + lr) * 32 + slot;
    const unsigned short* Br = Bs + (wc * 64 + lr) * 32 + slot;

#define STAGE(buf, k0)                                                \
    {                                                                 \
        GLOAD16(Ap + (k0), dA + (buf) * 4096);                        \
        GLOAD16(Ap + 64 * 1024 + (k0), dA + (buf) * 4096 + 2048);     \
        GLOAD16(Bp + (k0), dB + (buf) * 4096);                        \
        GLOAD16(Bp + 64 * 1024 + (k0), dB + (buf) * 4096 + 2048);     \
    }

    STAGE(0, 0);
#pragma unroll 2
    for (int k0 = 0; k0 < 1024; k0 += 32) {
        const int cur = (k0 >> 5) & 1;
        __syncthreads();                      // drains vmcnt: buf[cur] ready; prev reads done
        if (k0 + 32 < 1024) STAGE(cur ^ 1, k0 + 32);
        short8 af[4], bfr[4];
#pragma unroll
        for (int i = 0; i < 4; i++)
            af[i] = *(const short8*)(Ar + cur * 4096 + i * 512);
#pragma unroll
        for (int j = 0; j < 4; j++)
            bfr[j] = *(const short8*)(Br + cur * 4096 + j * 512);
#pragma unroll
        for (int i = 0; i < 4; i++)
#pragma unroll
            for (int j = 0; j < 4; j++)
                acc[i][j] = mfma16(af[i], bfr[j], acc[i][j]);
    }
#undef STAGE
}

// qkv GEMM: epilogue +bias, +pe (q,k), q *= 1/8*log2e; scatter into FRAGMENT-MAJOR
// layouts so the attn kernel's loads are lane-coalesced (addr = base + lane*16B).
__global__ __launch_bounds__(256) void qkv_gemm(
    const unsigned short* __restrict__ x, const unsigned short* __restrict__ wq,
    const float* __restrict__ bias, const float* __restrict__ pe,
    unsigned short* __restrict__ qo, unsigned short* __restrict__ ko,
    unsigned short* __restrict__ vt) {
    __shared__ unsigned short As[2 * 4096], Bs[2 * 4096];
    const int m0 = blockIdx.y * 128, n0 = blockIdx.x * 128;
    f32x4 acc[4][4];
    gemm_mainloop(x, wq, m0, n0, acc, As, Bs);

    const int t = threadIdx.x, w = t >> 6, l = t & 63;
    const int wr = w >> 1, wc = w & 1, lr = l & 15, lg = l >> 4;
#pragma unroll
    for (int i = 0; i < 4; i++) {
#pragma unroll
        for (int j = 0; j < 4; j++) {
            const int n = n0 + wc * 64 + j * 16 + lr;
            const int part = n >> 10, d = n & 1023, h = d >> 6, hd = d & 63;
            const float bia = bias[n];
#pragma unroll
            for (int r = 0; r < 4; r++) {
                const int m = m0 + wr * 64 + i * 16 + lg * 4 + r;
                const int b = m >> 11, s = m & 2047;
                const int bh = b * 16 + h;
                float v = acc[i][j][r] + bia;
                if (part == 2) {
                    const size_t off = (size_t)bh * 131072 + (s >> 5) * 2048 +
                                       (hd >> 5) * 1024 + ((s >> 4) & 1) * 512 +
                                       (((s >> 3) & 1) * 32 + (hd & 31)) * 8 + (s & 7);
                    vt[off] = f2bf(v);
                } else {
                    const size_t off = (size_t)bh * 131072 + (s >> 5) * 2048 +
                                       (hd >> 4) * 512 +
                                       (((hd >> 3) & 1) * 32 + (s & 31)) * 8 + (hd & 7);
                    if (part == 0) {
                        v = (v + pe[b * 1024 + d]) * 0.1803368801111204f; // 1/8 * log2(e)
                        qo[off] = f2bf(v);
                    } else {
                        v += pe[b * 1024 + d];
                        ko[off] = f2bf(v);
                    }
                }
            }
        }
    }
}

// fc GEMM: M=4096, N=1024, out f32 += fc_b
__global__ __launch_bounds__(256) void fc_gemm(
    const unsigned short* __restrict__ a, const unsigned short* __restrict__ wf,
    const float* __restrict__ bias, float* __restrict__ out) {
    __shared__ unsigned short As[2 * 4096], Bs[2 * 4096];
    const int m0 = blockIdx.y * 128, n0 = blockIdx.x * 128;
    f32x4 acc[4][4];
    gemm_mainloop(a, wf, m0, n0, acc, As, Bs);

    const int t = threadIdx.x, w = t >> 6, l = t & 63;
    const int wr = w >> 1, wc = w & 1, lr = l & 15, lg = l >> 4;
#pragma unroll
    for (int i = 0; i < 4; i++) {
#pragma unroll
        for (int j = 0; j < 4; j++) {
            const int n = n0 + wc * 64 + j * 16 + lr;
            const float bia = bias[n];
#pragma unroll
            for (int r = 0; r < 4; r++) {
                const int m = m0 + wr * 64 + i * 16 + lg * 4 + r;
                out[(size_t)m * 1024 + n] = acc[i][j][r] + bia;
            }
        }
    }
}

// ---------- split-K flash attention: 2 q-tiles/wave, no-max softmax, f32 row-sums ------
// Each wave processes q-tiles qbA and qbB = qbA+32 against the SAME K/V chunk stream:
// halves K/V+mask loads per unit compute and gives two independent dep chains.
// p = exp2(s) on scores (bounded; masked -> -1e9 -> 0). Row-sums: in-lane f32 tree +
// shfl_xor(32) (R1-R5-proven). C-init via opaque FZ. SPLIT=2. Grid 512 x 256thr.
// ALL global loads are addr = fragbase + lane*16B (fragment-major, R6).
// Lane (c = l&31, hi = l>>5). S^T = mfma(K,Q): col c = q; key = (reg&3)+8*(reg>>2)+4*hi.
// Emits UNNORMALIZED partial O~^T (f32, [64 d][32 q]) + per-q sum l, per tile.
// XCD swizzle: bid&7 = xcd; 4 (b,h) pairs per xcd -> K/V L2-resident.
__global__ __launch_bounds__(256) void attn(
    const unsigned short* __restrict__ q, const unsigned short* __restrict__ k,
    const unsigned short* __restrict__ vt, const unsigned int* __restrict__ mw,
    float* __restrict__ po, float* __restrict__ ms) {
    const int t = threadIdx.x, w = t >> 6;
    const int l = t & 63, c = l & 31, hi = l >> 5;
    const int bid = blockIdx.x;
    const int xcd = bid & 7, idx = bid >> 3;        // idx 0..63
    const int bh = xcd * 4 + (idx & 3);
    const int rest = idx >> 2;                      // 0..15
    const int chunk = rest & 1, qg = rest >> 1;     // chunk 0..1, qgroup 0..7
    const int qbA = qg * 4 + w;                     // 0..31
    const int qbB = qbA + 32;                       // 32..63
    const int kb0 = chunk * 32;

    // fragment-major bases; every load below is  ptr + lane*8 shorts (16B)
    const unsigned short* qfbA = q + (size_t)bh * 131072 + qbA * 2048 + l * 8;
    const unsigned short* kfb  = k + (size_t)bh * 131072 + l * 8;
    const unsigned short* vfb  = vt + (size_t)bh * 131072 + l * 8;

    short8 qfA[4], qfB[4];
#pragma unroll
    for (int d = 0; d < 4; d++) {
        qfA[d] = *(const short8*)(qfbA + d * 512);
        qfB[d] = *(const short8*)(qfbA + 65536 + d * 512);   // qbB = qbA+32 -> +32*2048
    }

    // opaque zero C operand (loop-invariant; blocks per-iter zero re-materialization)
    float z = 0.f;
    asm volatile("" : "+v"(z));
    f32x16 FZ;
#pragma unroll
    for (int i = 0; i < 16; i++) FZ[i] = z;

    // preload first tile of this chunk
    short8 kf[4], vf[2][2];
#pragma unroll
    for (int d = 0; d < 4; d++) kf[d] = *(const short8*)(kfb + kb0 * 2048 + d * 512);
#pragma unroll
    for (int kc = 0; kc < 2; kc++) {
        vf[0][kc] = *(const short8*)(vfb + kb0 * 2048 + kc * 512);
        vf[1][kc] = *(const short8*)(vfb + kb0 * 2048 + 1024 + kc * 512);
    }
    unsigned wdA = mw[kb0 * 2048 + qbA * 32 + c];
    unsigned wdB = mw[kb0 * 2048 + qbB * 32 + c];

    f32x16 OA0, OA1, OB0, OB1;
#pragma unroll
    for (int i = 0; i < 16; i++) { OA0[i] = 0.f; OA1[i] = 0.f; OB0[i] = 0.f; OB1[i] = 0.f; }
    float lA = 0.f, lB = 0.f;

#pragma unroll 2
    for (int kb = kb0; kb < kb0 + 32; kb++) {
        // QK^T for tile A (K in regs); C = opaque zero
        f32x16 SA = mfma32(kf[0], qfA[0], FZ);
#pragma unroll
        for (int d = 1; d < 4; d++) SA = mfma32(kf[d], qfA[d], SA);

        // prefetch tile kb+1 (tail prefetch reads adjacent ws buffers: safe, unused)
        short8 kn[4], vn[2][2];
        const unsigned short* kpn = kfb + (kb + 1) * 2048;
        const unsigned short* vpn = vfb + (kb + 1) * 2048;
#pragma unroll
        for (int d = 0; d < 4; d++) kn[d] = *(const short8*)(kpn + d * 512);
#pragma unroll
        for (int kc = 0; kc < 2; kc++) {
            vn[0][kc] = *(const short8*)(vpn + kc * 512);
            vn[1][kc] = *(const short8*)(vpn + 1024 + kc * 512);
        }
        const unsigned wnA = mw[(kb + 1) * 2048 + qbA * 32 + c];
        const unsigned wnB = mw[(kb + 1) * 2048 + qbB * 32 + c];

        // softmax A: mask -> -1e9, p = exp2, f32 row-sum
        {
            const unsigned wds = wdA >> (4 * hi);
            float p[16];
#pragma unroll
            for (int g = 0; g < 4; g++)
#pragma unroll
                for (int u = 0; u < 4; u++)
                    p[g * 4 + u] = (wds & (1u << (8 * g + u))) ? -1e9f : SA[g * 4 + u];
#pragma unroll
            for (int i = 0; i < 16; i++) p[i] = exp2f(p[i]);
            float rs = (((p[0] + p[1]) + (p[2] + p[3])) + ((p[4] + p[5]) + (p[6] + p[7]))) +
                       (((p[8] + p[9]) + (p[10] + p[11])) + ((p[12] + p[13]) + (p[14] + p[15])));
            rs += __shfl_xor(rs, 32);
            lA += rs;
            unsigned w8[8];
#pragma unroll
            for (int g = 0; g < 4; g++) {
                w8[2 * g]     = cvtpk(p[4 * g], p[4 * g + 1]);
                w8[2 * g + 1] = cvtpk(p[4 * g + 2], p[4 * g + 3]);
            }
            short8 pa[2];
#pragma unroll
            for (int kc = 0; kc < 2; kc++) {
                unsigned a0 = w8[4 * kc], a2 = w8[4 * kc + 2];
                plswap(a0, a2);
                unsigned a1 = w8[4 * kc + 1], a3 = w8[4 * kc + 3];
                plswap(a1, a3);
                uint4v tv; tv[0] = a0; tv[1] = a1; tv[2] = a2; tv[3] = a3;
                pa[kc] = __builtin_bit_cast(short8, tv);
            }
            OA0 = mfma32(vf[0][0], pa[0], OA0);
            OA0 = mfma32(vf[0][1], pa[1], OA0);
            OA1 = mfma32(vf[1][0], pa[0], OA1);
            OA1 = mfma32(vf[1][1], pa[1], OA1);
        }

        // QK^T for tile B
        f32x16 SB = mfma32(kf[0], qfB[0], FZ);
#pragma unroll
        for (int d = 1; d < 4; d++) SB = mfma32(kf[d], qfB[d], SB);

        // softmax B
        {
            const unsigned wds = wdB >> (4 * hi);
            float p[16];
#pragma unroll
            for (int g = 0; g < 4; g++)
#pragma unroll
                for (int u = 0; u < 4; u++)
                    p[g * 4 + u] = (wds & (1u << (8 * g + u))) ? -1e9f : SB[g * 4 + u];
#pragma unroll
            for (int i = 0; i < 16; i++) p[i] = exp2f(p[i]);
            float rs = (((p[0] + p[1]) + (p[2] + p[3])) + ((p[4] + p[5]) + (p[6] + p[7]))) +
                       (((p[8] + p[9]) + (p[10] + p[11])) + ((p[12] + p[13]) + (p[14] + p[15])));
            rs += __shfl_xor(rs, 32);
            lB += rs;
            unsigned w8[8];
#pragma unroll
            for (int g = 0; g < 4; g++) {
                w8[2 * g]     = cvtpk(p[4 * g], p[4 * g + 1]);
                w8[2 * g + 1] = cvtpk(p[4 * g + 2], p[4 * g + 3]);
            }
            short8 pa[2];
#pragma unroll
            for (int kc = 0; kc < 2; kc++) {
                unsigned a0 = w8[4 * kc], a2 = w8[4 * kc + 2];
                plswap(a0, a2);
                unsigned a1 = w8[4 * kc + 1], a3 = w8[4 * kc + 3];
                plswap(a1, a3);
                uint4v tv; tv[0] = a0; tv[1] = a1; tv[2] = a2; tv[3] = a3;
                pa[kc] = __builtin_bit_cast(short8, tv);
            }
            OB0 = mfma32(vf[0][0], pa[0], OB0);
            OB0 = mfma32(vf[0][1], pa[1], OB0);
            OB1 = mfma32(vf[1][0], pa[0], OB1);
            OB1 = mfma32(vf[1][1], pa[1], OB1);
        }

#pragma unroll
        for (int d = 0; d < 4; d++) kf[d] = kn[d];
#pragma unroll
        for (int kc = 0; kc < 2; kc++) { vf[0][kc] = vn[0][kc]; vf[1][kc] = vn[1][kc]; }
        wdA = wnA; wdB = wnB;
    }

    // emit partials for both tiles: per-q sum l and unnormalized O~^T [64][32]
    const int tileA = bh * 64 + qbA, tileB = bh * 64 + qbB;
    if (hi == 0) {
        ms[((size_t)tileA * 2 + chunk) * 32 + c] = lA;
        ms[((size_t)tileB * 2 + chunk) * 32 + c] = lB;
    }
    float* pbA = po + ((size_t)tileA * 2 + chunk) * 2048;   // [64 d][32 q]
    float* pbB = po + ((size_t)tileB * 2 + chunk) * 2048;
#pragma unroll
    for (int i = 0; i < 16; i++) {
        const int kr = (i & 3) + 8 * (i >> 2) + 4 * hi;
        pbA[kr * 32 + c]        = OA0[i];
        pbA[(32 + kr) * 32 + c] = OA1[i];
        pbB[kr * 32 + c]        = OB0[i];
        pbB[(32 + kr) * 32 + c] = OB1[i];
    }
}

// combine partials: 4 waves/block, one (bh,qb) tile per wave. lane: q=l>>1, dh=(l&1)*32.
// O = (O~0 + O~1) / (l0 + l1)  (no max weighting needed -- no-max softmax partials)
__global__ __launch_bounds__(256) void combine(
    const float* __restrict__ po, const float* __restrict__ ms,
    unsigned short* __restrict__ ao) {
    const int cid = blockIdx.x * 4 + (threadIdx.x >> 6);   // 0..2047 = bh*64 + qb
    const int bh = cid >> 6, qb = cid & 63;
    const int b = bh >> 4, h = bh & 15, q0 = qb * 32;
    const int l = threadIdx.x & 63, q = l >> 1, dh = (l & 1) * 32;

    const float L = ms[(size_t)cid * 64 + q] + ms[(size_t)cid * 64 + 32 + q];
    const float inv = 1.0f / L;

    const float* pb = po + (size_t)cid * 2 * 2048;   // [2][64][32]
    unsigned short* gout = ao + ((size_t)(b * 2048 + q0 + q)) * 1024 + h * 64 + dh;
#pragma unroll
    for (int ch = 0; ch < 4; ch++) {
        uint4v pk;
#pragma unroll
        for (int u = 0; u < 4; u++) {
            const int j0 = ch * 8 + 2 * u;
            float a0 = pb[(dh + j0) * 32 + q]     + pb[2048 + (dh + j0) * 32 + q];
            float a1 = pb[(dh + j0 + 1) * 32 + q] + pb[2048 + (dh + j0 + 1) * 32 + q];
            pk[u] = cvtpk(a0 * inv, a1 * inv);
        }
        *(uint4v*)(gout + ch * 8) = pk;
    }
}

// ---------------- launcher ----------------
extern "C" void kernel_launch(void* const* d_in, const int* in_sizes, int n_in,
                              void* d_out, int out_size, void* d_ws, size_t ws_size,
                              hipStream_t stream) {
    const float* x     = (const float*)d_in[0];
    const int*   mask  = (const int*)d_in[1];
    const float* qkv_w = (const float*)d_in[2];
    const float* qkv_b = (const float*)d_in[3];
    const float* fc_w  = (const float*)d_in[4];
    const float* fc_b  = (const float*)d_in[5];
    float* out = (float*)d_out;

    char* ws = (char*)d_ws;
    size_t off = 0;
    auto alloc = [&](size_t bytes) {
        off = (off + 255) & ~(size_t)255;
        void* p = ws + off;
        off += bytes;
        return p;
    };
    float*          pe     = (float*)alloc(2 * 1024 * 4);
    unsigned int*   mwords = (unsigned int*)alloc((size_t)2048 * 64 * 4);
    unsigned short* xb     = (unsigned short*)alloc((size_t)4096 * 1024 * 2);
    unsigned short* wqkv   = (unsigned short*)alloc((size_t)3072 * 1024 * 2);
    unsigned short* wfc    = (unsigned short*)alloc((size_t)1024 * 1024 * 2);
    unsigned short* qb16   = (unsigned short*)alloc((size_t)2 * 16 * 2048 * 64 * 2);
    unsigned short* kb16   = (unsigned short*)alloc((size_t)2 * 16 * 2048 * 64 * 2);
    unsigned short* vtb    = (unsigned short*)alloc((size_t)2 * 16 * 64 * 2048 * 2);
    unsigned short* attn_o = (unsigned short*)alloc((size_t)4096 * 1024 * 2);
    float*          po     = (float*)alloc((size_t)2048 * 2 * 2048 * 4);
    float*          msb    = (float*)alloc((size_t)2048 * 2 * 32 * 4);

    pe_kernel<<<1, 512, 0, stream>>>(pe);
    cvt3<<<8192, 256, 0, stream>>>(x, qkv_w, fc_w, xb, wqkv, wfc);
    pack_mask<<<512, 256, 0, stream>>>(mask, mwords);
    qkv_gemm<<<dim3(24, 32), 256, 0, stream>>>(xb, wqkv, qkv_b, pe, qb16, kb16, vtb);
    attn<<<dim3(512), 256, 0, stream>>>(qb16, kb16, vtb, mwords, po, msb);
    combine<<<dim3(512), 256, 0, stream>>>(po, msb, attn_o);
    fc_gemm<<<dim3(8, 32), 256, 0, stream>>>(attn_o, wfc, fc_b, out);
}

// Round 12
// 164.151 us; speedup vs baseline: 1.0994x; 1.0994x over previous
//
#include <hip/hip_runtime.h>
#include <hip/hip_bf16.h>
#include <cstdint>

typedef __attribute__((ext_vector_type(8))) short short8;
typedef __attribute__((ext_vector_type(4))) float f32x4;
typedef __attribute__((ext_vector_type(16))) float f32x16;
typedef __attribute__((ext_vector_type(4))) unsigned uint4v;

#define DEV static __device__ __forceinline__

DEV f32x4 mfma16(short8 a, short8 b, f32x4 c) {
    return __builtin_amdgcn_mfma_f32_16x16x32_bf16(a, b, c, 0, 0, 0);
}
DEV f32x16 mfma32(short8 a, short8 b, f32x16 c) {
    return __builtin_amdgcn_mfma_f32_32x32x16_bf16(a, b, c, 0, 0, 0);
}

DEV unsigned short f2bf(float f) {
    __hip_bfloat16 h = __float2bfloat16(f);
    return __builtin_bit_cast(unsigned short, h);
}

// pack two f32 -> two bf16 in a u32 (lo = first arg), RNE
DEV unsigned cvtpk(float lo, float hi) {
    unsigned r;
    asm("v_cvt_pk_bf16_f32 %0, %1, %2" : "=v"(r) : "v"(lo), "v"(hi));
    return r;
}
// vdst_hi <-> vsrc_lo swap: after, a = {a_lo, b_lo}, b = {a_hi, b_hi}
DEV void plswap(unsigned& a, unsigned& b) {
    asm volatile("v_permlane32_swap_b32 %0, %1" : "+v"(a), "+v"(b));
}

// global -> LDS direct load, 16B per lane. Dest: wave-uniform base + lane*16.
#define GLOAD16(gp, lp)                                                        \
    __builtin_amdgcn_global_load_lds(                                          \
        (const __attribute__((address_space(1))) unsigned int*)(uintptr_t)(gp),\
        (__attribute__((address_space(3))) unsigned int*)(uintptr_t)(lp),      \
        16, 0, 0)

// ---------------- prep kernels ----------------

__global__ void pe_kernel(float* __restrict__ pe) {
    int i = threadIdx.x;
    if (i >= 512) return;
    float div = expf((float)(2 * i) * (-9.210340371976184f / 1024.0f));
    pe[2 * i]          = 0.0f;      // sin(0*div)
    pe[2 * i + 1]      = 1.0f;      // cos(0*div)
    pe[1024 + 2 * i]     = sinf(div);
    pe[1024 + 2 * i + 1] = cosf(div);
}

// fused f32->bf16 conversion of x, qkv_w, fc_w (one launch). 2097152 float4s total.
__global__ void cvt3(const float* __restrict__ x, const float* __restrict__ wq,
                     const float* __restrict__ wf, unsigned short* __restrict__ xb,
                     unsigned short* __restrict__ wqb, unsigned short* __restrict__ wfb) {
    int i = blockIdx.x * blockDim.x + threadIdx.x;   // 0..2097151
    const float* src; unsigned short* dst; int off;
    if (i < 1048576)      { src = x;  dst = xb;  off = i; }
    else if (i < 1835008) { src = wq; dst = wqb; off = i - 1048576; }
    else                  { src = wf; dst = wfb; off = i - 1835008; }
    float4 v = ((const float4*)src)[off];
    ushort4 o;
    o.x = f2bf(v.x); o.y = f2bf(v.y); o.z = f2bf(v.z); o.w = f2bf(v.w);
    ((ushort4*)dst)[off] = o;
}

// mask [2048,2048] int32 (0/1) -> TRANSPOSED bit-words wT[kb][row] (kb 0..63, row 0..2047)
__global__ void pack_mask(const int* __restrict__ mask, unsigned int* __restrict__ wT) {
    int o = blockIdx.x * blockDim.x + threadIdx.x;   // 0..131071
    int kb = o >> 11, row = o & 2047;
    const int4* m4 = (const int4*)(mask + (size_t)row * 2048 + kb * 32);
    unsigned int bits = 0;
#pragma unroll
    for (int j = 0; j < 8; j++) {
        int4 v = m4[j];
        bits |= (unsigned)(v.x & 1) << (4 * j);
        bits |= (unsigned)(v.y & 1) << (4 * j + 1);
        bits |= (unsigned)(v.z & 1) << (4 * j + 2);
        bits |= (unsigned)(v.w & 1) << (4 * j + 3);
    }
    wT[o] = bits;
}

// ------- GEMM mainloop: 128x128 tile, BK=32, double-buffered LDS, swizzled reads -------
// (R9-proven.) Pre-swizzled SOURCE chunk + linear LDS dest; reads XOR the chunk slot.
// One barrier per K-step; STAGE(next) gets a full iteration of ds_read+MFMA to land.
DEV void gemm_mainloop(const unsigned short* __restrict__ A,
                       const unsigned short* __restrict__ Bm,
                       int m0, int n0, f32x4 (&acc)[4][4],
                       unsigned short* As, unsigned short* Bs) {   // each [2*4096]
    const int t = threadIdx.x;
    const int w = t >> 6;
    const int l = t & 63, lr = l & 15, lg = l >> 4;
    const int wr = w >> 1, wc = w & 1;
    const int srow = t >> 2;
    const int scg = ((t & 3) ^ ((t >> 3) & 3)) * 8;   // pre-swizzled source chunk
#pragma unroll
    for (int i = 0; i < 4; i++)
#pragma unroll
        for (int j = 0; j < 4; j++) acc[i][j] = f32x4{0.f, 0.f, 0.f, 0.f};

    const unsigned short* Ap = A + (size_t)(m0 + srow) * 1024 + scg;
    const unsigned short* Bp = Bm + (size_t)(n0 + srow) * 1024 + scg;
    unsigned short* dA = As + w * 512;
    unsigned short* dB = Bs + w * 512;

    // swizzled read bases (loop-invariant): slot = lg ^ ((lr>>1)&3)
    const int slot = (lg ^ ((lr >> 1) & 3)) * 8;
    const unsigned short* Ar = As + (wr * 64 + lr) * 32 + slot;
    const unsigned short* Br = Bs + (wc * 64 + lr) * 32 + slot;

#define STAGE(buf, k0)                                                \
    {                                                                 \
        GLOAD16(Ap + (k0), dA + (buf) * 4096);                        \
        GLOAD16(Ap + 64 * 1024 + (k0), dA + (buf) * 4096 + 2048);     \
        GLOAD16(Bp + (k0), dB + (buf) * 4096);                        \
        GLOAD16(Bp + 64 * 1024 + (k0), dB + (buf) * 4096 + 2048);     \
    }

    STAGE(0, 0);
#pragma unroll 2
    for (int k0 = 0; k0 < 1024; k0 += 32) {
        const int cur = (k0 >> 5) & 1;
        __syncthreads();                      // drains vmcnt: buf[cur] ready; prev reads done
        if (k0 + 32 < 1024) STAGE(cur ^ 1, k0 + 32);
        short8 af[4], bfr[4];
#pragma unroll
        for (int i = 0; i < 4; i++)
            af[i] = *(const short8*)(Ar + cur * 4096 + i * 512);
#pragma unroll
        for (int j = 0; j < 4; j++)
            bfr[j] = *(const short8*)(Br + cur * 4096 + j * 512);
#pragma unroll
        for (int i = 0; i < 4; i++)
#pragma unroll
            for (int j = 0; j < 4; j++)
                acc[i][j] = mfma16(af[i], bfr[j], acc[i][j]);
    }
#undef STAGE
}

// qkv GEMM: epilogue +bias, +pe (q,k), q *= 1/8*log2e; scatter into FRAGMENT-MAJOR
// layouts so the attn kernel's loads are lane-coalesced (addr = base + lane*16B).
__global__ __launch_bounds__(256) void qkv_gemm(
    const unsigned short* __restrict__ x, const unsigned short* __restrict__ wq,
    const float* __restrict__ bias, const float* __restrict__ pe,
    unsigned short* __restrict__ qo, unsigned short* __restrict__ ko,
    unsigned short* __restrict__ vt) {
    __shared__ unsigned short As[2 * 4096], Bs[2 * 4096];
    const int m0 = blockIdx.y * 128, n0 = blockIdx.x * 128;
    f32x4 acc[4][4];
    gemm_mainloop(x, wq, m0, n0, acc, As, Bs);

    const int t = threadIdx.x, w = t >> 6, l = t & 63;
    const int wr = w >> 1, wc = w & 1, lr = l & 15, lg = l >> 4;
#pragma unroll
    for (int i = 0; i < 4; i++) {
#pragma unroll
        for (int j = 0; j < 4; j++) {
            const int n = n0 + wc * 64 + j * 16 + lr;
            const int part = n >> 10, d = n & 1023, h = d >> 6, hd = d & 63;
            const float bia = bias[n];
#pragma unroll
            for (int r = 0; r < 4; r++) {
                const int m = m0 + wr * 64 + i * 16 + lg * 4 + r;
                const int b = m >> 11, s = m & 2047;
                const int bh = b * 16 + h;
                float v = acc[i][j][r] + bia;
                if (part == 2) {
                    const size_t off = (size_t)bh * 131072 + (s >> 5) * 2048 +
                                       (hd >> 5) * 1024 + ((s >> 4) & 1) * 512 +
                                       (((s >> 3) & 1) * 32 + (hd & 31)) * 8 + (s & 7);
                    vt[off] = f2bf(v);
                } else {
                    const size_t off = (size_t)bh * 131072 + (s >> 5) * 2048 +
                                       (hd >> 4) * 512 +
                                       (((hd >> 3) & 1) * 32 + (s & 31)) * 8 + (hd & 7);
                    if (part == 0) {
                        v = (v + pe[b * 1024 + d]) * 0.1803368801111204f; // 1/8 * log2(e)
                        qo[off] = f2bf(v);
                    } else {
                        v += pe[b * 1024 + d];
                        ko[off] = f2bf(v);
                    }
                }
            }
        }
    }
}

// fc GEMM: M=4096, N=1024, out f32 += fc_b
__global__ __launch_bounds__(256) void fc_gemm(
    const unsigned short* __restrict__ a, const unsigned short* __restrict__ wf,
    const float* __restrict__ bias, float* __restrict__ out) {
    __shared__ unsigned short As[2 * 4096], Bs[2 * 4096];
    const int m0 = blockIdx.y * 128, n0 = blockIdx.x * 128;
    f32x4 acc[4][4];
    gemm_mainloop(a, wf, m0, n0, acc, As, Bs);

    const int t = threadIdx.x, w = t >> 6, l = t & 63;
    const int wr = w >> 1, wc = w & 1, lr = l & 15, lg = l >> 4;
#pragma unroll
    for (int i = 0; i < 4; i++) {
#pragma unroll
        for (int j = 0; j < 4; j++) {
            const int n = n0 + wc * 64 + j * 16 + lr;
            const float bia = bias[n];
#pragma unroll
            for (int r = 0; r < 4; r++) {
                const int m = m0 + wr * 64 + i * 16 + lg * 4 + r;
                out[(size_t)m * 1024 + n] = acc[i][j][r] + bia;
            }
        }
    }
}

// ---- split-K flash attention with IN-BLOCK combine (no separate combine kernel) ----
// Block = (bh, q-pair): 4 waves = 2 q-tiles x 2 key-chunks. Mainloop identical to R9
// (proven): no-max softmax (p = exp2(s), bounded), bit-test mask -> -1e9, MFMA row-sums,
// FZ opaque-zero C-init (R11-validated). After the loop, each wave stashes its
// unnormalized O~^T + l in LDS; one barrier; the 4 waves cooperatively add the two
// chunks, normalize, and store bf16 straight to attn_o (combine kernel's math/order).
// Grid 1024 x 256thr. XCD swizzle: bid&7 = xcd; 4 (b,h) pairs per xcd -> K/V L2-resident.
__global__ __launch_bounds__(256) void attn(
    const unsigned short* __restrict__ q, const unsigned short* __restrict__ k,
    const unsigned short* __restrict__ vt, const unsigned int* __restrict__ mw,
    unsigned short* __restrict__ ao) {
    __shared__ float CL[4][2080];   // per wave: [64d x 32q | 32 l], 8320 B
    const int t = threadIdx.x, w = t >> 6;
    const int l = t & 63, c = l & 31, hi = l >> 5;
    const int bid = blockIdx.x;
    const int xcd = bid & 7, idx = bid >> 3;        // idx 0..127
    const int bh = xcd * 4 + (idx & 3);
    const int qpair = idx >> 2;                     // 0..31
    const int chunk = w & 1;                        // key chunk
    const int qb = qpair * 2 + (w >> 1);            // q-tile 0..63
    const int b = bh >> 4, h = bh & 15;
    const int kb0 = chunk * 32;

    // fragment-major bases; every load below is  ptr + lane*8 shorts (16B)
    const unsigned short* qfb = q + (size_t)bh * 131072 + qb * 2048 + l * 8;
    const unsigned short* kfb = k + (size_t)bh * 131072 + l * 8;
    const unsigned short* vfb = vt + (size_t)bh * 131072 + l * 8;

    short8 qf[4];
#pragma unroll
    for (int d = 0; d < 4; d++)
        qf[d] = *(const short8*)(qfb + d * 512);

    // ones A-operand for the row-sum MFMA (bf16 1.0 = 0x3F80)
    short8 ones;
#pragma unroll
    for (int i = 0; i < 8; i++) ones[i] = (short)0x3F80;

    // opaque zero C operand (loop-invariant; blocks per-iter zero re-materialization)
    float z = 0.f;
    asm volatile("" : "+v"(z));
    f32x16 FZ;
#pragma unroll
    for (int i = 0; i < 16; i++) FZ[i] = z;

    // preload first tile of this chunk
    short8 kf[4], vf[2][2];
#pragma unroll
    for (int d = 0; d < 4; d++) kf[d] = *(const short8*)(kfb + kb0 * 2048 + d * 512);
#pragma unroll
    for (int kc = 0; kc < 2; kc++) {
        vf[0][kc] = *(const short8*)(vfb + kb0 * 2048 + kc * 512);
        vf[1][kc] = *(const short8*)(vfb + kb0 * 2048 + 1024 + kc * 512);
    }
    unsigned int wd = mw[kb0 * 2048 + qb * 32 + c];

    f32x16 OT0, OT1, LS;
#pragma unroll
    for (int i = 0; i < 16; i++) { OT0[i] = 0.f; OT1[i] = 0.f; LS[i] = 0.f; }

#pragma unroll 2
    for (int kb = kb0; kb < kb0 + 32; kb++) {
        // QK^T (K in regs from prefetch); C = opaque zero
        f32x16 S = mfma32(kf[0], qf[0], FZ);
#pragma unroll
        for (int d = 1; d < 4; d++) S = mfma32(kf[d], qf[d], S);

        // prefetch tile kb+1 (tail prefetch reads adjacent ws buffers: safe, unused)
        short8 kn[4], vn[2][2];
        const unsigned short* kpn = kfb + (kb + 1) * 2048;
        const unsigned short* vpn = vfb + (kb + 1) * 2048;
#pragma unroll
        for (int d = 0; d < 4; d++) kn[d] = *(const short8*)(kpn + d * 512);
#pragma unroll
        for (int kc = 0; kc < 2; kc++) {
            vn[0][kc] = *(const short8*)(vpn + kc * 512);
            vn[1][kc] = *(const short8*)(vpn + 1024 + kc * 512);
        }
        const unsigned int wn = mw[(kb + 1) * 2048 + qb * 32 + c];

        // mask -> -1e9, then p = exp2(s) directly (no max subtraction)
        const unsigned int wds = wd >> (4 * hi);
        float p[16];
#pragma unroll
        for (int g = 0; g < 4; g++)
#pragma unroll
            for (int u = 0; u < 4; u++)
                p[g * 4 + u] = (wds & (1u << (8 * g + u))) ? -1e9f : S[g * 4 + u];
#pragma unroll
        for (int i = 0; i < 16; i++) p[i] = exp2f(p[i]);

        // P -> bf16 A-frag: 8 cvt_pk + 4 permlane32_swap (T12)
        unsigned w8[8];
#pragma unroll
        for (int g = 0; g < 4; g++) {
            w8[2 * g]     = cvtpk(p[4 * g], p[4 * g + 1]);
            w8[2 * g + 1] = cvtpk(p[4 * g + 2], p[4 * g + 3]);
        }
        short8 pa[2];
#pragma unroll
        for (int kc = 0; kc < 2; kc++) {
            unsigned a0 = w8[4 * kc], a2 = w8[4 * kc + 2];
            plswap(a0, a2);
            unsigned a1 = w8[4 * kc + 1], a3 = w8[4 * kc + 3];
            plswap(a1, a3);
            uint4v tv; tv[0] = a0; tv[1] = a1; tv[2] = a2; tv[3] = a3;
            pa[kc] = __builtin_bit_cast(short8, tv);
        }

        // PV: O^T[d][q] += V^T * P ; row-sums on the MFMA pipe
        OT0 = mfma32(vf[0][0], pa[0], OT0);
        OT0 = mfma32(vf[0][1], pa[1], OT0);
        OT1 = mfma32(vf[1][0], pa[0], OT1);
        OT1 = mfma32(vf[1][1], pa[1], OT1);
        LS  = mfma32(ones,     pa[0], LS);
        LS  = mfma32(ones,     pa[1], LS);

#pragma unroll
        for (int d = 0; d < 4; d++) kf[d] = kn[d];
#pragma unroll
        for (int kc = 0; kc < 2; kc++) { vf[0][kc] = vn[0][kc]; vf[1][kc] = vn[1][kc]; }
        wd = wn;
    }

    // stash unnormalized O~^T [64][32] + per-q sum l into this wave's LDS region
    float* R = CL[w];
#pragma unroll
    for (int i = 0; i < 16; i++) {
        const int kr = (i & 3) + 8 * (i >> 2) + 4 * hi;
        R[kr * 32 + c]        = OT0[i];
        R[(32 + kr) * 32 + c] = OT1[i];
    }
    if (hi == 0) R[2048 + c] = LS[0];
    __syncthreads();

    // in-block combine: wave w -> q-tile (w>>1), d-half (w&1). lane: q = l>>1,
    // db = (l&1)*16 + (w&1)*32. O = (O~c0 + O~c1) / (l_c0 + l_c1), store bf16.
    const float* C0 = CL[(w >> 1) * 2];
    const float* C1 = CL[(w >> 1) * 2 + 1];
    const int qq = l >> 1, db = (l & 1) * 16 + (w & 1) * 32;
    const float inv = 1.0f / (C0[2048 + qq] + C1[2048 + qq]);
    const int row = b * 2048 + (qpair * 2 + (w >> 1)) * 32 + qq;
    unsigned short* gout = ao + (size_t)row * 1024 + h * 64 + db;
    uint4v pk0, pk1;
#pragma unroll
    for (int u = 0; u < 4; u++) {
        const int d0 = db + 2 * u, d1 = db + 8 + 2 * u;
        pk0[u] = cvtpk((C0[d0 * 32 + qq] + C1[d0 * 32 + qq]) * inv,
                       (C0[(d0 + 1) * 32 + qq] + C1[(d0 + 1) * 32 + qq]) * inv);
        pk1[u] = cvtpk((C0[d1 * 32 + qq] + C1[d1 * 32 + qq]) * inv,
                       (C0[(d1 + 1) * 32 + qq] + C1[(d1 + 1) * 32 + qq]) * inv);
    }
    *(uint4v*)(gout)     = pk0;
    *(uint4v*)(gout + 8) = pk1;
}

// ---------------- launcher ----------------
extern "C" void kernel_launch(void* const* d_in, const int* in_sizes, int n_in,
                              void* d_out, int out_size, void* d_ws, size_t ws_size,
                              hipStream_t stream) {
    const float* x     = (const float*)d_in[0];
    const int*   mask  = (const int*)d_in[1];
    const float* qkv_w = (const float*)d_in[2];
    const float* qkv_b = (const float*)d_in[3];
    const float* fc_w  = (const float*)d_in[4];
    const float* fc_b  = (const float*)d_in[5];
    float* out = (float*)d_out;

    char* ws = (char*)d_ws;
    size_t off = 0;
    auto alloc = [&](size_t bytes) {
        off = (off + 255) & ~(size_t)255;
        void* p = ws + off;
        off += bytes;
        return p;
    };
    float*          pe     = (float*)alloc(2 * 1024 * 4);
    unsigned int*   mwords = (unsigned int*)alloc((size_t)2048 * 64 * 4);
    unsigned short* xb     = (unsigned short*)alloc((size_t)4096 * 1024 * 2);
    unsigned short* wqkv   = (unsigned short*)alloc((size_t)3072 * 1024 * 2);
    unsigned short* wfc    = (unsigned short*)alloc((size_t)1024 * 1024 * 2);
    unsigned short* qb16   = (unsigned short*)alloc((size_t)2 * 16 * 2048 * 64 * 2);
    unsigned short* kb16   = (unsigned short*)alloc((size_t)2 * 16 * 2048 * 64 * 2);
    unsigned short* vtb    = (unsigned short*)alloc((size_t)2 * 16 * 64 * 2048 * 2);
    unsigned short* attn_o = (unsigned short*)alloc((size_t)4096 * 1024 * 2);

    pe_kernel<<<1, 512, 0, stream>>>(pe);
    cvt3<<<8192, 256, 0, stream>>>(x, qkv_w, fc_w, xb, wqkv, wfc);
    pack_mask<<<512, 256, 0, stream>>>(mask, mwords);
    qkv_gemm<<<dim3(24, 32), 256, 0, stream>>>(xb, wqkv, qkv_b, pe, qb16, kb16, vtb);
    attn<<<dim3(1024), 256, 0, stream>>>(qb16, kb16, vtb, mwords, attn_o);
    fc_gemm<<<dim3(8, 32), 256, 0, stream>>>(attn_o, wfc, fc_b, out);
}

// Round 13
// 150.404 us; speedup vs baseline: 1.1999x; 1.0914x over previous
//
#include <hip/hip_runtime.h>
#include <hip/hip_bf16.h>
#include <cstdint>

typedef __attribute__((ext_vector_type(8))) short short8;
typedef __attribute__((ext_vector_type(4))) float f32x4;
typedef __attribute__((ext_vector_type(16))) float f32x16;
typedef __attribute__((ext_vector_type(4))) unsigned uint4v;

#define DEV static __device__ __forceinline__

DEV f32x4 mfma16(short8 a, short8 b, f32x4 c) {
    return __builtin_amdgcn_mfma_f32_16x16x32_bf16(a, b, c, 0, 0, 0);
}
DEV f32x16 mfma32(short8 a, short8 b, f32x16 c) {
    return __builtin_amdgcn_mfma_f32_32x32x16_bf16(a, b, c, 0, 0, 0);
}

DEV unsigned short f2bf(float f) {
    __hip_bfloat16 h = __float2bfloat16(f);
    return __builtin_bit_cast(unsigned short, h);
}

// raw hardware exp2: 1 trans-pipe instruction (no libm range-check expansion).
// Inputs here are |s| <= ~30 or -1e9 (masked -> 0.0 exactly), both safe.
DEV float fexp2(float x) {
#if __has_builtin(__builtin_amdgcn_exp2f)
    return __builtin_amdgcn_exp2f(x);
#else
    float r;
    asm("v_exp_f32 %0, %1" : "=v"(r) : "v"(x));
    return r;
#endif
}

// pack two f32 -> two bf16 in a u32 (lo = first arg), RNE
DEV unsigned cvtpk(float lo, float hi) {
    unsigned r;
    asm("v_cvt_pk_bf16_f32 %0, %1, %2" : "=v"(r) : "v"(lo), "v"(hi));
    return r;
}
// vdst_hi <-> vsrc_lo swap: after, a = {a_lo, b_lo}, b = {a_hi, b_hi}
DEV void plswap(unsigned& a, unsigned& b) {
    asm volatile("v_permlane32_swap_b32 %0, %1" : "+v"(a), "+v"(b));
}

// global -> LDS direct load, 16B per lane. Dest: wave-uniform base + lane*16.
#define GLOAD16(gp, lp)                                                        \
    __builtin_amdgcn_global_load_lds(                                          \
        (const __attribute__((address_space(1))) unsigned int*)(uintptr_t)(gp),\
        (__attribute__((address_space(3))) unsigned int*)(uintptr_t)(lp),      \
        16, 0, 0)

// ---------------- prep kernels ----------------

__global__ void pe_kernel(float* __restrict__ pe) {
    int i = threadIdx.x;
    if (i >= 512) return;
    float div = expf((float)(2 * i) * (-9.210340371976184f / 1024.0f));
    pe[2 * i]          = 0.0f;      // sin(0*div)
    pe[2 * i + 1]      = 1.0f;      // cos(0*div)
    pe[1024 + 2 * i]     = sinf(div);
    pe[1024 + 2 * i + 1] = cosf(div);
}

// fused f32->bf16 conversion of x, qkv_w, fc_w (one launch). 2097152 float4s total.
__global__ void cvt3(const float* __restrict__ x, const float* __restrict__ wq,
                     const float* __restrict__ wf, unsigned short* __restrict__ xb,
                     unsigned short* __restrict__ wqb, unsigned short* __restrict__ wfb) {
    int i = blockIdx.x * blockDim.x + threadIdx.x;   // 0..2097151
    const float* src; unsigned short* dst; int off;
    if (i < 1048576)      { src = x;  dst = xb;  off = i; }
    else if (i < 1835008) { src = wq; dst = wqb; off = i - 1048576; }
    else                  { src = wf; dst = wfb; off = i - 1835008; }
    float4 v = ((const float4*)src)[off];
    ushort4 o;
    o.x = f2bf(v.x); o.y = f2bf(v.y); o.z = f2bf(v.z); o.w = f2bf(v.w);
    ((ushort4*)dst)[off] = o;
}

// mask [2048,2048] int32 (0/1) -> TRANSPOSED bit-words wT[kb][row] (kb 0..63, row 0..2047)
__global__ void pack_mask(const int* __restrict__ mask, unsigned int* __restrict__ wT) {
    int o = blockIdx.x * blockDim.x + threadIdx.x;   // 0..131071
    int kb = o >> 11, row = o & 2047;
    const int4* m4 = (const int4*)(mask + (size_t)row * 2048 + kb * 32);
    unsigned int bits = 0;
#pragma unroll
    for (int j = 0; j < 8; j++) {
        int4 v = m4[j];
        bits |= (unsigned)(v.x & 1) << (4 * j);
        bits |= (unsigned)(v.y & 1) << (4 * j + 1);
        bits |= (unsigned)(v.z & 1) << (4 * j + 2);
        bits |= (unsigned)(v.w & 1) << (4 * j + 3);
    }
    wT[o] = bits;
}

// ------- GEMM mainloop: 128x128 tile, BK=32, double-buffered LDS, swizzled reads -------
// (R9-proven.) Pre-swizzled SOURCE chunk + linear LDS dest; reads XOR the chunk slot.
// One barrier per K-step; STAGE(next) gets a full iteration of ds_read+MFMA to land.
DEV void gemm_mainloop(const unsigned short* __restrict__ A,
                       const unsigned short* __restrict__ Bm,
                       int m0, int n0, f32x4 (&acc)[4][4],
                       unsigned short* As, unsigned short* Bs) {   // each [2*4096]
    const int t = threadIdx.x;
    const int w = t >> 6;
    const int l = t & 63, lr = l & 15, lg = l >> 4;
    const int wr = w >> 1, wc = w & 1;
    const int srow = t >> 2;
    const int scg = ((t & 3) ^ ((t >> 3) & 3)) * 8;   // pre-swizzled source chunk
#pragma unroll
    for (int i = 0; i < 4; i++)
#pragma unroll
        for (int j = 0; j < 4; j++) acc[i][j] = f32x4{0.f, 0.f, 0.f, 0.f};

    const unsigned short* Ap = A + (size_t)(m0 + srow) * 1024 + scg;
    const unsigned short* Bp = Bm + (size_t)(n0 + srow) * 1024 + scg;
    unsigned short* dA = As + w * 512;
    unsigned short* dB = Bs + w * 512;

    // swizzled read bases (loop-invariant): slot = lg ^ ((lr>>1)&3)
    const int slot = (lg ^ ((lr >> 1) & 3)) * 8;
    const unsigned short* Ar = As + (wr * 64 + lr) * 32 + slot;
    const unsigned short* Br = Bs + (wc * 64 + lr) * 32 + slot;

#define STAGE(buf, k0)                                                \
    {                                                                 \
        GLOAD16(Ap + (k0), dA + (buf) * 4096);                        \
        GLOAD16(Ap + 64 * 1024 + (k0), dA + (buf) * 4096 + 2048);     \
        GLOAD16(Bp + (k0), dB + (buf) * 4096);                        \
        GLOAD16(Bp + 64 * 1024 + (k0), dB + (buf) * 4096 + 2048);     \
    }

    STAGE(0, 0);
#pragma unroll 2
    for (int k0 = 0; k0 < 1024; k0 += 32) {
        const int cur = (k0 >> 5) & 1;
        __syncthreads();                      // drains vmcnt: buf[cur] ready; prev reads done
        if (k0 + 32 < 1024) STAGE(cur ^ 1, k0 + 32);
        short8 af[4], bfr[4];
#pragma unroll
        for (int i = 0; i < 4; i++)
            af[i] = *(const short8*)(Ar + cur * 4096 + i * 512);
#pragma unroll
        for (int j = 0; j < 4; j++)
            bfr[j] = *(const short8*)(Br + cur * 4096 + j * 512);
#pragma unroll
        for (int i = 0; i < 4; i++)
#pragma unroll
            for (int j = 0; j < 4; j++)
                acc[i][j] = mfma16(af[i], bfr[j], acc[i][j]);
    }
#undef STAGE
}

// qkv GEMM: epilogue +bias, +pe (q,k), q *= 1/8*log2e; scatter into FRAGMENT-MAJOR
// layouts so the attn kernel's loads are lane-coalesced (addr = base + lane*16B).
__global__ __launch_bounds__(256) void qkv_gemm(
    const unsigned short* __restrict__ x, const unsigned short* __restrict__ wq,
    const float* __restrict__ bias, const float* __restrict__ pe,
    unsigned short* __restrict__ qo, unsigned short* __restrict__ ko,
    unsigned short* __restrict__ vt) {
    __shared__ unsigned short As[2 * 4096], Bs[2 * 4096];
    const int m0 = blockIdx.y * 128, n0 = blockIdx.x * 128;
    f32x4 acc[4][4];
    gemm_mainloop(x, wq, m0, n0, acc, As, Bs);

    const int t = threadIdx.x, w = t >> 6, l = t & 63;
    const int wr = w >> 1, wc = w & 1, lr = l & 15, lg = l >> 4;
#pragma unroll
    for (int i = 0; i < 4; i++) {
#pragma unroll
        for (int j = 0; j < 4; j++) {
            const int n = n0 + wc * 64 + j * 16 + lr;
            const int part = n >> 10, d = n & 1023, h = d >> 6, hd = d & 63;
            const float bia = bias[n];
#pragma unroll
            for (int r = 0; r < 4; r++) {
                const int m = m0 + wr * 64 + i * 16 + lg * 4 + r;
                const int b = m >> 11, s = m & 2047;
                const int bh = b * 16 + h;
                float v = acc[i][j][r] + bia;
                if (part == 2) {
                    const size_t off = (size_t)bh * 131072 + (s >> 5) * 2048 +
                                       (hd >> 5) * 1024 + ((s >> 4) & 1) * 512 +
                                       (((s >> 3) & 1) * 32 + (hd & 31)) * 8 + (s & 7);
                    vt[off] = f2bf(v);
                } else {
                    const size_t off = (size_t)bh * 131072 + (s >> 5) * 2048 +
                                       (hd >> 4) * 512 +
                                       (((hd >> 3) & 1) * 32 + (s & 31)) * 8 + (hd & 7);
                    if (part == 0) {
                        v = (v + pe[b * 1024 + d]) * 0.1803368801111204f; // 1/8 * log2(e)
                        qo[off] = f2bf(v);
                    } else {
                        v += pe[b * 1024 + d];
                        ko[off] = f2bf(v);
                    }
                }
            }
        }
    }
}

// fc GEMM: M=4096, N=1024, out f32 += fc_b
__global__ __launch_bounds__(256) void fc_gemm(
    const unsigned short* __restrict__ a, const unsigned short* __restrict__ wf,
    const float* __restrict__ bias, float* __restrict__ out) {
    __shared__ unsigned short As[2 * 4096], Bs[2 * 4096];
    const int m0 = blockIdx.y * 128, n0 = blockIdx.x * 128;
    f32x4 acc[4][4];
    gemm_mainloop(a, wf, m0, n0, acc, As, Bs);

    const int t = threadIdx.x, w = t >> 6, l = t & 63;
    const int wr = w >> 1, wc = w & 1, lr = l & 15, lg = l >> 4;
#pragma unroll
    for (int i = 0; i < 4; i++) {
#pragma unroll
        for (int j = 0; j < 4; j++) {
            const int n = n0 + wc * 64 + j * 16 + lr;
            const float bia = bias[n];
#pragma unroll
            for (int r = 0; r < 4; r++) {
                const int m = m0 + wr * 64 + i * 16 + lg * 4 + r;
                out[(size_t)m * 1024 + n] = acc[i][j][r] + bia;
            }
        }
    }
}

// ---- split-K flash attention with IN-BLOCK combine (no separate combine kernel) ----
// Block = (bh, q-pair): 4 waves = 2 q-tiles x 2 key-chunks. Mainloop identical to R12
// except exp2f -> raw v_exp_f32 (fexp2). After the loop, each wave stashes its
// unnormalized O~^T + l in LDS; one barrier; the 4 waves cooperatively add the two
// chunks, normalize, and store bf16 straight to attn_o.
// Grid 1024 x 256thr. XCD swizzle: bid&7 = xcd; 4 (b,h) pairs per xcd -> K/V L2-resident.
__global__ __launch_bounds__(256) void attn(
    const unsigned short* __restrict__ q, const unsigned short* __restrict__ k,
    const unsigned short* __restrict__ vt, const unsigned int* __restrict__ mw,
    unsigned short* __restrict__ ao) {
    __shared__ float CL[4][2080];   // per wave: [64d x 32q | 32 l], 8320 B
    const int t = threadIdx.x, w = t >> 6;
    const int l = t & 63, c = l & 31, hi = l >> 5;
    const int bid = blockIdx.x;
    const int xcd = bid & 7, idx = bid >> 3;        // idx 0..127
    const int bh = xcd * 4 + (idx & 3);
    const int qpair = idx >> 2;                     // 0..31
    const int chunk = w & 1;                        // key chunk
    const int qb = qpair * 2 + (w >> 1);            // q-tile 0..63
    const int b = bh >> 4, h = bh & 15;
    const int kb0 = chunk * 32;

    // fragment-major bases; every load below is  ptr + lane*8 shorts (16B)
    const unsigned short* qfb = q + (size_t)bh * 131072 + qb * 2048 + l * 8;
    const unsigned short* kfb = k + (size_t)bh * 131072 + l * 8;
    const unsigned short* vfb = vt + (size_t)bh * 131072 + l * 8;

    short8 qf[4];
#pragma unroll
    for (int d = 0; d < 4; d++)
        qf[d] = *(const short8*)(qfb + d * 512);

    // ones A-operand for the row-sum MFMA (bf16 1.0 = 0x3F80)
    short8 ones;
#pragma unroll
    for (int i = 0; i < 8; i++) ones[i] = (short)0x3F80;

    // opaque zero C operand (loop-invariant; blocks per-iter zero re-materialization)
    float z = 0.f;
    asm volatile("" : "+v"(z));
    f32x16 FZ;
#pragma unroll
    for (int i = 0; i < 16; i++) FZ[i] = z;

    // preload first tile of this chunk
    short8 kf[4], vf[2][2];
#pragma unroll
    for (int d = 0; d < 4; d++) kf[d] = *(const short8*)(kfb + kb0 * 2048 + d * 512);
#pragma unroll
    for (int kc = 0; kc < 2; kc++) {
        vf[0][kc] = *(const short8*)(vfb + kb0 * 2048 + kc * 512);
        vf[1][kc] = *(const short8*)(vfb + kb0 * 2048 + 1024 + kc * 512);
    }
    unsigned int wd = mw[kb0 * 2048 + qb * 32 + c];

    f32x16 OT0, OT1, LS;
#pragma unroll
    for (int i = 0; i < 16; i++) { OT0[i] = 0.f; OT1[i] = 0.f; LS[i] = 0.f; }

#pragma unroll 2
    for (int kb = kb0; kb < kb0 + 32; kb++) {
        // QK^T (K in regs from prefetch); C = opaque zero
        f32x16 S = mfma32(kf[0], qf[0], FZ);
#pragma unroll
        for (int d = 1; d < 4; d++) S = mfma32(kf[d], qf[d], S);

        // prefetch tile kb+1 (tail prefetch reads adjacent ws buffers: safe, unused)
        short8 kn[4], vn[2][2];
        const unsigned short* kpn = kfb + (kb + 1) * 2048;
        const unsigned short* vpn = vfb + (kb + 1) * 2048;
#pragma unroll
        for (int d = 0; d < 4; d++) kn[d] = *(const short8*)(kpn + d * 512);
#pragma unroll
        for (int kc = 0; kc < 2; kc++) {
            vn[0][kc] = *(const short8*)(vpn + kc * 512);
            vn[1][kc] = *(const short8*)(vpn + 1024 + kc * 512);
        }
        const unsigned int wn = mw[(kb + 1) * 2048 + qb * 32 + c];

        // mask -> -1e9, then p = 2^s via raw v_exp_f32 (exp2(-1e9) = 0 exactly)
        const unsigned int wds = wd >> (4 * hi);
        float p[16];
#pragma unroll
        for (int g = 0; g < 4; g++)
#pragma unroll
            for (int u = 0; u < 4; u++)
                p[g * 4 + u] = (wds & (1u << (8 * g + u))) ? -1e9f : S[g * 4 + u];
#pragma unroll
        for (int i = 0; i < 16; i++) p[i] = fexp2(p[i]);

        // P -> bf16 A-frag: 8 cvt_pk + 4 permlane32_swap (T12)
        unsigned w8[8];
#pragma unroll
        for (int g = 0; g < 4; g++) {
            w8[2 * g]     = cvtpk(p[4 * g], p[4 * g + 1]);
            w8[2 * g + 1] = cvtpk(p[4 * g + 2], p[4 * g + 3]);
        }
        short8 pa[2];
#pragma unroll
        for (int kc = 0; kc < 2; kc++) {
            unsigned a0 = w8[4 * kc], a2 = w8[4 * kc + 2];
            plswap(a0, a2);
            unsigned a1 = w8[4 * kc + 1], a3 = w8[4 * kc + 3];
            plswap(a1, a3);
            uint4v tv; tv[0] = a0; tv[1] = a1; tv[2] = a2; tv[3] = a3;
            pa[kc] = __builtin_bit_cast(short8, tv);
        }

        // PV: O^T[d][q] += V^T * P ; row-sums on the MFMA pipe
        OT0 = mfma32(vf[0][0], pa[0], OT0);
        OT0 = mfma32(vf[0][1], pa[1], OT0);
        OT1 = mfma32(vf[1][0], pa[0], OT1);
        OT1 = mfma32(vf[1][1], pa[1], OT1);
        LS  = mfma32(ones,     pa[0], LS);
        LS  = mfma32(ones,     pa[1], LS);

#pragma unroll
        for (int d = 0; d < 4; d++) kf[d] = kn[d];
#pragma unroll
        for (int kc = 0; kc < 2; kc++) { vf[0][kc] = vn[0][kc]; vf[1][kc] = vn[1][kc]; }
        wd = wn;
    }

    // stash unnormalized O~^T [64][32] + per-q sum l into this wave's LDS region
    float* R = CL[w];
#pragma unroll
    for (int i = 0; i < 16; i++) {
        const int kr = (i & 3) + 8 * (i >> 2) + 4 * hi;
        R[kr * 32 + c]        = OT0[i];
        R[(32 + kr) * 32 + c] = OT1[i];
    }
    if (hi == 0) R[2048 + c] = LS[0];
    __syncthreads();

    // in-block combine: wave w -> q-tile (w>>1), d-half (w&1). lane: q = l>>1,
    // db = (l&1)*16 + (w&1)*32. O = (O~c0 + O~c1) / (l_c0 + l_c1), store bf16.
    const float* C0 = CL[(w >> 1) * 2];
    const float* C1 = CL[(w >> 1) * 2 + 1];
    const int qq = l >> 1, db = (l & 1) * 16 + (w & 1) * 32;
    const float inv = 1.0f / (C0[2048 + qq] + C1[2048 + qq]);
    const int row = b * 2048 + (qpair * 2 + (w >> 1)) * 32 + qq;
    unsigned short* gout = ao + (size_t)row * 1024 + h * 64 + db;
    uint4v pk0, pk1;
#pragma unroll
    for (int u = 0; u < 4; u++) {
        const int d0 = db + 2 * u, d1 = db + 8 + 2 * u;
        pk0[u] = cvtpk((C0[d0 * 32 + qq] + C1[d0 * 32 + qq]) * inv,
                       (C0[(d0 + 1) * 32 + qq] + C1[(d0 + 1) * 32 + qq]) * inv);
        pk1[u] = cvtpk((C0[d1 * 32 + qq] + C1[d1 * 32 + qq]) * inv,
                       (C0[(d1 + 1) * 32 + qq] + C1[(d1 + 1) * 32 + qq]) * inv);
    }
    *(uint4v*)(gout)     = pk0;
    *(uint4v*)(gout + 8) = pk1;
}

// ---------------- launcher ----------------
extern "C" void kernel_launch(void* const* d_in, const int* in_sizes, int n_in,
                              void* d_out, int out_size, void* d_ws, size_t ws_size,
                              hipStream_t stream) {
    const float* x     = (const float*)d_in[0];
    const int*   mask  = (const int*)d_in[1];
    const float* qkv_w = (const float*)d_in[2];
    const float* qkv_b = (const float*)d_in[3];
    const float* fc_w  = (const float*)d_in[4];
    const float* fc_b  = (const float*)d_in[5];
    float* out = (float*)d_out;

    char* ws = (char*)d_ws;
    size_t off = 0;
    auto alloc = [&](size_t bytes) {
        off = (off + 255) & ~(size_t)255;
        void* p = ws + off;
        off += bytes;
        return p;
    };
    float*          pe     = (float*)alloc(2 * 1024 * 4);
    unsigned int*   mwords = (unsigned int*)alloc((size_t)2048 * 64 * 4);
    unsigned short* xb     = (unsigned short*)alloc((size_t)4096 * 1024 * 2);
    unsigned short* wqkv   = (unsigned short*)alloc((size_t)3072 * 1024 * 2);
    unsigned short* wfc    = (unsigned short*)alloc((size_t)1024 * 1024 * 2);
    unsigned short* qb16   = (unsigned short*)alloc((size_t)2 * 16 * 2048 * 64 * 2);
    unsigned short* kb16   = (unsigned short*)alloc((size_t)2 * 16 * 2048 * 64 * 2);
    unsigned short* vtb    = (unsigned short*)alloc((size_t)2 * 16 * 64 * 2048 * 2);
    unsigned short* attn_o = (unsigned short*)alloc((size_t)4096 * 1024 * 2);

    pe_kernel<<<1, 512, 0, stream>>>(pe);
    cvt3<<<8192, 256, 0, stream>>>(x, qkv_w, fc_w, xb, wqkv, wfc);
    pack_mask<<<512, 256, 0, stream>>>(mask, mwords);
    qkv_gemm<<<dim3(24, 32), 256, 0, stream>>>(xb, wqkv, qkv_b, pe, qb16, kb16, vtb);
    attn<<<dim3(1024), 256, 0, stream>>>(qb16, kb16, vtb, mwords, attn_o);
    fc_gemm<<<dim3(8, 32), 256, 0, stream>>>(attn_o, wfc, fc_b, out);
}

// Round 15
// 147.327 us; speedup vs baseline: 1.2249x; 1.0209x over previous
//
#include <hip/hip_runtime.h>
#include <hip/hip_bf16.h>
#include <cstdint>

typedef __attribute__((ext_vector_type(8))) short short8;
typedef __attribute__((ext_vector_type(4))) float f32x4;
typedef __attribute__((ext_vector_type(16))) float f32x16;
typedef __attribute__((ext_vector_type(4))) unsigned uint4v;

#define DEV static __device__ __forceinline__

DEV f32x4 mfma16(short8 a, short8 b, f32x4 c) {
    return __builtin_amdgcn_mfma_f32_16x16x32_bf16(a, b, c, 0, 0, 0);
}
DEV f32x16 mfma32(short8 a, short8 b, f32x16 c) {
    return __builtin_amdgcn_mfma_f32_32x32x16_bf16(a, b, c, 0, 0, 0);
}

DEV unsigned short f2bf(float f) {
    __hip_bfloat16 h = __float2bfloat16(f);
    return __builtin_bit_cast(unsigned short, h);
}

// raw hardware exp2: 1 trans-pipe instruction (no libm range-check expansion).
DEV float fexp2(float x) {
#if __has_builtin(__builtin_amdgcn_exp2f)
    return __builtin_amdgcn_exp2f(x);
#else
    float r;
    asm("v_exp_f32 %0, %1" : "=v"(r) : "v"(x));
    return r;
#endif
}

// pack two f32 -> two bf16 in a u32 (lo = first arg), RNE
DEV unsigned cvtpk(float lo, float hi) {
    unsigned r;
    asm("v_cvt_pk_bf16_f32 %0, %1, %2" : "=v"(r) : "v"(lo), "v"(hi));
    return r;
}
// vdst_hi <-> vsrc_lo swap: after, a = {a_lo, b_lo}, b = {a_hi, b_hi}
DEV void plswap(unsigned& a, unsigned& b) {
    asm volatile("v_permlane32_swap_b32 %0, %1" : "+v"(a), "+v"(b));
}

// global -> LDS direct load, 16B per lane. Dest: wave-uniform base + lane*16.
#define GLOAD16(gp, lp)                                                        \
    __builtin_amdgcn_global_load_lds(                                          \
        (const __attribute__((address_space(1))) unsigned int*)(uintptr_t)(gp),\
        (__attribute__((address_space(3))) unsigned int*)(uintptr_t)(lp),      \
        16, 0, 0)

// ---------------- prep kernels ----------------

__global__ void pe_kernel(float* __restrict__ pe) {
    int i = threadIdx.x;
    if (i >= 512) return;
    float div = expf((float)(2 * i) * (-9.210340371976184f / 1024.0f));
    pe[2 * i]          = 0.0f;      // sin(0*div)
    pe[2 * i + 1]      = 1.0f;      // cos(0*div)
    pe[1024 + 2 * i]     = sinf(div);
    pe[1024 + 2 * i + 1] = cosf(div);
}

// fused f32->bf16 conversion of x, qkv_w, fc_w (one launch). 2097152 float4s total.
__global__ void cvt3(const float* __restrict__ x, const float* __restrict__ wq,
                     const float* __restrict__ wf, unsigned short* __restrict__ xb,
                     unsigned short* __restrict__ wqb, unsigned short* __restrict__ wfb) {
    int i = blockIdx.x * blockDim.x + threadIdx.x;   // 0..2097151
    const float* src; unsigned short* dst; int off;
    if (i < 1048576)      { src = x;  dst = xb;  off = i; }
    else if (i < 1835008) { src = wq; dst = wqb; off = i - 1048576; }
    else                  { src = wf; dst = wfb; off = i - 1835008; }
    float4 v = ((const float4*)src)[off];
    ushort4 o;
    o.x = f2bf(v.x); o.y = f2bf(v.y); o.z = f2bf(v.z); o.w = f2bf(v.w);
    ((ushort4*)dst)[off] = o;
}

// mask [2048,2048] int32 (0/1) -> TRANSPOSED bit-words wT[kb][row] (kb 0..63, row 0..2047)
__global__ void pack_mask(const int* __restrict__ mask, unsigned int* __restrict__ wT) {
    int o = blockIdx.x * blockDim.x + threadIdx.x;   // 0..131071
    int kb = o >> 11, row = o & 2047;
    const int4* m4 = (const int4*)(mask + (size_t)row * 2048 + kb * 32);
    unsigned int bits = 0;
#pragma unroll
    for (int j = 0; j < 8; j++) {
        int4 v = m4[j];
        bits |= (unsigned)(v.x & 1) << (4 * j);
        bits |= (unsigned)(v.y & 1) << (4 * j + 1);
        bits |= (unsigned)(v.z & 1) << (4 * j + 2);
        bits |= (unsigned)(v.w & 1) << (4 * j + 3);
    }
    wT[o] = bits;
}

// ------- GEMM mainloop: 128x128 tile, BK=32, double-buffered LDS, swizzled reads -------
// (R9-proven.) Pre-swizzled SOURCE chunk + linear LDS dest; reads XOR the chunk slot.
DEV void gemm_mainloop(const unsigned short* __restrict__ A,
                       const unsigned short* __restrict__ Bm,
                       int m0, int n0, f32x4 (&acc)[4][4],
                       unsigned short* As, unsigned short* Bs) {   // each [2*4096]
    const int t = threadIdx.x;
    const int w = t >> 6;
    const int l = t & 63, lr = l & 15, lg = l >> 4;
    const int wr = w >> 1, wc = w & 1;
    const int srow = t >> 2;
    const int scg = ((t & 3) ^ ((t >> 3) & 3)) * 8;   // pre-swizzled source chunk
#pragma unroll
    for (int i = 0; i < 4; i++)
#pragma unroll
        for (int j = 0; j < 4; j++) acc[i][j] = f32x4{0.f, 0.f, 0.f, 0.f};

    const unsigned short* Ap = A + (size_t)(m0 + srow) * 1024 + scg;
    const unsigned short* Bp = Bm + (size_t)(n0 + srow) * 1024 + scg;
    unsigned short* dA = As + w * 512;
    unsigned short* dB = Bs + w * 512;

    // swizzled read bases (loop-invariant): slot = lg ^ ((lr>>1)&3)
    const int slot = (lg ^ ((lr >> 1) & 3)) * 8;
    const unsigned short* Ar = As + (wr * 64 + lr) * 32 + slot;
    const unsigned short* Br = Bs + (wc * 64 + lr) * 32 + slot;

#define STAGE(buf, k0)                                                \
    {                                                                 \
        GLOAD16(Ap + (k0), dA + (buf) * 4096);                        \
        GLOAD16(Ap + 64 * 1024 + (k0), dA + (buf) * 4096 + 2048);     \
        GLOAD16(Bp + (k0), dB + (buf) * 4096);                        \
        GLOAD16(Bp + 64 * 1024 + (k0), dB + (buf) * 4096 + 2048);     \
    }

    STAGE(0, 0);
#pragma unroll 2
    for (int k0 = 0; k0 < 1024; k0 += 32) {
        const int cur = (k0 >> 5) & 1;
        __syncthreads();                      // drains vmcnt: buf[cur] ready; prev reads done
        if (k0 + 32 < 1024) STAGE(cur ^ 1, k0 + 32);
        short8 af[4], bfr[4];
#pragma unroll
        for (int i = 0; i < 4; i++)
            af[i] = *(const short8*)(Ar + cur * 4096 + i * 512);
#pragma unroll
        for (int j = 0; j < 4; j++)
            bfr[j] = *(const short8*)(Br + cur * 4096 + j * 512);
#pragma unroll
        for (int i = 0; i < 4; i++)
#pragma unroll
            for (int j = 0; j < 4; j++)
                acc[i][j] = mfma16(af[i], bfr[j], acc[i][j]);
    }
#undef STAGE
}

// qkv GEMM: epilogue +bias, +pe (q,k), q *= 1/8*log2e; outputs in FRAGMENT-MAJOR
// layouts. Epilogue routes through LDS -- the 128x128 tile spans exactly 8 complete
// 4KB fragment chunks (4 s-tiles x 2 heads); stage scattered in LDS (same proven
// offset formulas, chunk-relative), then 8 coalesced dwordx4 stores/thread.
// R15 fix: fragment tile index is PER-BATCH (s>>5), i.e. (m0 & 2047) >> 5 -- R14 used
// m0>>5, overflowing into the next bh chunk for batch 1.
__global__ __launch_bounds__(256) void qkv_gemm(
    const unsigned short* __restrict__ x, const unsigned short* __restrict__ wq,
    const float* __restrict__ bias, const float* __restrict__ pe,
    unsigned short* __restrict__ qo, unsigned short* __restrict__ ko,
    unsigned short* __restrict__ vt) {
    __shared__ unsigned short SB[16384];      // mainloop: As|Bs ; epilogue: 8x2048 chunks
    const int m0 = blockIdx.y * 128, n0 = blockIdx.x * 128;
    f32x4 acc[4][4];
    gemm_mainloop(x, wq, m0, n0, acc, SB, SB + 8192);

    const int t = threadIdx.x, w = t >> 6, l = t & 63;
    const int wr = w >> 1, wc = w & 1, lr = l & 15, lg = l >> 4;
    const int part = n0 >> 10;                // uniform per block (1024 % 128 == 0)
    const int h0 = (n0 & 1023) >> 6;
    const int b  = m0 >> 11;

    __syncthreads();   // all waves done reading SB (mainloop) before overwrite
#pragma unroll
    for (int i = 0; i < 4; i++) {
#pragma unroll
        for (int j = 0; j < 4; j++) {
            const int n = n0 + wc * 64 + j * 16 + lr;
            const int d = n & 1023, hd = d & 63;
            const int h_loc = (d >> 6) & 1;
            const float bia = bias[n];
            const float pv = (part < 2) ? pe[b * 1024 + d] : 0.f;
#pragma unroll
            for (int r = 0; r < 4; r++) {
                const int m = m0 + wr * 64 + i * 16 + lg * 4 + r;
                const int s = m & 2047, s5 = s & 31, t_loc = (s >> 5) & 3;
                float v = acc[i][j][r] + bia;
                int inner;
                if (part == 2) {
                    inner = (hd >> 5) * 1024 + ((s5 >> 4) & 1) * 512 +
                            (((s5 >> 3) & 1) * 32 + (hd & 31)) * 8 + (s5 & 7);
                } else {
                    v += pv;
                    if (part == 0) v *= 0.1803368801111204f;   // 1/8 * log2(e)
                    inner = (hd >> 4) * 512 + (((hd >> 3) & 1) * 32 + s5) * 8 + (hd & 7);
                }
                SB[(t_loc * 2 + h_loc) * 2048 + inner] = f2bf(v);
            }
        }
    }
    __syncthreads();

    // linear copy: chunk cidx = t>>5 -> global fragment tile (t_g, h0 + (cidx&1));
    // t_g is the PER-BATCH s-tile: ((m0 & 2047) >> 5) + (cidx >> 1).
    unsigned short* dst0 = (part == 0) ? qo : (part == 1) ? ko : vt;
    const int cidx = t >> 5;
    const int t_g = ((m0 & 2047) >> 5) + (cidx >> 1);
    const int bh = b * 16 + h0 + (cidx & 1);
    unsigned short* gdst = dst0 + (size_t)bh * 131072 + t_g * 2048 + (t & 31) * 64;
    const unsigned short* lsrc = SB + cidx * 2048 + (t & 31) * 64;
#pragma unroll
    for (int u = 0; u < 8; u++)
        *(short8*)(gdst + u * 8) = *(const short8*)(lsrc + u * 8);
}

// fc GEMM: M=4096, N=1024, out f32 += fc_b
__global__ __launch_bounds__(256) void fc_gemm(
    const unsigned short* __restrict__ a, const unsigned short* __restrict__ wf,
    const float* __restrict__ bias, float* __restrict__ out) {
    __shared__ unsigned short As[2 * 4096], Bs[2 * 4096];
    const int m0 = blockIdx.y * 128, n0 = blockIdx.x * 128;
    f32x4 acc[4][4];
    gemm_mainloop(a, wf, m0, n0, acc, As, Bs);

    const int t = threadIdx.x, w = t >> 6, l = t & 63;
    const int wr = w >> 1, wc = w & 1, lr = l & 15, lg = l >> 4;
#pragma unroll
    for (int i = 0; i < 4; i++) {
#pragma unroll
        for (int j = 0; j < 4; j++) {
            const int n = n0 + wc * 64 + j * 16 + lr;
            const float bia = bias[n];
#pragma unroll
            for (int r = 0; r < 4; r++) {
                const int m = m0 + wr * 64 + i * 16 + lg * 4 + r;
                out[(size_t)m * 1024 + n] = acc[i][j][r] + bia;
            }
        }
    }
}

// ---- split-K flash attention with IN-BLOCK combine (R13-proven) + T5 setprio ----
__global__ __launch_bounds__(256) void attn(
    const unsigned short* __restrict__ q, const unsigned short* __restrict__ k,
    const unsigned short* __restrict__ vt, const unsigned int* __restrict__ mw,
    unsigned short* __restrict__ ao) {
    __shared__ float CL[4][2080];   // per wave: [64d x 32q | 32 l], 8320 B
    const int t = threadIdx.x, w = t >> 6;
    const int l = t & 63, c = l & 31, hi = l >> 5;
    const int bid = blockIdx.x;
    const int xcd = bid & 7, idx = bid >> 3;        // idx 0..127
    const int bh = xcd * 4 + (idx & 3);
    const int qpair = idx >> 2;                     // 0..31
    const int chunk = w & 1;                        // key chunk
    const int qb = qpair * 2 + (w >> 1);            // q-tile 0..63
    const int b = bh >> 4, h = bh & 15;
    const int kb0 = chunk * 32;

    // fragment-major bases; every load below is  ptr + lane*8 shorts (16B)
    const unsigned short* qfb = q + (size_t)bh * 131072 + qb * 2048 + l * 8;
    const unsigned short* kfb = k + (size_t)bh * 131072 + l * 8;
    const unsigned short* vfb = vt + (size_t)bh * 131072 + l * 8;

    short8 qf[4];
#pragma unroll
    for (int d = 0; d < 4; d++)
        qf[d] = *(const short8*)(qfb + d * 512);

    // ones A-operand for the row-sum MFMA (bf16 1.0 = 0x3F80)
    short8 ones;
#pragma unroll
    for (int i = 0; i < 8; i++) ones[i] = (short)0x3F80;

    // opaque zero C operand (loop-invariant; blocks per-iter zero re-materialization)
    float z = 0.f;
    asm volatile("" : "+v"(z));
    f32x16 FZ;
#pragma unroll
    for (int i = 0; i < 16; i++) FZ[i] = z;

    // preload first tile of this chunk
    short8 kf[4], vf[2][2];
#pragma unroll
    for (int d = 0; d < 4; d++) kf[d] = *(const short8*)(kfb + kb0 * 2048 + d * 512);
#pragma unroll
    for (int kc = 0; kc < 2; kc++) {
        vf[0][kc] = *(const short8*)(vfb + kb0 * 2048 + kc * 512);
        vf[1][kc] = *(const short8*)(vfb + kb0 * 2048 + 1024 + kc * 512);
    }
    unsigned int wd = mw[kb0 * 2048 + qb * 32 + c];

    f32x16 OT0, OT1, LS;
#pragma unroll
    for (int i = 0; i < 16; i++) { OT0[i] = 0.f; OT1[i] = 0.f; LS[i] = 0.f; }

#pragma unroll 2
    for (int kb = kb0; kb < kb0 + 32; kb++) {
        // QK^T (K in regs from prefetch); C = opaque zero
        __builtin_amdgcn_s_setprio(1);
        f32x16 S = mfma32(kf[0], qf[0], FZ);
#pragma unroll
        for (int d = 1; d < 4; d++) S = mfma32(kf[d], qf[d], S);
        __builtin_amdgcn_s_setprio(0);

        // prefetch tile kb+1 (tail prefetch reads adjacent ws buffers: safe, unused)
        short8 kn[4], vn[2][2];
        const unsigned short* kpn = kfb + (kb + 1) * 2048;
        const unsigned short* vpn = vfb + (kb + 1) * 2048;
#pragma unroll
        for (int d = 0; d < 4; d++) kn[d] = *(const short8*)(kpn + d * 512);
#pragma unroll
        for (int kc = 0; kc < 2; kc++) {
            vn[0][kc] = *(const short8*)(vpn + kc * 512);
            vn[1][kc] = *(const short8*)(vpn + 1024 + kc * 512);
        }
        const unsigned int wn = mw[(kb + 1) * 2048 + qb * 32 + c];

        // mask -> -1e9, then p = 2^s via raw v_exp_f32 (exp2(-1e9) = 0 exactly)
        const unsigned int wds = wd >> (4 * hi);
        float p[16];
#pragma unroll
        for (int g = 0; g < 4; g++)
#pragma unroll
            for (int u = 0; u < 4; u++)
                p[g * 4 + u] = (wds & (1u << (8 * g + u))) ? -1e9f : S[g * 4 + u];
#pragma unroll
        for (int i = 0; i < 16; i++) p[i] = fexp2(p[i]);

        // P -> bf16 A-frag: 8 cvt_pk + 4 permlane32_swap (T12)
        unsigned w8[8];
#pragma unroll
        for (int g = 0; g < 4; g++) {
            w8[2 * g]     = cvtpk(p[4 * g], p[4 * g + 1]);
            w8[2 * g + 1] = cvtpk(p[4 * g + 2], p[4 * g + 3]);
        }
        short8 pa[2];
#pragma unroll
        for (int kc = 0; kc < 2; kc++) {
            unsigned a0 = w8[4 * kc], a2 = w8[4 * kc + 2];
            plswap(a0, a2);
            unsigned a1 = w8[4 * kc + 1], a3 = w8[4 * kc + 3];
            plswap(a1, a3);
            uint4v tv; tv[0] = a0; tv[1] = a1; tv[2] = a2; tv[3] = a3;
            pa[kc] = __builtin_bit_cast(short8, tv);
        }

        // PV: O^T[d][q] += V^T * P ; row-sums on the MFMA pipe
        __builtin_amdgcn_s_setprio(1);
        OT0 = mfma32(vf[0][0], pa[0], OT0);
        OT0 = mfma32(vf[0][1], pa[1], OT0);
        OT1 = mfma32(vf[1][0], pa[0], OT1);
        OT1 = mfma32(vf[1][1], pa[1], OT1);
        LS  = mfma32(ones,     pa[0], LS);
        LS  = mfma32(ones,     pa[1], LS);
        __builtin_amdgcn_s_setprio(0);

#pragma unroll
        for (int d = 0; d < 4; d++) kf[d] = kn[d];
#pragma unroll
        for (int kc = 0; kc < 2; kc++) { vf[0][kc] = vn[0][kc]; vf[1][kc] = vn[1][kc]; }
        wd = wn;
    }

    // stash unnormalized O~^T [64][32] + per-q sum l into this wave's LDS region
    float* R = CL[w];
#pragma unroll
    for (int i = 0; i < 16; i++) {
        const int kr = (i & 3) + 8 * (i >> 2) + 4 * hi;
        R[kr * 32 + c]        = OT0[i];
        R[(32 + kr) * 32 + c] = OT1[i];
    }
    if (hi == 0) R[2048 + c] = LS[0];
    __syncthreads();

    // in-block combine: wave w -> q-tile (w>>1), d-half (w&1). lane: q = l>>1,
    // db = (l&1)*16 + (w&1)*32. O = (O~c0 + O~c1) / (l_c0 + l_c1), store bf16.
    const float* C0 = CL[(w >> 1) * 2];
    const float* C1 = CL[(w >> 1) * 2 + 1];
    const int qq = l >> 1, db = (l & 1) * 16 + (w & 1) * 32;
    const float inv = 1.0f / (C0[2048 + qq] + C1[2048 + qq]);
    const int row = b * 2048 + (qpair * 2 + (w >> 1)) * 32 + qq;
    unsigned short* gout = ao + (size_t)row * 1024 + h * 64 + db;
    uint4v pk0, pk1;
#pragma unroll
    for (int u = 0; u < 4; u++) {
        const int d0 = db + 2 * u, d1 = db + 8 + 2 * u;
        pk0[u] = cvtpk((C0[d0 * 32 + qq] + C1[d0 * 32 + qq]) * inv,
                       (C0[(d0 + 1) * 32 + qq] + C1[(d0 + 1) * 32 + qq]) * inv);
        pk1[u] = cvtpk((C0[d1 * 32 + qq] + C1[d1 * 32 + qq]) * inv,
                       (C0[(d1 + 1) * 32 + qq] + C1[(d1 + 1) * 32 + qq]) * inv);
    }
    *(uint4v*)(gout)     = pk0;
    *(uint4v*)(gout + 8) = pk1;
}

// ---------------- launcher ----------------
extern "C" void kernel_launch(void* const* d_in, const int* in_sizes, int n_in,
                              void* d_out, int out_size, void* d_ws, size_t ws_size,
                              hipStream_t stream) {
    const float* x     = (const float*)d_in[0];
    const int*   mask  = (const int*)d_in[1];
    const float* qkv_w = (const float*)d_in[2];
    const float* qkv_b = (const float*)d_in[3];
    const float* fc_w  = (const float*)d_in[4];
    const float* fc_b  = (const float*)d_in[5];
    float* out = (float*)d_out;

    char* ws = (char*)d_ws;
    size_t off = 0;
    auto alloc = [&](size_t bytes) {
        off = (off + 255) & ~(size_t)255;
        void* p = ws + off;
        off += bytes;
        return p;
    };
    float*          pe     = (float*)alloc(2 * 1024 * 4);
    unsigned int*   mwords = (unsigned int*)alloc((size_t)2048 * 64 * 4);
    unsigned short* xb     = (unsigned short*)alloc((size_t)4096 * 1024 * 2);
    unsigned short* wqkv   = (unsigned short*)alloc((size_t)3072 * 1024 * 2);
    unsigned short* wfc    = (unsigned short*)alloc((size_t)1024 * 1024 * 2);
    unsigned short* qb16   = (unsigned short*)alloc((size_t)2 * 16 * 2048 * 64 * 2);
    unsigned short* kb16   = (unsigned short*)alloc((size_t)2 * 16 * 2048 * 64 * 2);
    unsigned short* vtb    = (unsigned short*)alloc((size_t)2 * 16 * 64 * 2048 * 2);
    unsigned short* attn_o = (unsigned short*)alloc((size_t)4096 * 1024 * 2);

    pe_kernel<<<1, 512, 0, stream>>>(pe);
    cvt3<<<8192, 256, 0, stream>>>(x, qkv_w, fc_w, xb, wqkv, wfc);
    pack_mask<<<512, 256, 0, stream>>>(mask, mwords);
    qkv_gemm<<<dim3(24, 32), 256, 0, stream>>>(xb, wqkv, qkv_b, pe, qb16, kb16, vtb);
    attn<<<dim3(1024), 256, 0, stream>>>(qb16, kb16, vtb, mwords, attn_o);
    fc_gemm<<<dim3(8, 32), 256, 0, stream>>>(attn_o, wfc, fc_b, out);
}

// Round 18
// 143.994 us; speedup vs baseline: 1.2533x; 1.0232x over previous
//
#include <hip/hip_runtime.h>
#include <hip/hip_bf16.h>
#include <cstdint>

typedef __attribute__((ext_vector_type(8))) short short8;
typedef __attribute__((ext_vector_type(4))) float f32x4;
typedef __attribute__((ext_vector_type(16))) float f32x16;
typedef __attribute__((ext_vector_type(4))) unsigned uint4v;

#define DEV static __device__ __forceinline__

DEV f32x4 mfma16(short8 a, short8 b, f32x4 c) {
    return __builtin_amdgcn_mfma_f32_16x16x32_bf16(a, b, c, 0, 0, 0);
}
DEV f32x16 mfma32(short8 a, short8 b, f32x16 c) {
    return __builtin_amdgcn_mfma_f32_32x32x16_bf16(a, b, c, 0, 0, 0);
}

DEV unsigned short f2bf(float f) {
    __hip_bfloat16 h = __float2bfloat16(f);
    return __builtin_bit_cast(unsigned short, h);
}

// raw hardware exp2: 1 trans-pipe instruction (no libm range-check expansion).
DEV float fexp2(float x) {
#if __has_builtin(__builtin_amdgcn_exp2f)
    return __builtin_amdgcn_exp2f(x);
#else
    float r;
    asm("v_exp_f32 %0, %1" : "=v"(r) : "v"(x));
    return r;
#endif
}

// pack two f32 -> two bf16 in a u32 (lo = first arg), RNE
DEV unsigned cvtpk(float lo, float hi) {
    unsigned r;
    asm("v_cvt_pk_bf16_f32 %0, %1, %2" : "=v"(r) : "v"(lo), "v"(hi));
    return r;
}
// vdst_hi <-> vsrc_lo swap: after, a = {a_lo, b_lo}, b = {a_hi, b_hi}
DEV void plswap(unsigned& a, unsigned& b) {
    asm volatile("v_permlane32_swap_b32 %0, %1" : "+v"(a), "+v"(b));
}

// global -> LDS direct load, 16B per lane. Dest: wave-uniform base + lane*16.
#define GLOAD16(gp, lp)                                                        \
    __builtin_amdgcn_global_load_lds(                                          \
        (const __attribute__((address_space(1))) unsigned int*)(uintptr_t)(gp),\
        (__attribute__((address_space(3))) unsigned int*)(uintptr_t)(lp),      \
        16, 0, 0)

// ---------------- prep kernels ----------------

__global__ void pe_kernel(float* __restrict__ pe) {
    int i = threadIdx.x;
    if (i >= 512) return;
    float div = expf((float)(2 * i) * (-9.210340371976184f / 1024.0f));
    pe[2 * i]          = 0.0f;      // sin(0*div)
    pe[2 * i + 1]      = 1.0f;      // cos(0*div)
    pe[1024 + 2 * i]     = sinf(div);
    pe[1024 + 2 * i + 1] = cosf(div);
}

// fused f32->bf16 conversion of x, qkv_w, fc_w (one launch). 2097152 float4s total.
__global__ void cvt3(const float* __restrict__ x, const float* __restrict__ wq,
                     const float* __restrict__ wf, unsigned short* __restrict__ xb,
                     unsigned short* __restrict__ wqb, unsigned short* __restrict__ wfb) {
    int i = blockIdx.x * blockDim.x + threadIdx.x;   // 0..2097151
    const float* src; unsigned short* dst; int off;
    if (i < 1048576)      { src = x;  dst = xb;  off = i; }
    else if (i < 1835008) { src = wq; dst = wqb; off = i - 1048576; }
    else                  { src = wf; dst = wfb; off = i - 1835008; }
    float4 v = ((const float4*)src)[off];
    ushort4 o;
    o.x = f2bf(v.x); o.y = f2bf(v.y); o.z = f2bf(v.z); o.w = f2bf(v.w);
    ((ushort4*)dst)[off] = o;
}

// mask [2048,2048] int32 (0/1) -> TRANSPOSED bit-words wT[kb][row] (kb 0..63, row 0..2047)
__global__ void pack_mask(const int* __restrict__ mask, unsigned int* __restrict__ wT) {
    int o = blockIdx.x * blockDim.x + threadIdx.x;   // 0..131071
    int kb = o >> 11, row = o & 2047;
    const int4* m4 = (const int4*)(mask + (size_t)row * 2048 + kb * 32);
    unsigned int bits = 0;
#pragma unroll
    for (int j = 0; j < 8; j++) {
        int4 v = m4[j];
        bits |= (unsigned)(v.x & 1) << (4 * j);
        bits |= (unsigned)(v.y & 1) << (4 * j + 1);
        bits |= (unsigned)(v.z & 1) << (4 * j + 2);
        bits |= (unsigned)(v.w & 1) << (4 * j + 3);
    }
    wT[o] = bits;
}

// ------- GEMM mainloop: 128x128 tile, BK=32, double-buffered LDS, swizzled reads -------
// (R15-proven; the raw-barrier distance-2 pipeline failed twice on HW and is retired.)
// Pre-swizzled SOURCE chunk + linear LDS dest; reads XOR the chunk slot. One
// __syncthreads per K-step; STAGE(next) gets a full iteration of ds_read+MFMA to land.
DEV void gemm_mainloop(const unsigned short* __restrict__ A,
                       const unsigned short* __restrict__ Bm,
                       int m0, int n0, f32x4 (&acc)[4][4],
                       unsigned short* As, unsigned short* Bs) {   // each [2*4096]
    const int t = threadIdx.x;
    const int w = t >> 6;
    const int l = t & 63, lr = l & 15, lg = l >> 4;
    const int wr = w >> 1, wc = w & 1;
    const int srow = t >> 2;
    const int scg = ((t & 3) ^ ((t >> 3) & 3)) * 8;   // pre-swizzled source chunk
#pragma unroll
    for (int i = 0; i < 4; i++)
#pragma unroll
        for (int j = 0; j < 4; j++) acc[i][j] = f32x4{0.f, 0.f, 0.f, 0.f};

    const unsigned short* Ap = A + (size_t)(m0 + srow) * 1024 + scg;
    const unsigned short* Bp = Bm + (size_t)(n0 + srow) * 1024 + scg;
    unsigned short* dA = As + w * 512;
    unsigned short* dB = Bs + w * 512;

    // swizzled read bases (loop-invariant): slot = lg ^ ((lr>>1)&3)
    const int slot = (lg ^ ((lr >> 1) & 3)) * 8;
    const unsigned short* Ar = As + (wr * 64 + lr) * 32 + slot;
    const unsigned short* Br = Bs + (wc * 64 + lr) * 32 + slot;

#define STAGE(buf, k0)                                                \
    {                                                                 \
        GLOAD16(Ap + (k0), dA + (buf) * 4096);                        \
        GLOAD16(Ap + 64 * 1024 + (k0), dA + (buf) * 4096 + 2048);     \
        GLOAD16(Bp + (k0), dB + (buf) * 4096);                        \
        GLOAD16(Bp + 64 * 1024 + (k0), dB + (buf) * 4096 + 2048);     \
    }

    STAGE(0, 0);
#pragma unroll 2
    for (int k0 = 0; k0 < 1024; k0 += 32) {
        const int cur = (k0 >> 5) & 1;
        __syncthreads();                      // drains vmcnt: buf[cur] ready; prev reads done
        if (k0 + 32 < 1024) STAGE(cur ^ 1, k0 + 32);
        short8 af[4], bfr[4];
#pragma unroll
        for (int i = 0; i < 4; i++)
            af[i] = *(const short8*)(Ar + cur * 4096 + i * 512);
#pragma unroll
        for (int j = 0; j < 4; j++)
            bfr[j] = *(const short8*)(Br + cur * 4096 + j * 512);
#pragma unroll
        for (int i = 0; i < 4; i++)
#pragma unroll
            for (int j = 0; j < 4; j++)
                acc[i][j] = mfma16(af[i], bfr[j], acc[i][j]);
    }
#undef STAGE
}

// qkv GEMM: 1D grid 768 with XCD-aware swizzle (T1; 768 = 8*96, bijective): each XCD
// gets 96 contiguous logical blocks = 4 m-rows x 24 n -- A panels become XCD-L2-local.
// Epilogue +bias, +pe (q,k), q *= 1/8*log2e; outputs in FRAGMENT-MAJOR layouts via LDS
// (8 complete 4KB fragment chunks), then 8 coalesced dwordx4 stores/thread.
__global__ __launch_bounds__(256) void qkv_gemm(
    const unsigned short* __restrict__ x, const unsigned short* __restrict__ wq,
    const float* __restrict__ bias, const float* __restrict__ pe,
    unsigned short* __restrict__ qo, unsigned short* __restrict__ ko,
    unsigned short* __restrict__ vt) {
    __shared__ unsigned short SB[16384];      // mainloop: As|Bs ; epilogue: 8x2048 chunks
    const int lin = blockIdx.x;
    const int swz = (lin & 7) * 96 + (lin >> 3);
    const int m0 = (swz / 24) * 128, n0 = (swz % 24) * 128;
    f32x4 acc[4][4];
    gemm_mainloop(x, wq, m0, n0, acc, SB, SB + 8192);

    const int t = threadIdx.x, w = t >> 6, l = t & 63;
    const int wr = w >> 1, wc = w & 1, lr = l & 15, lg = l >> 4;
    const int part = n0 >> 10;                // uniform per block (1024 % 128 == 0)
    const int h0 = (n0 & 1023) >> 6;
    const int b  = m0 >> 11;

    __syncthreads();   // all waves done with SB (mainloop) before overwrite
#pragma unroll
    for (int i = 0; i < 4; i++) {
#pragma unroll
        for (int j = 0; j < 4; j++) {
            const int n = n0 + wc * 64 + j * 16 + lr;
            const int d = n & 1023, hd = d & 63;
            const int h_loc = (d >> 6) & 1;
            const float bia = bias[n];
            const float pv = (part < 2) ? pe[b * 1024 + d] : 0.f;
#pragma unroll
            for (int r = 0; r < 4; r++) {
                const int m = m0 + wr * 64 + i * 16 + lg * 4 + r;
                const int s = m & 2047, s5 = s & 31, t_loc = (s >> 5) & 3;
                float v = acc[i][j][r] + bia;
                int inner;
                if (part == 2) {
                    inner = (hd >> 5) * 1024 + ((s5 >> 4) & 1) * 512 +
                            (((s5 >> 3) & 1) * 32 + (hd & 31)) * 8 + (s5 & 7);
                } else {
                    v += pv;
                    if (part == 0) v *= 0.1803368801111204f;   // 1/8 * log2(e)
                    inner = (hd >> 4) * 512 + (((hd >> 3) & 1) * 32 + s5) * 8 + (hd & 7);
                }
                SB[(t_loc * 2 + h_loc) * 2048 + inner] = f2bf(v);
            }
        }
    }
    __syncthreads();

    // linear copy: chunk cidx = t>>5 -> global fragment tile (t_g, h0 + (cidx&1));
    // t_g is the PER-BATCH s-tile: ((m0 & 2047) >> 5) + (cidx >> 1).
    unsigned short* dst0 = (part == 0) ? qo : (part == 1) ? ko : vt;
    const int cidx = t >> 5;
    const int t_g = ((m0 & 2047) >> 5) + (cidx >> 1);
    const int bh = b * 16 + h0 + (cidx & 1);
    unsigned short* gdst = dst0 + (size_t)bh * 131072 + t_g * 2048 + (t & 31) * 64;
    const unsigned short* lsrc = SB + cidx * 2048 + (t & 31) * 64;
#pragma unroll
    for (int u = 0; u < 8; u++)
        *(short8*)(gdst + u * 8) = *(const short8*)(lsrc + u * 8);
}

// fc GEMM: 1D grid 256 with XCD swizzle (256 = 8*32): each XCD gets 4 m-rows x 8 n;
// its full wfc B working set (2MB) fits the 4MB XCD L2. out f32 += fc_b.
__global__ __launch_bounds__(256) void fc_gemm(
    const unsigned short* __restrict__ a, const unsigned short* __restrict__ wf,
    const float* __restrict__ bias, float* __restrict__ out) {
    __shared__ unsigned short As[2 * 4096], Bs[2 * 4096];
    const int lin = blockIdx.x;
    const int swz = (lin & 7) * 32 + (lin >> 3);
    const int m0 = (swz / 8) * 128, n0 = (swz % 8) * 128;
    f32x4 acc[4][4];
    gemm_mainloop(a, wf, m0, n0, acc, As, Bs);

    const int t = threadIdx.x, w = t >> 6, l = t & 63;
    const int wr = w >> 1, wc = w & 1, lr = l & 15, lg = l >> 4;
#pragma unroll
    for (int i = 0; i < 4; i++) {
#pragma unroll
        for (int j = 0; j < 4; j++) {
            const int n = n0 + wc * 64 + j * 16 + lr;
            const float bia = bias[n];
#pragma unroll
            for (int r = 0; r < 4; r++) {
                const int m = m0 + wr * 64 + i * 16 + lg * 4 + r;
                out[(size_t)m * 1024 + n] = acc[i][j][r] + bia;
            }
        }
    }
}

// ---- split-K flash attention with IN-BLOCK combine (R13-proven) + T5 setprio ----
__global__ __launch_bounds__(256) void attn(
    const unsigned short* __restrict__ q, const unsigned short* __restrict__ k,
    const unsigned short* __restrict__ vt, const unsigned int* __restrict__ mw,
    unsigned short* __restrict__ ao) {
    __shared__ float CL[4][2080];   // per wave: [64d x 32q | 32 l], 8320 B
    const int t = threadIdx.x, w = t >> 6;
    const int l = t & 63, c = l & 31, hi = l >> 5;
    const int bid = blockIdx.x;
    const int xcd = bid & 7, idx = bid >> 3;        // idx 0..127
    const int bh = xcd * 4 + (idx & 3);
    const int qpair = idx >> 2;                     // 0..31
    const int chunk = w & 1;                        // key chunk
    const int qb = qpair * 2 + (w >> 1);            // q-tile 0..63
    const int b = bh >> 4, h = bh & 15;
    const int kb0 = chunk * 32;

    // fragment-major bases; every load below is  ptr + lane*8 shorts (16B)
    const unsigned short* qfb = q + (size_t)bh * 131072 + qb * 2048 + l * 8;
    const unsigned short* kfb = k + (size_t)bh * 131072 + l * 8;
    const unsigned short* vfb = vt + (size_t)bh * 131072 + l * 8;

    short8 qf[4];
#pragma unroll
    for (int d = 0; d < 4; d++)
        qf[d] = *(const short8*)(qfb + d * 512);

    // ones A-operand for the row-sum MFMA (bf16 1.0 = 0x3F80)
    short8 ones;
#pragma unroll
    for (int i = 0; i < 8; i++) ones[i] = (short)0x3F80;

    // opaque zero C operand (loop-invariant; blocks per-iter zero re-materialization)
    float z = 0.f;
    asm volatile("" : "+v"(z));
    f32x16 FZ;
#pragma unroll
    for (int i = 0; i < 16; i++) FZ[i] = z;

    // preload first tile of this chunk
    short8 kf[4], vf[2][2];
#pragma unroll
    for (int d = 0; d < 4; d++) kf[d] = *(const short8*)(kfb + kb0 * 2048 + d * 512);
#pragma unroll
    for (int kc = 0; kc < 2; kc++) {
        vf[0][kc] = *(const short8*)(vfb + kb0 * 2048 + kc * 512);
        vf[1][kc] = *(const short8*)(vfb + kb0 * 2048 + 1024 + kc * 512);
    }
    unsigned int wd = mw[kb0 * 2048 + qb * 32 + c];

    f32x16 OT0, OT1, LS;
#pragma unroll
    for (int i = 0; i < 16; i++) { OT0[i] = 0.f; OT1[i] = 0.f; LS[i] = 0.f; }

#pragma unroll 2
    for (int kb = kb0; kb < kb0 + 32; kb++) {
        // QK^T (K in regs from prefetch); C = opaque zero
        __builtin_amdgcn_s_setprio(1);
        f32x16 S = mfma32(kf[0], qf[0], FZ);
#pragma unroll
        for (int d = 1; d < 4; d++) S = mfma32(kf[d], qf[d], S);
        __builtin_amdgcn_s_setprio(0);

        // prefetch tile kb+1 (tail prefetch reads adjacent ws buffers: safe, unused)
        short8 kn[4], vn[2][2];
        const unsigned short* kpn = kfb + (kb + 1) * 2048;
        const unsigned short* vpn = vfb + (kb + 1) * 2048;
#pragma unroll
        for (int d = 0; d < 4; d++) kn[d] = *(const short8*)(kpn + d * 512);
#pragma unroll
        for (int kc = 0; kc < 2; kc++) {
            vn[0][kc] = *(const short8*)(vpn + kc * 512);
            vn[1][kc] = *(const short8*)(vpn + 1024 + kc * 512);
        }
        const unsigned int wn = mw[(kb + 1) * 2048 + qb * 32 + c];

        // mask -> -1e9, then p = 2^s via raw v_exp_f32 (exp2(-1e9) = 0 exactly)
        const unsigned int wds = wd >> (4 * hi);
        float p[16];
#pragma unroll
        for (int g = 0; g < 4; g++)
#pragma unroll
            for (int u = 0; u < 4; u++)
                p[g * 4 + u] = (wds & (1u << (8 * g + u))) ? -1e9f : S[g * 4 + u];
#pragma unroll
        for (int i = 0; i < 16; i++) p[i] = fexp2(p[i]);

        // P -> bf16 A-frag: 8 cvt_pk + 4 permlane32_swap (T12)
        unsigned w8[8];
#pragma unroll
        for (int g = 0; g < 4; g++) {
            w8[2 * g]     = cvtpk(p[4 * g], p[4 * g + 1]);
            w8[2 * g + 1] = cvtpk(p[4 * g + 2], p[4 * g + 3]);
        }
        short8 pa[2];
#pragma unroll
        for (int kc = 0; kc < 2; kc++) {
            unsigned a0 = w8[4 * kc], a2 = w8[4 * kc + 2];
            plswap(a0, a2);
            unsigned a1 = w8[4 * kc + 1], a3 = w8[4 * kc + 3];
            plswap(a1, a3);
            uint4v tv; tv[0] = a0; tv[1] = a1; tv[2] = a2; tv[3] = a3;
            pa[kc] = __builtin_bit_cast(short8, tv);
        }

        // PV: O^T[d][q] += V^T * P ; row-sums on the MFMA pipe
        __builtin_amdgcn_s_setprio(1);
        OT0 = mfma32(vf[0][0], pa[0], OT0);
        OT0 = mfma32(vf[0][1], pa[1], OT0);
        OT1 = mfma32(vf[1][0], pa[0], OT1);
        OT1 = mfma32(vf[1][1], pa[1], OT1);
        LS  = mfma32(ones,     pa[0], LS);
        LS  = mfma32(ones,     pa[1], LS);
        __builtin_amdgcn_s_setprio(0);

#pragma unroll
        for (int d = 0; d < 4; d++) kf[d] = kn[d];
#pragma unroll
        for (int kc = 0; kc < 2; kc++) { vf[0][kc] = vn[0][kc]; vf[1][kc] = vn[1][kc]; }
        wd = wn;
    }

    // stash unnormalized O~^T [64][32] + per-q sum l into this wave's LDS region
    float* R = CL[w];
#pragma unroll
    for (int i = 0; i < 16; i++) {
        const int kr = (i & 3) + 8 * (i >> 2) + 4 * hi;
        R[kr * 32 + c]        = OT0[i];
        R[(32 + kr) * 32 + c] = OT1[i];
    }
    if (hi == 0) R[2048 + c] = LS[0];
    __syncthreads();

    // in-block combine: wave w -> q-tile (w>>1), d-half (w&1). lane: q = l>>1,
    // db = (l&1)*16 + (w&1)*32. O = (O~c0 + O~c1) / (l_c0 + l_c1), store bf16.
    const float* C0 = CL[(w >> 1) * 2];
    const float* C1 = CL[(w >> 1) * 2 + 1];
    const int qq = l >> 1, db = (l & 1) * 16 + (w & 1) * 32;
    const float inv = 1.0f / (C0[2048 + qq] + C1[2048 + qq]);
    const int row = b * 2048 + (qpair * 2 + (w >> 1)) * 32 + qq;
    unsigned short* gout = ao + (size_t)row * 1024 + h * 64 + db;
    uint4v pk0, pk1;
#pragma unroll
    for (int u = 0; u < 4; u++) {
        const int d0 = db + 2 * u, d1 = db + 8 + 2 * u;
        pk0[u] = cvtpk((C0[d0 * 32 + qq] + C1[d0 * 32 + qq]) * inv,
                       (C0[(d0 + 1) * 32 + qq] + C1[(d0 + 1) * 32 + qq]) * inv);
        pk1[u] = cvtpk((C0[d1 * 32 + qq] + C1[d1 * 32 + qq]) * inv,
                       (C0[(d1 + 1) * 32 + qq] + C1[(d1 + 1) * 32 + qq]) * inv);
    }
    *(uint4v*)(gout)     = pk0;
    *(uint4v*)(gout + 8) = pk1;
}

// ---------------- launcher ----------------
extern "C" void kernel_launch(void* const* d_in, const int* in_sizes, int n_in,
                              void* d_out, int out_size, void* d_ws, size_t ws_size,
                              hipStream_t stream) {
    const float* x     = (const float*)d_in[0];
    const int*   mask  = (const int*)d_in[1];
    const float* qkv_w = (const float*)d_in[2];
    const float* qkv_b = (const float*)d_in[3];
    const float* fc_w  = (const float*)d_in[4];
    const float* fc_b  = (const float*)d_in[5];
    float* out = (float*)d_out;

    char* ws = (char*)d_ws;
    size_t off = 0;
    auto alloc = [&](size_t bytes) {
        off = (off + 255) & ~(size_t)255;
        void* p = ws + off;
        off += bytes;
        return p;
    };
    float*          pe     = (float*)alloc(2 * 1024 * 4);
    unsigned int*   mwords = (unsigned int*)alloc((size_t)2048 * 64 * 4);
    unsigned short* xb     = (unsigned short*)alloc((size_t)4096 * 1024 * 2);
    unsigned short* wqkv   = (unsigned short*)alloc((size_t)3072 * 1024 * 2);
    unsigned short* wfc    = (unsigned short*)alloc((size_t)1024 * 1024 * 2);
    unsigned short* qb16   = (unsigned short*)alloc((size_t)2 * 16 * 2048 * 64 * 2);
    unsigned short* kb16   = (unsigned short*)alloc((size_t)2 * 16 * 2048 * 64 * 2);
    unsigned short* vtb    = (unsigned short*)alloc((size_t)2 * 16 * 64 * 2048 * 2);
    unsigned short* attn_o = (unsigned short*)alloc((size_t)4096 * 1024 * 2);

    pe_kernel<<<1, 512, 0, stream>>>(pe);
    cvt3<<<8192, 256, 0, stream>>>(x, qkv_w, fc_w, xb, wqkv, wfc);
    pack_mask<<<512, 256, 0, stream>>>(mask, mwords);
    qkv_gemm<<<dim3(768), 256, 0, stream>>>(xb, wqkv, qkv_b, pe, qb16, kb16, vtb);
    attn<<<dim3(1024), 256, 0, stream>>>(qb16, kb16, vtb, mwords, attn_o);
    fc_gemm<<<dim3(256), 256, 0, stream>>>(attn_o, wfc, fc_b, out);
}

// Round 19
// 143.324 us; speedup vs baseline: 1.2591x; 1.0047x over previous
//
#include <hip/hip_runtime.h>
#include <hip/hip_bf16.h>
#include <cstdint>

typedef __attribute__((ext_vector_type(8))) short short8;
typedef __attribute__((ext_vector_type(4))) float f32x4;
typedef __attribute__((ext_vector_type(16))) float f32x16;
typedef __attribute__((ext_vector_type(4))) unsigned uint4v;

#define DEV static __device__ __forceinline__

DEV f32x4 mfma16(short8 a, short8 b, f32x4 c) {
    return __builtin_amdgcn_mfma_f32_16x16x32_bf16(a, b, c, 0, 0, 0);
}
DEV f32x16 mfma32(short8 a, short8 b, f32x16 c) {
    return __builtin_amdgcn_mfma_f32_32x32x16_bf16(a, b, c, 0, 0, 0);
}

DEV unsigned short f2bf(float f) {
    __hip_bfloat16 h = __float2bfloat16(f);
    return __builtin_bit_cast(unsigned short, h);
}

// raw hardware exp2: 1 trans-pipe instruction (no libm range-check expansion).
DEV float fexp2(float x) {
#if __has_builtin(__builtin_amdgcn_exp2f)
    return __builtin_amdgcn_exp2f(x);
#else
    float r;
    asm("v_exp_f32 %0, %1" : "=v"(r) : "v"(x));
    return r;
#endif
}

// pack two f32 -> two bf16 in a u32 (lo = first arg), RNE
DEV unsigned cvtpk(float lo, float hi) {
    unsigned r;
    asm("v_cvt_pk_bf16_f32 %0, %1, %2" : "=v"(r) : "v"(lo), "v"(hi));
    return r;
}
// vdst_hi <-> vsrc_lo swap: after, a = {a_lo, b_lo}, b = {a_hi, b_hi}
DEV void plswap(unsigned& a, unsigned& b) {
    asm volatile("v_permlane32_swap_b32 %0, %1" : "+v"(a), "+v"(b));
}

// global -> LDS direct load, 16B per lane. Dest: wave-uniform base + lane*16.
#define GLOAD16(gp, lp)                                                        \
    __builtin_amdgcn_global_load_lds(                                          \
        (const __attribute__((address_space(1))) unsigned int*)(uintptr_t)(gp),\
        (__attribute__((address_space(3))) unsigned int*)(uintptr_t)(lp),      \
        16, 0, 0)

// ---------------- prep kernels ----------------

__global__ void pe_kernel(float* __restrict__ pe) {
    int i = threadIdx.x;
    if (i >= 512) return;
    float div = expf((float)(2 * i) * (-9.210340371976184f / 1024.0f));
    pe[2 * i]          = 0.0f;      // sin(0*div)
    pe[2 * i + 1]      = 1.0f;      // cos(0*div)
    pe[1024 + 2 * i]     = sinf(div);
    pe[1024 + 2 * i + 1] = cosf(div);
}

// fused f32->bf16 conversion of x, qkv_w, fc_w (one launch). 2097152 float4s total.
__global__ void cvt3(const float* __restrict__ x, const float* __restrict__ wq,
                     const float* __restrict__ wf, unsigned short* __restrict__ xb,
                     unsigned short* __restrict__ wqb, unsigned short* __restrict__ wfb) {
    int i = blockIdx.x * blockDim.x + threadIdx.x;   // 0..2097151
    const float* src; unsigned short* dst; int off;
    if (i < 1048576)      { src = x;  dst = xb;  off = i; }
    else if (i < 1835008) { src = wq; dst = wqb; off = i - 1048576; }
    else                  { src = wf; dst = wfb; off = i - 1835008; }
    float4 v = ((const float4*)src)[off];
    ushort4 o;
    o.x = f2bf(v.x); o.y = f2bf(v.y); o.z = f2bf(v.z); o.w = f2bf(v.w);
    ((ushort4*)dst)[off] = o;
}

// mask [2048,2048] int32 (0/1) -> TRANSPOSED bit-words wT[kb][row] (kb 0..63, row 0..2047)
__global__ void pack_mask(const int* __restrict__ mask, unsigned int* __restrict__ wT) {
    int o = blockIdx.x * blockDim.x + threadIdx.x;   // 0..131071
    int kb = o >> 11, row = o & 2047;
    const int4* m4 = (const int4*)(mask + (size_t)row * 2048 + kb * 32);
    unsigned int bits = 0;
#pragma unroll
    for (int j = 0; j < 8; j++) {
        int4 v = m4[j];
        bits |= (unsigned)(v.x & 1) << (4 * j);
        bits |= (unsigned)(v.y & 1) << (4 * j + 1);
        bits |= (unsigned)(v.z & 1) << (4 * j + 2);
        bits |= (unsigned)(v.w & 1) << (4 * j + 3);
    }
    wT[o] = bits;
}

// ------- GEMM mainloop: 128x128 tile, BK=32, double-buffered LDS, swizzled reads -------
// (R15-proven.) Pre-swizzled SOURCE chunk + linear LDS dest; reads XOR the chunk slot.
DEV void gemm_mainloop(const unsigned short* __restrict__ A,
                       const unsigned short* __restrict__ Bm,
                       int m0, int n0, f32x4 (&acc)[4][4],
                       unsigned short* As, unsigned short* Bs) {   // each [2*4096]
    const int t = threadIdx.x;
    const int w = t >> 6;
    const int l = t & 63, lr = l & 15, lg = l >> 4;
    const int wr = w >> 1, wc = w & 1;
    const int srow = t >> 2;
    const int scg = ((t & 3) ^ ((t >> 3) & 3)) * 8;   // pre-swizzled source chunk
#pragma unroll
    for (int i = 0; i < 4; i++)
#pragma unroll
        for (int j = 0; j < 4; j++) acc[i][j] = f32x4{0.f, 0.f, 0.f, 0.f};

    const unsigned short* Ap = A + (size_t)(m0 + srow) * 1024 + scg;
    const unsigned short* Bp = Bm + (size_t)(n0 + srow) * 1024 + scg;
    unsigned short* dA = As + w * 512;
    unsigned short* dB = Bs + w * 512;

    // swizzled read bases (loop-invariant): slot = lg ^ ((lr>>1)&3)
    const int slot = (lg ^ ((lr >> 1) & 3)) * 8;
    const unsigned short* Ar = As + (wr * 64 + lr) * 32 + slot;
    const unsigned short* Br = Bs + (wc * 64 + lr) * 32 + slot;

#define STAGE(buf, k0)                                                \
    {                                                                 \
        GLOAD16(Ap + (k0), dA + (buf) * 4096);                        \
        GLOAD16(Ap + 64 * 1024 + (k0), dA + (buf) * 4096 + 2048);     \
        GLOAD16(Bp + (k0), dB + (buf) * 4096);                        \
        GLOAD16(Bp + 64 * 1024 + (k0), dB + (buf) * 4096 + 2048);     \
    }

    STAGE(0, 0);
#pragma unroll 2
    for (int k0 = 0; k0 < 1024; k0 += 32) {
        const int cur = (k0 >> 5) & 1;
        __syncthreads();                      // drains vmcnt: buf[cur] ready; prev reads done
        if (k0 + 32 < 1024) STAGE(cur ^ 1, k0 + 32);
        short8 af[4], bfr[4];
#pragma unroll
        for (int i = 0; i < 4; i++)
            af[i] = *(const short8*)(Ar + cur * 4096 + i * 512);
#pragma unroll
        for (int j = 0; j < 4; j++)
            bfr[j] = *(const short8*)(Br + cur * 4096 + j * 512);
#pragma unroll
        for (int i = 0; i < 4; i++)
#pragma unroll
            for (int j = 0; j < 4; j++)
                acc[i][j] = mfma16(af[i], bfr[j], acc[i][j]);
    }
#undef STAGE
}

// qkv GEMM: 1D grid 768 with XCD-aware swizzle (T1; 768 = 8*96, bijective): each XCD
// gets 96 contiguous logical blocks = 4 m-rows x 24 n -- A panels become XCD-L2-local.
// Epilogue +bias, +pe (q,k), q *= 1/8*log2e; outputs in FRAGMENT-MAJOR layouts via LDS
// (8 complete 4KB fragment chunks), then 8 coalesced dwordx4 stores/thread.
__global__ __launch_bounds__(256) void qkv_gemm(
    const unsigned short* __restrict__ x, const unsigned short* __restrict__ wq,
    const float* __restrict__ bias, const float* __restrict__ pe,
    unsigned short* __restrict__ qo, unsigned short* __restrict__ ko,
    unsigned short* __restrict__ vt) {
    __shared__ unsigned short SB[16384];      // mainloop: As|Bs ; epilogue: 8x2048 chunks
    const int lin = blockIdx.x;
    const int swz = (lin & 7) * 96 + (lin >> 3);
    const int m0 = (swz / 24) * 128, n0 = (swz % 24) * 128;
    f32x4 acc[4][4];
    gemm_mainloop(x, wq, m0, n0, acc, SB, SB + 8192);

    const int t = threadIdx.x, w = t >> 6, l = t & 63;
    const int wr = w >> 1, wc = w & 1, lr = l & 15, lg = l >> 4;
    const int part = n0 >> 10;                // uniform per block (1024 % 128 == 0)
    const int h0 = (n0 & 1023) >> 6;
    const int b  = m0 >> 11;

    __syncthreads();   // all waves done with SB (mainloop) before overwrite
#pragma unroll
    for (int i = 0; i < 4; i++) {
#pragma unroll
        for (int j = 0; j < 4; j++) {
            const int n = n0 + wc * 64 + j * 16 + lr;
            const int d = n & 1023, hd = d & 63;
            const int h_loc = (d >> 6) & 1;
            const float bia = bias[n];
            const float pv = (part < 2) ? pe[b * 1024 + d] : 0.f;
#pragma unroll
            for (int r = 0; r < 4; r++) {
                const int m = m0 + wr * 64 + i * 16 + lg * 4 + r;
                const int s = m & 2047, s5 = s & 31, t_loc = (s >> 5) & 3;
                float v = acc[i][j][r] + bia;
                int inner;
                if (part == 2) {
                    inner = (hd >> 5) * 1024 + ((s5 >> 4) & 1) * 512 +
                            (((s5 >> 3) & 1) * 32 + (hd & 31)) * 8 + (s5 & 7);
                } else {
                    v += pv;
                    if (part == 0) v *= 0.1803368801111204f;   // 1/8 * log2(e)
                    inner = (hd >> 4) * 512 + (((hd >> 3) & 1) * 32 + s5) * 8 + (hd & 7);
                }
                SB[(t_loc * 2 + h_loc) * 2048 + inner] = f2bf(v);
            }
        }
    }
    __syncthreads();

    // linear copy: chunk cidx = t>>5 -> global fragment tile (t_g, h0 + (cidx&1));
    // t_g is the PER-BATCH s-tile: ((m0 & 2047) >> 5) + (cidx >> 1).
    unsigned short* dst0 = (part == 0) ? qo : (part == 1) ? ko : vt;
    const int cidx = t >> 5;
    const int t_g = ((m0 & 2047) >> 5) + (cidx >> 1);
    const int bh = b * 16 + h0 + (cidx & 1);
    unsigned short* gdst = dst0 + (size_t)bh * 131072 + t_g * 2048 + (t & 31) * 64;
    const unsigned short* lsrc = SB + cidx * 2048 + (t & 31) * 64;
#pragma unroll
    for (int u = 0; u < 8; u++)
        *(short8*)(gdst + u * 8) = *(const short8*)(lsrc + u * 8);
}

// fc GEMM: 1D grid 256 with XCD swizzle (256 = 8*32): each XCD gets 4 m-rows x 8 n;
// its full wfc B working set (2MB) fits the 4MB XCD L2. out f32 += fc_b.
__global__ __launch_bounds__(256) void fc_gemm(
    const unsigned short* __restrict__ a, const unsigned short* __restrict__ wf,
    const float* __restrict__ bias, float* __restrict__ out) {
    __shared__ unsigned short As[2 * 4096], Bs[2 * 4096];
    const int lin = blockIdx.x;
    const int swz = (lin & 7) * 32 + (lin >> 3);
    const int m0 = (swz / 8) * 128, n0 = (swz % 8) * 128;
    f32x4 acc[4][4];
    gemm_mainloop(a, wf, m0, n0, acc, As, Bs);

    const int t = threadIdx.x, w = t >> 6, l = t & 63;
    const int wr = w >> 1, wc = w & 1, lr = l & 15, lg = l >> 4;
#pragma unroll
    for (int i = 0; i < 4; i++) {
#pragma unroll
        for (int j = 0; j < 4; j++) {
            const int n = n0 + wc * 64 + j * 16 + lr;
            const float bia = bias[n];
#pragma unroll
            for (int r = 0; r < 4; r++) {
                const int m = m0 + wr * 64 + i * 16 + lg * 4 + r;
                out[(size_t)m * 1024 + n] = acc[i][j][r] + bia;
            }
        }
    }
}

// ---- split-K flash attention, REG-DIET: no register prefetch (loads at use; XCD-L2
// resident + 3 waves/SIMD hide latency), f32 row-sum (R11-proven) instead of LS MFMA.
// Frees ~56 regs/wave (prefetch doubles + LS + ones) -> target 3 waves/SIMD.
// In-block combine (R13-proven) + T5 setprio. Grid 1024 x 256thr.
__global__ __launch_bounds__(256) void attn(
    const unsigned short* __restrict__ q, const unsigned short* __restrict__ k,
    const unsigned short* __restrict__ vt, const unsigned int* __restrict__ mw,
    unsigned short* __restrict__ ao) {
    __shared__ float CL[4][2080];   // per wave: [64d x 32q | 32 l], 8320 B
    const int t = threadIdx.x, w = t >> 6;
    const int l = t & 63, c = l & 31, hi = l >> 5;
    const int bid = blockIdx.x;
    const int xcd = bid & 7, idx = bid >> 3;        // idx 0..127
    const int bh = xcd * 4 + (idx & 3);
    const int qpair = idx >> 2;                     // 0..31
    const int chunk = w & 1;                        // key chunk
    const int qb = qpair * 2 + (w >> 1);            // q-tile 0..63
    const int b = bh >> 4, h = bh & 15;
    const int kb0 = chunk * 32;

    // fragment-major bases; every load below is  ptr + lane*8 shorts (16B)
    const unsigned short* qfb = q + (size_t)bh * 131072 + qb * 2048 + l * 8;
    const unsigned short* kfb = k + (size_t)bh * 131072 + l * 8;
    const unsigned short* vfb = vt + (size_t)bh * 131072 + l * 8;

    short8 qf[4];
#pragma unroll
    for (int d = 0; d < 4; d++)
        qf[d] = *(const short8*)(qfb + d * 512);

    // opaque zero C operand (loop-invariant; blocks per-iter zero re-materialization)
    float z = 0.f;
    asm volatile("" : "+v"(z));
    f32x16 FZ;
#pragma unroll
    for (int i = 0; i < 16; i++) FZ[i] = z;

    f32x16 OT0, OT1;
#pragma unroll
    for (int i = 0; i < 16; i++) { OT0[i] = 0.f; OT1[i] = 0.f; }
    float lrow = 0.f;

#pragma unroll 2
    for (int kb = kb0; kb < kb0 + 32; kb++) {
        // loads at use (no reg prefetch): K frags, V frags, mask word
        const unsigned short* kp = kfb + kb * 2048;
        const unsigned short* vp = vfb + kb * 2048;
        short8 kf[4], vf[2][2];
#pragma unroll
        for (int d = 0; d < 4; d++) kf[d] = *(const short8*)(kp + d * 512);
#pragma unroll
        for (int kc = 0; kc < 2; kc++) {
            vf[0][kc] = *(const short8*)(vp + kc * 512);
            vf[1][kc] = *(const short8*)(vp + 1024 + kc * 512);
        }
        const unsigned int wd = mw[kb * 2048 + qb * 32 + c];

        // QK^T; C = opaque zero
        __builtin_amdgcn_s_setprio(1);
        f32x16 S = mfma32(kf[0], qf[0], FZ);
#pragma unroll
        for (int d = 1; d < 4; d++) S = mfma32(kf[d], qf[d], S);
        __builtin_amdgcn_s_setprio(0);

        // mask -> -1e9, then p = 2^s via raw v_exp_f32 (exp2(-1e9) = 0 exactly)
        const unsigned int wds = wd >> (4 * hi);
        float p[16];
#pragma unroll
        for (int g = 0; g < 4; g++)
#pragma unroll
            for (int u = 0; u < 4; u++)
                p[g * 4 + u] = (wds & (1u << (8 * g + u))) ? -1e9f : S[g * 4 + u];
#pragma unroll
        for (int i = 0; i < 16; i++) p[i] = fexp2(p[i]);

        // f32 row-sum (R11-proven): in-lane tree + shfl_xor(32)
        float rs = (((p[0] + p[1]) + (p[2] + p[3])) + ((p[4] + p[5]) + (p[6] + p[7]))) +
                   (((p[8] + p[9]) + (p[10] + p[11])) + ((p[12] + p[13]) + (p[14] + p[15])));
        rs += __shfl_xor(rs, 32);
        lrow += rs;

        // P -> bf16 A-frag: 8 cvt_pk + 4 permlane32_swap (T12)
        unsigned w8[8];
#pragma unroll
        for (int g = 0; g < 4; g++) {
            w8[2 * g]     = cvtpk(p[4 * g], p[4 * g + 1]);
            w8[2 * g + 1] = cvtpk(p[4 * g + 2], p[4 * g + 3]);
        }
        short8 pa[2];
#pragma unroll
        for (int kc = 0; kc < 2; kc++) {
            unsigned a0 = w8[4 * kc], a2 = w8[4 * kc + 2];
            plswap(a0, a2);
            unsigned a1 = w8[4 * kc + 1], a3 = w8[4 * kc + 3];
            plswap(a1, a3);
            uint4v tv; tv[0] = a0; tv[1] = a1; tv[2] = a2; tv[3] = a3;
            pa[kc] = __builtin_bit_cast(short8, tv);
        }

        // PV: O^T[d][q] += V^T * P
        __builtin_amdgcn_s_setprio(1);
        OT0 = mfma32(vf[0][0], pa[0], OT0);
        OT0 = mfma32(vf[0][1], pa[1], OT0);
        OT1 = mfma32(vf[1][0], pa[0], OT1);
        OT1 = mfma32(vf[1][1], pa[1], OT1);
        __builtin_amdgcn_s_setprio(0);
    }

    // stash unnormalized O~^T [64][32] + per-q sum l into this wave's LDS region
    float* R = CL[w];
#pragma unroll
    for (int i = 0; i < 16; i++) {
        const int kr = (i & 3) + 8 * (i >> 2) + 4 * hi;
        R[kr * 32 + c]        = OT0[i];
        R[(32 + kr) * 32 + c] = OT1[i];
    }
    if (hi == 0) R[2048 + c] = lrow;
    __syncthreads();

    // in-block combine: wave w -> q-tile (w>>1), d-half (w&1). lane: q = l>>1,
    // db = (l&1)*16 + (w&1)*32. O = (O~c0 + O~c1) / (l_c0 + l_c1), store bf16.
    const float* C0 = CL[(w >> 1) * 2];
    const float* C1 = CL[(w >> 1) * 2 + 1];
    const int qq = l >> 1, db = (l & 1) * 16 + (w & 1) * 32;
    const float inv = 1.0f / (C0[2048 + qq] + C1[2048 + qq]);
    const int row = b * 2048 + (qpair * 2 + (w >> 1)) * 32 + qq;
    unsigned short* gout = ao + (size_t)row * 1024 + h * 64 + db;
    uint4v pk0, pk1;
#pragma unroll
    for (int u = 0; u < 4; u++) {
        const int d0 = db + 2 * u, d1 = db + 8 + 2 * u;
        pk0[u] = cvtpk((C0[d0 * 32 + qq] + C1[d0 * 32 + qq]) * inv,
                       (C0[(d0 + 1) * 32 + qq] + C1[(d0 + 1) * 32 + qq]) * inv);
        pk1[u] = cvtpk((C0[d1 * 32 + qq] + C1[d1 * 32 + qq]) * inv,
                       (C0[(d1 + 1) * 32 + qq] + C1[(d1 + 1) * 32 + qq]) * inv);
    }
    *(uint4v*)(gout)     = pk0;
    *(uint4v*)(gout + 8) = pk1;
}

// ---------------- launcher ----------------
extern "C" void kernel_launch(void* const* d_in, const int* in_sizes, int n_in,
                              void* d_out, int out_size, void* d_ws, size_t ws_size,
                              hipStream_t stream) {
    const float* x     = (const float*)d_in[0];
    const int*   mask  = (const int*)d_in[1];
    const float* qkv_w = (const float*)d_in[2];
    const float* qkv_b = (const float*)d_in[3];
    const float* fc_w  = (const float*)d_in[4];
    const float* fc_b  = (const float*)d_in[5];
    float* out = (float*)d_out;

    char* ws = (char*)d_ws;
    size_t off = 0;
    auto alloc = [&](size_t bytes) {
        off = (off + 255) & ~(size_t)255;
        void* p = ws + off;
        off += bytes;
        return p;
    };
    float*          pe     = (float*)alloc(2 * 1024 * 4);
    unsigned int*   mwords = (unsigned int*)alloc((size_t)2048 * 64 * 4);
    unsigned short* xb     = (unsigned short*)alloc((size_t)4096 * 1024 * 2);
    unsigned short* wqkv   = (unsigned short*)alloc((size_t)3072 * 1024 * 2);
    unsigned short* wfc    = (unsigned short*)alloc((size_t)1024 * 1024 * 2);
    unsigned short* qb16   = (unsigned short*)alloc((size_t)2 * 16 * 2048 * 64 * 2);
    unsigned short* kb16   = (unsigned short*)alloc((size_t)2 * 16 * 2048 * 64 * 2);
    unsigned short* vtb    = (unsigned short*)alloc((size_t)2 * 16 * 64 * 2048 * 2);
    unsigned short* attn_o = (unsigned short*)alloc((size_t)4096 * 1024 * 2);

    pe_kernel<<<1, 512, 0, stream>>>(pe);
    cvt3<<<8192, 256, 0, stream>>>(x, qkv_w, fc_w, xb, wqkv, wfc);
    pack_mask<<<512, 256, 0, stream>>>(mask, mwords);
    qkv_gemm<<<dim3(768), 256, 0, stream>>>(xb, wqkv, qkv_b, pe, qb16, kb16, vtb);
    attn<<<dim3(1024), 256, 0, stream>>>(qb16, kb16, vtb, mwords, attn_o);
    fc_gemm<<<dim3(256), 256, 0, stream>>>(attn_o, wfc, fc_b, out);
}

// Round 21
// 142.340 us; speedup vs baseline: 1.2679x; 1.0069x over previous
//
#include <hip/hip_runtime.h>
#include <hip/hip_bf16.h>
#include <cstdint>

typedef __attribute__((ext_vector_type(8))) short short8;
typedef __attribute__((ext_vector_type(4))) float f32x4;
typedef __attribute__((ext_vector_type(16))) float f32x16;
typedef __attribute__((ext_vector_type(4))) unsigned uint4v;

#define DEV static __device__ __forceinline__

DEV f32x4 mfma16(short8 a, short8 b, f32x4 c) {
    return __builtin_amdgcn_mfma_f32_16x16x32_bf16(a, b, c, 0, 0, 0);
}
DEV f32x16 mfma32(short8 a, short8 b, f32x16 c) {
    return __builtin_amdgcn_mfma_f32_32x32x16_bf16(a, b, c, 0, 0, 0);
}

DEV unsigned short f2bf(float f) {
    __hip_bfloat16 h = __float2bfloat16(f);
    return __builtin_bit_cast(unsigned short, h);
}

// raw hardware exp2: 1 trans-pipe instruction (no libm range-check expansion).
DEV float fexp2(float x) {
#if __has_builtin(__builtin_amdgcn_exp2f)
    return __builtin_amdgcn_exp2f(x);
#else
    float r;
    asm("v_exp_f32 %0, %1" : "=v"(r) : "v"(x));
    return r;
#endif
}

// pack two f32 -> two bf16 in a u32 (lo = first arg), RNE
DEV unsigned cvtpk(float lo, float hi) {
    unsigned r;
    asm("v_cvt_pk_bf16_f32 %0, %1, %2" : "=v"(r) : "v"(lo), "v"(hi));
    return r;
}
// vdst_hi <-> vsrc_lo swap: after, a = {a_lo, b_lo}, b = {a_hi, b_hi}
DEV void plswap(unsigned& a, unsigned& b) {
    asm volatile("v_permlane32_swap_b32 %0, %1" : "+v"(a), "+v"(b));
}

// global -> LDS direct load, 16B per lane. Dest: wave-uniform base + lane*16.
#define GLOAD16(gp, lp)                                                        \
    __builtin_amdgcn_global_load_lds(                                          \
        (const __attribute__((address_space(1))) unsigned int*)(uintptr_t)(gp),\
        (__attribute__((address_space(3))) unsigned int*)(uintptr_t)(lp),      \
        16, 0, 0)

// ---------------- fused prep kernel (one launch, block-range dispatch) ----------------
// blocks [0, 8192):  f32->bf16 convert of x | qkv_w | fc_w   (cvt3 body)
// blocks [8192, 8704): mask -> transposed bit-words wT[kb][row] (pack_mask body)
// block  8704:        sinusoidal pe table -- 256 threads cover 512 entries (R21 fix:
//                     R20 used i=threadIdx.x only, leaving pe[512..] poisoned).
__global__ void prep(const float* __restrict__ x, const float* __restrict__ wq,
                     const float* __restrict__ wf, const int* __restrict__ mask,
                     unsigned short* __restrict__ xb, unsigned short* __restrict__ wqb,
                     unsigned short* __restrict__ wfb, unsigned int* __restrict__ wT,
                     float* __restrict__ pe) {
    const int bid = blockIdx.x;
    if (bid < 8192) {
        int i = bid * 256 + threadIdx.x;             // 0..2097151
        const float* src; unsigned short* dst; int off;
        if (i < 1048576)      { src = x;  dst = xb;  off = i; }
        else if (i < 1835008) { src = wq; dst = wqb; off = i - 1048576; }
        else                  { src = wf; dst = wfb; off = i - 1835008; }
        float4 v = ((const float4*)src)[off];
        ushort4 o;
        o.x = f2bf(v.x); o.y = f2bf(v.y); o.z = f2bf(v.z); o.w = f2bf(v.w);
        ((ushort4*)dst)[off] = o;
    } else if (bid < 8704) {
        int o = (bid - 8192) * 256 + threadIdx.x;    // 0..131071
        int kb = o >> 11, row = o & 2047;
        const int4* m4 = (const int4*)(mask + (size_t)row * 2048 + kb * 32);
        unsigned int bits = 0;
#pragma unroll
        for (int j = 0; j < 8; j++) {
            int4 v = m4[j];
            bits |= (unsigned)(v.x & 1) << (4 * j);
            bits |= (unsigned)(v.y & 1) << (4 * j + 1);
            bits |= (unsigned)(v.z & 1) << (4 * j + 2);
            bits |= (unsigned)(v.w & 1) << (4 * j + 3);
        }
        wT[o] = bits;
    } else {
        for (int i = threadIdx.x; i < 512; i += 256) {
            float div = expf((float)(2 * i) * (-9.210340371976184f / 1024.0f));
            pe[2 * i]          = 0.0f;      // sin(0*div)
            pe[2 * i + 1]      = 1.0f;      // cos(0*div)
            pe[1024 + 2 * i]     = sinf(div);
            pe[1024 + 2 * i + 1] = cosf(div);
        }
    }
}

// ------- GEMM mainloop: 128x128 tile, BK=32, double-buffered LDS, swizzled reads -------
// (R15-proven.) Pre-swizzled SOURCE chunk + linear LDS dest; reads XOR the chunk slot.
DEV void gemm_mainloop(const unsigned short* __restrict__ A,
                       const unsigned short* __restrict__ Bm,
                       int m0, int n0, f32x4 (&acc)[4][4],
                       unsigned short* As, unsigned short* Bs) {   // each [2*4096]
    const int t = threadIdx.x;
    const int w = t >> 6;
    const int l = t & 63, lr = l & 15, lg = l >> 4;
    const int wr = w >> 1, wc = w & 1;
    const int srow = t >> 2;
    const int scg = ((t & 3) ^ ((t >> 3) & 3)) * 8;   // pre-swizzled source chunk
#pragma unroll
    for (int i = 0; i < 4; i++)
#pragma unroll
        for (int j = 0; j < 4; j++) acc[i][j] = f32x4{0.f, 0.f, 0.f, 0.f};

    const unsigned short* Ap = A + (size_t)(m0 + srow) * 1024 + scg;
    const unsigned short* Bp = Bm + (size_t)(n0 + srow) * 1024 + scg;
    unsigned short* dA = As + w * 512;
    unsigned short* dB = Bs + w * 512;

    // swizzled read bases (loop-invariant): slot = lg ^ ((lr>>1)&3)
    const int slot = (lg ^ ((lr >> 1) & 3)) * 8;
    const unsigned short* Ar = As + (wr * 64 + lr) * 32 + slot;
    const unsigned short* Br = Bs + (wc * 64 + lr) * 32 + slot;

#define STAGE(buf, k0)                                                \
    {                                                                 \
        GLOAD16(Ap + (k0), dA + (buf) * 4096);                        \
        GLOAD16(Ap + 64 * 1024 + (k0), dA + (buf) * 4096 + 2048);     \
        GLOAD16(Bp + (k0), dB + (buf) * 4096);                        \
        GLOAD16(Bp + 64 * 1024 + (k0), dB + (buf) * 4096 + 2048);     \
    }

    STAGE(0, 0);
#pragma unroll 2
    for (int k0 = 0; k0 < 1024; k0 += 32) {
        const int cur = (k0 >> 5) & 1;
        __syncthreads();                      // drains vmcnt: buf[cur] ready; prev reads done
        if (k0 + 32 < 1024) STAGE(cur ^ 1, k0 + 32);
        short8 af[4], bfr[4];
#pragma unroll
        for (int i = 0; i < 4; i++)
            af[i] = *(const short8*)(Ar + cur * 4096 + i * 512);
#pragma unroll
        for (int j = 0; j < 4; j++)
            bfr[j] = *(const short8*)(Br + cur * 4096 + j * 512);
#pragma unroll
        for (int i = 0; i < 4; i++)
#pragma unroll
            for (int j = 0; j < 4; j++)
                acc[i][j] = mfma16(af[i], bfr[j], acc[i][j]);
    }
#undef STAGE
}

// qkv GEMM: 1D grid 768 with XCD-aware swizzle (T1; 768 = 8*96, bijective): each XCD
// gets 96 contiguous logical blocks = 4 m-rows x 24 n -- A panels become XCD-L2-local.
// Epilogue +bias, +pe (q,k), q *= 1/8*log2e; outputs in FRAGMENT-MAJOR layouts via LDS
// (8 complete 4KB fragment chunks), then 8 coalesced dwordx4 stores/thread.
__global__ __launch_bounds__(256) void qkv_gemm(
    const unsigned short* __restrict__ x, const unsigned short* __restrict__ wq,
    const float* __restrict__ bias, const float* __restrict__ pe,
    unsigned short* __restrict__ qo, unsigned short* __restrict__ ko,
    unsigned short* __restrict__ vt) {
    __shared__ unsigned short SB[16384];      // mainloop: As|Bs ; epilogue: 8x2048 chunks
    const int lin = blockIdx.x;
    const int swz = (lin & 7) * 96 + (lin >> 3);
    const int m0 = (swz / 24) * 128, n0 = (swz % 24) * 128;
    f32x4 acc[4][4];
    gemm_mainloop(x, wq, m0, n0, acc, SB, SB + 8192);

    const int t = threadIdx.x, w = t >> 6, l = t & 63;
    const int wr = w >> 1, wc = w & 1, lr = l & 15, lg = l >> 4;
    const int part = n0 >> 10;                // uniform per block (1024 % 128 == 0)
    const int h0 = (n0 & 1023) >> 6;
    const int b  = m0 >> 11;

    __syncthreads();   // all waves done with SB (mainloop) before overwrite
#pragma unroll
    for (int i = 0; i < 4; i++) {
#pragma unroll
        for (int j = 0; j < 4; j++) {
            const int n = n0 + wc * 64 + j * 16 + lr;
            const int d = n & 1023, hd = d & 63;
            const int h_loc = (d >> 6) & 1;
            const float bia = bias[n];
            const float pv = (part < 2) ? pe[b * 1024 + d] : 0.f;
#pragma unroll
            for (int r = 0; r < 4; r++) {
                const int m = m0 + wr * 64 + i * 16 + lg * 4 + r;
                const int s = m & 2047, s5 = s & 31, t_loc = (s >> 5) & 3;
                float v = acc[i][j][r] + bia;
                int inner;
                if (part == 2) {
                    inner = (hd >> 5) * 1024 + ((s5 >> 4) & 1) * 512 +
                            (((s5 >> 3) & 1) * 32 + (hd & 31)) * 8 + (s5 & 7);
                } else {
                    v += pv;
                    if (part == 0) v *= 0.1803368801111204f;   // 1/8 * log2(e)
                    inner = (hd >> 4) * 512 + (((hd >> 3) & 1) * 32 + s5) * 8 + (hd & 7);
                }
                SB[(t_loc * 2 + h_loc) * 2048 + inner] = f2bf(v);
            }
        }
    }
    __syncthreads();

    // linear copy: chunk cidx = t>>5 -> global fragment tile (t_g, h0 + (cidx&1));
    // t_g is the PER-BATCH s-tile: ((m0 & 2047) >> 5) + (cidx >> 1).
    unsigned short* dst0 = (part == 0) ? qo : (part == 1) ? ko : vt;
    const int cidx = t >> 5;
    const int t_g = ((m0 & 2047) >> 5) + (cidx >> 1);
    const int bh = b * 16 + h0 + (cidx & 1);
    unsigned short* gdst = dst0 + (size_t)bh * 131072 + t_g * 2048 + (t & 31) * 64;
    const unsigned short* lsrc = SB + cidx * 2048 + (t & 31) * 64;
#pragma unroll
    for (int u = 0; u < 8; u++)
        *(short8*)(gdst + u * 8) = *(const short8*)(lsrc + u * 8);
}

// fc GEMM: 1D grid 256 with XCD swizzle (256 = 8*32): each XCD gets 4 m-rows x 8 n;
// its full wfc B working set (2MB) fits the 4MB XCD L2. out f32 += fc_b.
__global__ __launch_bounds__(256) void fc_gemm(
    const unsigned short* __restrict__ a, const unsigned short* __restrict__ wf,
    const float* __restrict__ bias, float* __restrict__ out) {
    __shared__ unsigned short As[2 * 4096], Bs[2 * 4096];
    const int lin = blockIdx.x;
    const int swz = (lin & 7) * 32 + (lin >> 3);
    const int m0 = (swz / 8) * 128, n0 = (swz % 8) * 128;
    f32x4 acc[4][4];
    gemm_mainloop(a, wf, m0, n0, acc, As, Bs);

    const int t = threadIdx.x, w = t >> 6, l = t & 63;
    const int wr = w >> 1, wc = w & 1, lr = l & 15, lg = l >> 4;
#pragma unroll
    for (int i = 0; i < 4; i++) {
#pragma unroll
        for (int j = 0; j < 4; j++) {
            const int n = n0 + wc * 64 + j * 16 + lr;
            const float bia = bias[n];
#pragma unroll
            for (int r = 0; r < 4; r++) {
                const int m = m0 + wr * 64 + i * 16 + lg * 4 + r;
                out[(size_t)m * 1024 + n] = acc[i][j][r] + bia;
            }
        }
    }
}

// ---- split-K flash attention (R19-proven): reg-diet, loads at use, f32 row-sum,
// in-block combine, T5 setprio. Grid 1024 x 256thr.
__global__ __launch_bounds__(256) void attn(
    const unsigned short* __restrict__ q, const unsigned short* __restrict__ k,
    const unsigned short* __restrict__ vt, const unsigned int* __restrict__ mw,
    unsigned short* __restrict__ ao) {
    __shared__ float CL[4][2080];   // per wave: [64d x 32q | 32 l], 8320 B
    const int t = threadIdx.x, w = t >> 6;
    const int l = t & 63, c = l & 31, hi = l >> 5;
    const int bid = blockIdx.x;
    const int xcd = bid & 7, idx = bid >> 3;        // idx 0..127
    const int bh = xcd * 4 + (idx & 3);
    const int qpair = idx >> 2;                     // 0..31
    const int chunk = w & 1;                        // key chunk
    const int qb = qpair * 2 + (w >> 1);            // q-tile 0..63
    const int b = bh >> 4, h = bh & 15;
    const int kb0 = chunk * 32;

    // fragment-major bases; every load below is  ptr + lane*8 shorts (16B)
    const unsigned short* qfb = q + (size_t)bh * 131072 + qb * 2048 + l * 8;
    const unsigned short* kfb = k + (size_t)bh * 131072 + l * 8;
    const unsigned short* vfb = vt + (size_t)bh * 131072 + l * 8;

    short8 qf[4];
#pragma unroll
    for (int d = 0; d < 4; d++)
        qf[d] = *(const short8*)(qfb + d * 512);

    // opaque zero C operand (loop-invariant; blocks per-iter zero re-materialization)
    float z = 0.f;
    asm volatile("" : "+v"(z));
    f32x16 FZ;
#pragma unroll
    for (int i = 0; i < 16; i++) FZ[i] = z;

    f32x16 OT0, OT1;
#pragma unroll
    for (int i = 0; i < 16; i++) { OT0[i] = 0.f; OT1[i] = 0.f; }
    float lrow = 0.f;

#pragma unroll 2
    for (int kb = kb0; kb < kb0 + 32; kb++) {
        // loads at use (no reg prefetch): K frags, V frags, mask word
        const unsigned short* kp = kfb + kb * 2048;
        const unsigned short* vp = vfb + kb * 2048;
        short8 kf[4], vf[2][2];
#pragma unroll
        for (int d = 0; d < 4; d++) kf[d] = *(const short8*)(kp + d * 512);
#pragma unroll
        for (int kc = 0; kc < 2; kc++) {
            vf[0][kc] = *(const short8*)(vp + kc * 512);
            vf[1][kc] = *(const short8*)(vp + 1024 + kc * 512);
        }
        const unsigned int wd = mw[kb * 2048 + qb * 32 + c];

        // QK^T; C = opaque zero
        __builtin_amdgcn_s_setprio(1);
        f32x16 S = mfma32(kf[0], qf[0], FZ);
#pragma unroll
        for (int d = 1; d < 4; d++) S = mfma32(kf[d], qf[d], S);
        __builtin_amdgcn_s_setprio(0);

        // mask -> -1e9, then p = 2^s via raw v_exp_f32 (exp2(-1e9) = 0 exactly)
        const unsigned int wds = wd >> (4 * hi);
        float p[16];
#pragma unroll
        for (int g = 0; g < 4; g++)
#pragma unroll
            for (int u = 0; u < 4; u++)
                p[g * 4 + u] = (wds & (1u << (8 * g + u))) ? -1e9f : S[g * 4 + u];
#pragma unroll
        for (int i = 0; i < 16; i++) p[i] = fexp2(p[i]);

        // f32 row-sum (R11-proven): in-lane tree + shfl_xor(32)
        float rs = (((p[0] + p[1]) + (p[2] + p[3])) + ((p[4] + p[5]) + (p[6] + p[7]))) +
                   (((p[8] + p[9]) + (p[10] + p[11])) + ((p[12] + p[13]) + (p[14] + p[15])));
        rs += __shfl_xor(rs, 32);
        lrow += rs;

        // P -> bf16 A-frag: 8 cvt_pk + 4 permlane32_swap (T12)
        unsigned w8[8];
#pragma unroll
        for (int g = 0; g < 4; g++) {
            w8[2 * g]     = cvtpk(p[4 * g], p[4 * g + 1]);
            w8[2 * g + 1] = cvtpk(p[4 * g + 2], p[4 * g + 3]);
        }
        short8 pa[2];
#pragma unroll
        for (int kc = 0; kc < 2; kc++) {
            unsigned a0 = w8[4 * kc], a2 = w8[4 * kc + 2];
            plswap(a0, a2);
            unsigned a1 = w8[4 * kc + 1], a3 = w8[4 * kc + 3];
            plswap(a1, a3);
            uint4v tv; tv[0] = a0; tv[1] = a1; tv[2] = a2; tv[3] = a3;
            pa[kc] = __builtin_bit_cast(short8, tv);
        }

        // PV: O^T[d][q] += V^T * P
        __builtin_amdgcn_s_setprio(1);
        OT0 = mfma32(vf[0][0], pa[0], OT0);
        OT0 = mfma32(vf[0][1], pa[1], OT0);
        OT1 = mfma32(vf[1][0], pa[0], OT1);
        OT1 = mfma32(vf[1][1], pa[1], OT1);
        __builtin_amdgcn_s_setprio(0);
    }

    // stash unnormalized O~^T [64][32] + per-q sum l into this wave's LDS region
    float* R = CL[w];
#pragma unroll
    for (int i = 0; i < 16; i++) {
        const int kr = (i & 3) + 8 * (i >> 2) + 4 * hi;
        R[kr * 32 + c]        = OT0[i];
        R[(32 + kr) * 32 + c] = OT1[i];
    }
    if (hi == 0) R[2048 + c] = lrow;
    __syncthreads();

    // in-block combine: wave w -> q-tile (w>>1), d-half (w&1). lane: q = l>>1,
    // db = (l&1)*16 + (w&1)*32. O = (O~c0 + O~c1) / (l_c0 + l_c1), store bf16.
    const float* C0 = CL[(w >> 1) * 2];
    const float* C1 = CL[(w >> 1) * 2 + 1];
    const int qq = l >> 1, db = (l & 1) * 16 + (w & 1) * 32;
    const float inv = 1.0f / (C0[2048 + qq] + C1[2048 + qq]);
    const int row = b * 2048 + (qpair * 2 + (w >> 1)) * 32 + qq;
    unsigned short* gout = ao + (size_t)row * 1024 + h * 64 + db;
    uint4v pk0, pk1;
#pragma unroll
    for (int u = 0; u < 4; u++) {
        const int d0 = db + 2 * u, d1 = db + 8 + 2 * u;
        pk0[u] = cvtpk((C0[d0 * 32 + qq] + C1[d0 * 32 + qq]) * inv,
                       (C0[(d0 + 1) * 32 + qq] + C1[(d0 + 1) * 32 + qq]) * inv);
        pk1[u] = cvtpk((C0[d1 * 32 + qq] + C1[d1 * 32 + qq]) * inv,
                       (C0[(d1 + 1) * 32 + qq] + C1[(d1 + 1) * 32 + qq]) * inv);
    }
    *(uint4v*)(gout)     = pk0;
    *(uint4v*)(gout + 8) = pk1;
}

// ---------------- launcher ----------------
extern "C" void kernel_launch(void* const* d_in, const int* in_sizes, int n_in,
                              void* d_out, int out_size, void* d_ws, size_t ws_size,
                              hipStream_t stream) {
    const float* x     = (const float*)d_in[0];
    const int*   mask  = (const int*)d_in[1];
    const float* qkv_w = (const float*)d_in[2];
    const float* qkv_b = (const float*)d_in[3];
    const float* fc_w  = (const float*)d_in[4];
    const float* fc_b  = (const float*)d_in[5];
    float* out = (float*)d_out;

    char* ws = (char*)d_ws;
    size_t off = 0;
    auto alloc = [&](size_t bytes) {
        off = (off + 255) & ~(size_t)255;
        void* p = ws + off;
        off += bytes;
        return p;
    };
    float*          pe     = (float*)alloc(2 * 1024 * 4);
    unsigned int*   mwords = (unsigned int*)alloc((size_t)2048 * 64 * 4);
    unsigned short* xb     = (unsigned short*)alloc((size_t)4096 * 1024 * 2);
    unsigned short* wqkv   = (unsigned short*)alloc((size_t)3072 * 1024 * 2);
    unsigned short* wfc    = (unsigned short*)alloc((size_t)1024 * 1024 * 2);
    unsigned short* qb16   = (unsigned short*)alloc((size_t)2 * 16 * 2048 * 64 * 2);
    unsigned short* kb16   = (unsigned short*)alloc((size_t)2 * 16 * 2048 * 64 * 2);
    unsigned short* vtb    = (unsigned short*)alloc((size_t)2 * 16 * 64 * 2048 * 2);
    unsigned short* attn_o = (unsigned short*)alloc((size_t)4096 * 1024 * 2);

    prep<<<dim3(8705), 256, 0, stream>>>(x, qkv_w, fc_w, mask, xb, wqkv, wfc, mwords, pe);
    qkv_gemm<<<dim3(768), 256, 0, stream>>>(xb, wqkv, qkv_b, pe, qb16, kb16, vtb);
    attn<<<dim3(1024), 256, 0, stream>>>(qb16, kb16, vtb, mwords, attn_o);
    fc_gemm<<<dim3(256), 256, 0, stream>>>(attn_o, wfc, fc_b, out);
}

// Round 22
// 139.716 us; speedup vs baseline: 1.2917x; 1.0188x over previous
//
#include <hip/hip_runtime.h>
#include <hip/hip_bf16.h>
#include <cstdint>

typedef __attribute__((ext_vector_type(8))) short short8;
typedef __attribute__((ext_vector_type(4))) float f32x4;
typedef __attribute__((ext_vector_type(16))) float f32x16;
typedef __attribute__((ext_vector_type(4))) unsigned uint4v;

#define DEV static __device__ __forceinline__

DEV f32x4 mfma16(short8 a, short8 b, f32x4 c) {
    return __builtin_amdgcn_mfma_f32_16x16x32_bf16(a, b, c, 0, 0, 0);
}
DEV f32x16 mfma32(short8 a, short8 b, f32x16 c) {
    return __builtin_amdgcn_mfma_f32_32x32x16_bf16(a, b, c, 0, 0, 0);
}

DEV unsigned short f2bf(float f) {
    __hip_bfloat16 h = __float2bfloat16(f);
    return __builtin_bit_cast(unsigned short, h);
}

// raw hardware exp2: 1 trans-pipe instruction (no libm range-check expansion).
DEV float fexp2(float x) {
#if __has_builtin(__builtin_amdgcn_exp2f)
    return __builtin_amdgcn_exp2f(x);
#else
    float r;
    asm("v_exp_f32 %0, %1" : "=v"(r) : "v"(x));
    return r;
#endif
}

// pack two f32 -> two bf16 in a u32 (lo = first arg), RNE
DEV unsigned cvtpk(float lo, float hi) {
    unsigned r;
    asm("v_cvt_pk_bf16_f32 %0, %1, %2" : "=v"(r) : "v"(lo), "v"(hi));
    return r;
}
// vdst_hi <-> vsrc_lo swap: after, a = {a_lo, b_lo}, b = {a_hi, b_hi}
DEV void plswap(unsigned& a, unsigned& b) {
    asm volatile("v_permlane32_swap_b32 %0, %1" : "+v"(a), "+v"(b));
}

// global -> LDS direct load, 16B per lane. Dest: wave-uniform base + lane*16.
#define GLOAD16(gp, lp)                                                        \
    __builtin_amdgcn_global_load_lds(                                          \
        (const __attribute__((address_space(1))) unsigned int*)(uintptr_t)(gp),\
        (__attribute__((address_space(3))) unsigned int*)(uintptr_t)(lp),      \
        16, 0, 0)

// ---------------- fused prep kernel (one launch, block-range dispatch) ----------------
// blocks [0, 8192):  f32->bf16 convert of x | qkv_w | fc_w
// blocks [8192, 8704): mask -> transposed bit-words wT[kb][row]
// block  8704:        sinusoidal pe table (256 threads cover 512 entries)
__global__ void prep(const float* __restrict__ x, const float* __restrict__ wq,
                     const float* __restrict__ wf, const int* __restrict__ mask,
                     unsigned short* __restrict__ xb, unsigned short* __restrict__ wqb,
                     unsigned short* __restrict__ wfb, unsigned int* __restrict__ wT,
                     float* __restrict__ pe) {
    const int bid = blockIdx.x;
    if (bid < 8192) {
        int i = bid * 256 + threadIdx.x;             // 0..2097151
        const float* src; unsigned short* dst; int off;
        if (i < 1048576)      { src = x;  dst = xb;  off = i; }
        else if (i < 1835008) { src = wq; dst = wqb; off = i - 1048576; }
        else                  { src = wf; dst = wfb; off = i - 1835008; }
        float4 v = ((const float4*)src)[off];
        ushort4 o;
        o.x = f2bf(v.x); o.y = f2bf(v.y); o.z = f2bf(v.z); o.w = f2bf(v.w);
        ((ushort4*)dst)[off] = o;
    } else if (bid < 8704) {
        int o = (bid - 8192) * 256 + threadIdx.x;    // 0..131071
        int kb = o >> 11, row = o & 2047;
        const int4* m4 = (const int4*)(mask + (size_t)row * 2048 + kb * 32);
        unsigned int bits = 0;
#pragma unroll
        for (int j = 0; j < 8; j++) {
            int4 v = m4[j];
            bits |= (unsigned)(v.x & 1) << (4 * j);
            bits |= (unsigned)(v.y & 1) << (4 * j + 1);
            bits |= (unsigned)(v.z & 1) << (4 * j + 2);
            bits |= (unsigned)(v.w & 1) << (4 * j + 3);
        }
        wT[o] = bits;
    } else {
        for (int i = threadIdx.x; i < 512; i += 256) {
            float div = expf((float)(2 * i) * (-9.210340371976184f / 1024.0f));
            pe[2 * i]          = 0.0f;      // sin(0*div)
            pe[2 * i + 1]      = 1.0f;      // cos(0*div)
            pe[1024 + 2 * i]     = sinf(div);
            pe[1024 + 2 * i + 1] = cosf(div);
        }
    }
}

// ------- GEMM mainloop: 128x128 tile, BK=32, double-buffered LDS, swizzled reads -------
// (R15-proven.) Pre-swizzled SOURCE chunk + linear LDS dest; reads XOR the chunk slot.
DEV void gemm_mainloop(const unsigned short* __restrict__ A,
                       const unsigned short* __restrict__ Bm,
                       int m0, int n0, f32x4 (&acc)[4][4],
                       unsigned short* As, unsigned short* Bs) {   // each [2*4096]
    const int t = threadIdx.x;
    const int w = t >> 6;
    const int l = t & 63, lr = l & 15, lg = l >> 4;
    const int wr = w >> 1, wc = w & 1;
    const int srow = t >> 2;
    const int scg = ((t & 3) ^ ((t >> 3) & 3)) * 8;   // pre-swizzled source chunk
#pragma unroll
    for (int i = 0; i < 4; i++)
#pragma unroll
        for (int j = 0; j < 4; j++) acc[i][j] = f32x4{0.f, 0.f, 0.f, 0.f};

    const unsigned short* Ap = A + (size_t)(m0 + srow) * 1024 + scg;
    const unsigned short* Bp = Bm + (size_t)(n0 + srow) * 1024 + scg;
    unsigned short* dA = As + w * 512;
    unsigned short* dB = Bs + w * 512;

    // swizzled read bases (loop-invariant): slot = lg ^ ((lr>>1)&3)
    const int slot = (lg ^ ((lr >> 1) & 3)) * 8;
    const unsigned short* Ar = As + (wr * 64 + lr) * 32 + slot;
    const unsigned short* Br = Bs + (wc * 64 + lr) * 32 + slot;

#define STAGE(buf, k0)                                                \
    {                                                                 \
        GLOAD16(Ap + (k0), dA + (buf) * 4096);                        \
        GLOAD16(Ap + 64 * 1024 + (k0), dA + (buf) * 4096 + 2048);     \
        GLOAD16(Bp + (k0), dB + (buf) * 4096);                        \
        GLOAD16(Bp + 64 * 1024 + (k0), dB + (buf) * 4096 + 2048);     \
    }

    STAGE(0, 0);
#pragma unroll 2
    for (int k0 = 0; k0 < 1024; k0 += 32) {
        const int cur = (k0 >> 5) & 1;
        __syncthreads();                      // drains vmcnt: buf[cur] ready; prev reads done
        if (k0 + 32 < 1024) STAGE(cur ^ 1, k0 + 32);
        short8 af[4], bfr[4];
#pragma unroll
        for (int i = 0; i < 4; i++)
            af[i] = *(const short8*)(Ar + cur * 4096 + i * 512);
#pragma unroll
        for (int j = 0; j < 4; j++)
            bfr[j] = *(const short8*)(Br + cur * 4096 + j * 512);
#pragma unroll
        for (int i = 0; i < 4; i++)
#pragma unroll
            for (int j = 0; j < 4; j++)
                acc[i][j] = mfma16(af[i], bfr[j], acc[i][j]);
    }
#undef STAGE
}

// qkv GEMM: 1D grid 768 with XCD-aware swizzle (T1; 768 = 8*96, bijective).
// Epilogue +bias, +pe (q,k), q *= 1/8*log2e; FRAGMENT-MAJOR outputs via LDS.
__global__ __launch_bounds__(256) void qkv_gemm(
    const unsigned short* __restrict__ x, const unsigned short* __restrict__ wq,
    const float* __restrict__ bias, const float* __restrict__ pe,
    unsigned short* __restrict__ qo, unsigned short* __restrict__ ko,
    unsigned short* __restrict__ vt) {
    __shared__ unsigned short SB[16384];      // mainloop: As|Bs ; epilogue: 8x2048 chunks
    const int lin = blockIdx.x;
    const int swz = (lin & 7) * 96 + (lin >> 3);
    const int m0 = (swz / 24) * 128, n0 = (swz % 24) * 128;
    f32x4 acc[4][4];
    gemm_mainloop(x, wq, m0, n0, acc, SB, SB + 8192);

    const int t = threadIdx.x, w = t >> 6, l = t & 63;
    const int wr = w >> 1, wc = w & 1, lr = l & 15, lg = l >> 4;
    const int part = n0 >> 10;                // uniform per block (1024 % 128 == 0)
    const int h0 = (n0 & 1023) >> 6;
    const int b  = m0 >> 11;

    __syncthreads();   // all waves done with SB (mainloop) before overwrite
#pragma unroll
    for (int i = 0; i < 4; i++) {
#pragma unroll
        for (int j = 0; j < 4; j++) {
            const int n = n0 + wc * 64 + j * 16 + lr;
            const int d = n & 1023, hd = d & 63;
            const int h_loc = (d >> 6) & 1;
            const float bia = bias[n];
            const float pv = (part < 2) ? pe[b * 1024 + d] : 0.f;
#pragma unroll
            for (int r = 0; r < 4; r++) {
                const int m = m0 + wr * 64 + i * 16 + lg * 4 + r;
                const int s = m & 2047, s5 = s & 31, t_loc = (s >> 5) & 3;
                float v = acc[i][j][r] + bia;
                int inner;
                if (part == 2) {
                    inner = (hd >> 5) * 1024 + ((s5 >> 4) & 1) * 512 +
                            (((s5 >> 3) & 1) * 32 + (hd & 31)) * 8 + (s5 & 7);
                } else {
                    v += pv;
                    if (part == 0) v *= 0.1803368801111204f;   // 1/8 * log2(e)
                    inner = (hd >> 4) * 512 + (((hd >> 3) & 1) * 32 + s5) * 8 + (hd & 7);
                }
                SB[(t_loc * 2 + h_loc) * 2048 + inner] = f2bf(v);
            }
        }
    }
    __syncthreads();

    // linear copy: chunk cidx = t>>5 -> global fragment tile; t_g is PER-BATCH s-tile.
    unsigned short* dst0 = (part == 0) ? qo : (part == 1) ? ko : vt;
    const int cidx = t >> 5;
    const int t_g = ((m0 & 2047) >> 5) + (cidx >> 1);
    const int bh = b * 16 + h0 + (cidx & 1);
    unsigned short* gdst = dst0 + (size_t)bh * 131072 + t_g * 2048 + (t & 31) * 64;
    const unsigned short* lsrc = SB + cidx * 2048 + (t & 31) * 64;
#pragma unroll
    for (int u = 0; u < 8; u++)
        *(short8*)(gdst + u * 8) = *(const short8*)(lsrc + u * 8);
}

// fc GEMM: 64x128 tile (R22: halved M-tile doubles blocks/CU 1->2 for latency hiding).
// 4 waves as 2x2; wave tile 32x64, acc[2][4]. A-stage = 1 GLOAD16 round (64x32),
// B = 2. Same swizzle scheme (XOR key (row>>1)&3 == (lr>>1)&3 still holds since
// wr*32 and i*16 contribute 0 mod 4 to row>>1). Grid 512 = 8 XCD x 64 (8m x 8n per
// XCD; A panel 1MB L2-fit). out f32 += fc_b.
__global__ __launch_bounds__(256) void fc_gemm(
    const unsigned short* __restrict__ a, const unsigned short* __restrict__ wf,
    const float* __restrict__ bias, float* __restrict__ out) {
    __shared__ unsigned short As[2 * 2048], Bs[2 * 4096];
    const int lin = blockIdx.x;
    const int swz = (lin & 7) * 64 + (lin >> 3);
    const int m0 = (swz >> 3) * 64, n0 = (swz & 7) * 128;

    const int t = threadIdx.x;
    const int w = t >> 6;
    const int l = t & 63, lr = l & 15, lg = l >> 4;
    const int wr = w >> 1, wc = w & 1;
    const int srow = t >> 2;
    const int scg = ((t & 3) ^ ((t >> 3) & 3)) * 8;
    f32x4 acc[2][4];
#pragma unroll
    for (int i = 0; i < 2; i++)
#pragma unroll
        for (int j = 0; j < 4; j++) acc[i][j] = f32x4{0.f, 0.f, 0.f, 0.f};

    const unsigned short* Ap = a + (size_t)(m0 + srow) * 1024 + scg;
    const unsigned short* Bp = wf + (size_t)(n0 + srow) * 1024 + scg;
    unsigned short* dA = As + w * 512;
    unsigned short* dB = Bs + w * 512;

    const int slot = (lg ^ ((lr >> 1) & 3)) * 8;
    const unsigned short* Ar = As + (wr * 32 + lr) * 32 + slot;
    const unsigned short* Br = Bs + (wc * 64 + lr) * 32 + slot;

#define STAGE(buf, k0)                                                \
    {                                                                 \
        GLOAD16(Ap + (k0), dA + (buf) * 2048);                        \
        GLOAD16(Bp + (k0), dB + (buf) * 4096);                        \
        GLOAD16(Bp + 64 * 1024 + (k0), dB + (buf) * 4096 + 2048);     \
    }

    STAGE(0, 0);
#pragma unroll 2
    for (int k0 = 0; k0 < 1024; k0 += 32) {
        const int cur = (k0 >> 5) & 1;
        __syncthreads();
        if (k0 + 32 < 1024) STAGE(cur ^ 1, k0 + 32);
        short8 af[2], bfr[4];
#pragma unroll
        for (int i = 0; i < 2; i++)
            af[i] = *(const short8*)(Ar + cur * 2048 + i * 512);
#pragma unroll
        for (int j = 0; j < 4; j++)
            bfr[j] = *(const short8*)(Br + cur * 4096 + j * 512);
#pragma unroll
        for (int i = 0; i < 2; i++)
#pragma unroll
            for (int j = 0; j < 4; j++)
                acc[i][j] = mfma16(af[i], bfr[j], acc[i][j]);
    }
#undef STAGE

#pragma unroll
    for (int i = 0; i < 2; i++) {
#pragma unroll
        for (int j = 0; j < 4; j++) {
            const int n = n0 + wc * 64 + j * 16 + lr;
            const float bia = bias[n];
#pragma unroll
            for (int r = 0; r < 4; r++) {
                const int m = m0 + wr * 32 + i * 16 + lg * 4 + r;
                out[(size_t)m * 1024 + n] = acc[i][j][r] + bia;
            }
        }
    }
}

// ---- split-K flash attention (R19-proven): reg-diet, loads at use, f32 row-sum,
// in-block combine, T5 setprio. Grid 1024 x 256thr.
__global__ __launch_bounds__(256) void attn(
    const unsigned short* __restrict__ q, const unsigned short* __restrict__ k,
    const unsigned short* __restrict__ vt, const unsigned int* __restrict__ mw,
    unsigned short* __restrict__ ao) {
    __shared__ float CL[4][2080];   // per wave: [64d x 32q | 32 l], 8320 B
    const int t = threadIdx.x, w = t >> 6;
    const int l = t & 63, c = l & 31, hi = l >> 5;
    const int bid = blockIdx.x;
    const int xcd = bid & 7, idx = bid >> 3;        // idx 0..127
    const int bh = xcd * 4 + (idx & 3);
    const int qpair = idx >> 2;                     // 0..31
    const int chunk = w & 1;                        // key chunk
    const int qb = qpair * 2 + (w >> 1);            // q-tile 0..63
    const int b = bh >> 4, h = bh & 15;
    const int kb0 = chunk * 32;

    // fragment-major bases; every load below is  ptr + lane*8 shorts (16B)
    const unsigned short* qfb = q + (size_t)bh * 131072 + qb * 2048 + l * 8;
    const unsigned short* kfb = k + (size_t)bh * 131072 + l * 8;
    const unsigned short* vfb = vt + (size_t)bh * 131072 + l * 8;

    short8 qf[4];
#pragma unroll
    for (int d = 0; d < 4; d++)
        qf[d] = *(const short8*)(qfb + d * 512);

    // opaque zero C operand (loop-invariant; blocks per-iter zero re-materialization)
    float z = 0.f;
    asm volatile("" : "+v"(z));
    f32x16 FZ;
#pragma unroll
    for (int i = 0; i < 16; i++) FZ[i] = z;

    f32x16 OT0, OT1;
#pragma unroll
    for (int i = 0; i < 16; i++) { OT0[i] = 0.f; OT1[i] = 0.f; }
    float lrow = 0.f;

#pragma unroll 2
    for (int kb = kb0; kb < kb0 + 32; kb++) {
        // loads at use (no reg prefetch): K frags, V frags, mask word
        const unsigned short* kp = kfb + kb * 2048;
        const unsigned short* vp = vfb + kb * 2048;
        short8 kf[4], vf[2][2];
#pragma unroll
        for (int d = 0; d < 4; d++) kf[d] = *(const short8*)(kp + d * 512);
#pragma unroll
        for (int kc = 0; kc < 2; kc++) {
            vf[0][kc] = *(const short8*)(vp + kc * 512);
            vf[1][kc] = *(const short8*)(vp + 1024 + kc * 512);
        }
        const unsigned int wd = mw[kb * 2048 + qb * 32 + c];

        // QK^T; C = opaque zero
        __builtin_amdgcn_s_setprio(1);
        f32x16 S = mfma32(kf[0], qf[0], FZ);
#pragma unroll
        for (int d = 1; d < 4; d++) S = mfma32(kf[d], qf[d], S);
        __builtin_amdgcn_s_setprio(0);

        // mask -> -1e9, then p = 2^s via raw v_exp_f32 (exp2(-1e9) = 0 exactly)
        const unsigned int wds = wd >> (4 * hi);
        float p[16];
#pragma unroll
        for (int g = 0; g < 4; g++)
#pragma unroll
            for (int u = 0; u < 4; u++)
                p[g * 4 + u] = (wds & (1u << (8 * g + u))) ? -1e9f : S[g * 4 + u];
#pragma unroll
        for (int i = 0; i < 16; i++) p[i] = fexp2(p[i]);

        // f32 row-sum (R11-proven): in-lane tree + shfl_xor(32)
        float rs = (((p[0] + p[1]) + (p[2] + p[3])) + ((p[4] + p[5]) + (p[6] + p[7]))) +
                   (((p[8] + p[9]) + (p[10] + p[11])) + ((p[12] + p[13]) + (p[14] + p[15])));
        rs += __shfl_xor(rs, 32);
        lrow += rs;

        // P -> bf16 A-frag: 8 cvt_pk + 4 permlane32_swap (T12)
        unsigned w8[8];
#pragma unroll
        for (int g = 0; g < 4; g++) {
            w8[2 * g]     = cvtpk(p[4 * g], p[4 * g + 1]);
            w8[2 * g + 1] = cvtpk(p[4 * g + 2], p[4 * g + 3]);
        }
        short8 pa[2];
#pragma unroll
        for (int kc = 0; kc < 2; kc++) {
            unsigned a0 = w8[4 * kc], a2 = w8[4 * kc + 2];
            plswap(a0, a2);
            unsigned a1 = w8[4 * kc + 1], a3 = w8[4 * kc + 3];
            plswap(a1, a3);
            uint4v tv; tv[0] = a0; tv[1] = a1; tv[2] = a2; tv[3] = a3;
            pa[kc] = __builtin_bit_cast(short8, tv);
        }

        // PV: O^T[d][q] += V^T * P
        __builtin_amdgcn_s_setprio(1);
        OT0 = mfma32(vf[0][0], pa[0], OT0);
        OT0 = mfma32(vf[0][1], pa[1], OT0);
        OT1 = mfma32(vf[1][0], pa[0], OT1);
        OT1 = mfma32(vf[1][1], pa[1], OT1);
        __builtin_amdgcn_s_setprio(0);
    }

    // stash unnormalized O~^T [64][32] + per-q sum l into this wave's LDS region
    float* R = CL[w];
#pragma unroll
    for (int i = 0; i < 16; i++) {
        const int kr = (i & 3) + 8 * (i >> 2) + 4 * hi;
        R[kr * 32 + c]        = OT0[i];
        R[(32 + kr) * 32 + c] = OT1[i];
    }
    if (hi == 0) R[2048 + c] = lrow;
    __syncthreads();

    // in-block combine: wave w -> q-tile (w>>1), d-half (w&1). lane: q = l>>1,
    // db = (l&1)*16 + (w&1)*32. O = (O~c0 + O~c1) / (l_c0 + l_c1), store bf16.
    const float* C0 = CL[(w >> 1) * 2];
    const float* C1 = CL[(w >> 1) * 2 + 1];
    const int qq = l >> 1, db = (l & 1) * 16 + (w & 1) * 32;
    const float inv = 1.0f / (C0[2048 + qq] + C1[2048 + qq]);
    const int row = b * 2048 + (qpair * 2 + (w >> 1)) * 32 + qq;
    unsigned short* gout = ao + (size_t)row * 1024 + h * 64 + db;
    uint4v pk0, pk1;
#pragma unroll
    for (int u = 0; u < 4; u++) {
        const int d0 = db + 2 * u, d1 = db + 8 + 2 * u;
        pk0[u] = cvtpk((C0[d0 * 32 + qq] + C1[d0 * 32 + qq]) * inv,
                       (C0[(d0 + 1) * 32 + qq] + C1[(d0 + 1) * 32 + qq]) * inv);
        pk1[u] = cvtpk((C0[d1 * 32 + qq] + C1[d1 * 32 + qq]) * inv,
                       (C0[(d1 + 1) * 32 + qq] + C1[(d1 + 1) * 32 + qq]) * inv);
    }
    *(uint4v*)(gout)     = pk0;
    *(uint4v*)(gout + 8) = pk1;
}

// ---------------- launcher ----------------
extern "C" void kernel_launch(void* const* d_in, const int* in_sizes, int n_in,
                              void* d_out, int out_size, void* d_ws, size_t ws_size,
                              hipStream_t stream) {
    const float* x     = (const float*)d_in[0];
    const int*   mask  = (const int*)d_in[1];
    const float* qkv_w = (const float*)d_in[2];
    const float* qkv_b = (const float*)d_in[3];
    const float* fc_w  = (const float*)d_in[4];
    const float* fc_b  = (const float*)d_in[5];
    float* out = (float*)d_out;

    char* ws = (char*)d_ws;
    size_t off = 0;
    auto alloc = [&](size_t bytes) {
        off = (off + 255) & ~(size_t)255;
        void* p = ws + off;
        off += bytes;
        return p;
    };
    float*          pe     = (float*)alloc(2 * 1024 * 4);
    unsigned int*   mwords = (unsigned int*)alloc((size_t)2048 * 64 * 4);
    unsigned short* xb     = (unsigned short*)alloc((size_t)4096 * 1024 * 2);
    unsigned short* wqkv   = (unsigned short*)alloc((size_t)3072 * 1024 * 2);
    unsigned short* wfc    = (unsigned short*)alloc((size_t)1024 * 1024 * 2);
    unsigned short* qb16   = (unsigned short*)alloc((size_t)2 * 16 * 2048 * 64 * 2);
    unsigned short* kb16   = (unsigned short*)alloc((size_t)2 * 16 * 2048 * 64 * 2);
    unsigned short* vtb    = (unsigned short*)alloc((size_t)2 * 16 * 64 * 2048 * 2);
    unsigned short* attn_o = (unsigned short*)alloc((size_t)4096 * 1024 * 2);

    prep<<<dim3(8705), 256, 0, stream>>>(x, qkv_w, fc_w, mask, xb, wqkv, wfc, mwords, pe);
    qkv_gemm<<<dim3(768), 256, 0, stream>>>(xb, wqkv, qkv_b, pe, qb16, kb16, vtb);
    attn<<<dim3(1024), 256, 0, stream>>>(qb16, kb16, vtb, mwords, attn_o);
    fc_gemm<<<dim3(512), 256, 0, stream>>>(attn_o, wfc, fc_b, out);
}

// Round 23
// 138.955 us; speedup vs baseline: 1.2987x; 1.0055x over previous
//
#include <hip/hip_runtime.h>
#include <hip/hip_bf16.h>
#include <cstdint>

typedef __attribute__((ext_vector_type(8))) short short8;
typedef __attribute__((ext_vector_type(4))) float f32x4;
typedef __attribute__((ext_vector_type(16))) float f32x16;
typedef __attribute__((ext_vector_type(4))) unsigned uint4v;

#define DEV static __device__ __forceinline__

DEV f32x4 mfma16(short8 a, short8 b, f32x4 c) {
    return __builtin_amdgcn_mfma_f32_16x16x32_bf16(a, b, c, 0, 0, 0);
}
DEV f32x16 mfma32(short8 a, short8 b, f32x16 c) {
    return __builtin_amdgcn_mfma_f32_32x32x16_bf16(a, b, c, 0, 0, 0);
}

DEV unsigned short f2bf(float f) {
    __hip_bfloat16 h = __float2bfloat16(f);
    return __builtin_bit_cast(unsigned short, h);
}

// raw hardware exp2: 1 trans-pipe instruction (no libm range-check expansion).
DEV float fexp2(float x) {
#if __has_builtin(__builtin_amdgcn_exp2f)
    return __builtin_amdgcn_exp2f(x);
#else
    float r;
    asm("v_exp_f32 %0, %1" : "=v"(r) : "v"(x));
    return r;
#endif
}

// pack two f32 -> two bf16 in a u32 (lo = first arg), RNE
DEV unsigned cvtpk(float lo, float hi) {
    unsigned r;
    asm("v_cvt_pk_bf16_f32 %0, %1, %2" : "=v"(r) : "v"(lo), "v"(hi));
    return r;
}
// vdst_hi <-> vsrc_lo swap: after, a = {a_lo, b_lo}, b = {a_hi, b_hi}
DEV void plswap(unsigned& a, unsigned& b) {
    asm volatile("v_permlane32_swap_b32 %0, %1" : "+v"(a), "+v"(b));
}

// global -> LDS direct load, 16B per lane. Dest: wave-uniform base + lane*16.
#define GLOAD16(gp, lp)                                                        \
    __builtin_amdgcn_global_load_lds(                                          \
        (const __attribute__((address_space(1))) unsigned int*)(uintptr_t)(gp),\
        (__attribute__((address_space(3))) unsigned int*)(uintptr_t)(lp),      \
        16, 0, 0)

// ---------------- fused prep kernel (one launch, block-range dispatch) ----------------
// blocks [0, 8192):  f32->bf16 convert of x | qkv_w | fc_w
// blocks [8192, 8704): mask -> transposed bit-words wT[kb][row]
// block  8704:        sinusoidal pe table (256 threads cover 512 entries)
__global__ void prep(const float* __restrict__ x, const float* __restrict__ wq,
                     const float* __restrict__ wf, const int* __restrict__ mask,
                     unsigned short* __restrict__ xb, unsigned short* __restrict__ wqb,
                     unsigned short* __restrict__ wfb, unsigned int* __restrict__ wT,
                     float* __restrict__ pe) {
    const int bid = blockIdx.x;
    if (bid < 8192) {
        int i = bid * 256 + threadIdx.x;             // 0..2097151
        const float* src; unsigned short* dst; int off;
        if (i < 1048576)      { src = x;  dst = xb;  off = i; }
        else if (i < 1835008) { src = wq; dst = wqb; off = i - 1048576; }
        else                  { src = wf; dst = wfb; off = i - 1835008; }
        float4 v = ((const float4*)src)[off];
        ushort4 o;
        o.x = f2bf(v.x); o.y = f2bf(v.y); o.z = f2bf(v.z); o.w = f2bf(v.w);
        ((ushort4*)dst)[off] = o;
    } else if (bid < 8704) {
        int o = (bid - 8192) * 256 + threadIdx.x;    // 0..131071
        int kb = o >> 11, row = o & 2047;
        const int4* m4 = (const int4*)(mask + (size_t)row * 2048 + kb * 32);
        unsigned int bits = 0;
#pragma unroll
        for (int j = 0; j < 8; j++) {
            int4 v = m4[j];
            bits |= (unsigned)(v.x & 1) << (4 * j);
            bits |= (unsigned)(v.y & 1) << (4 * j + 1);
            bits |= (unsigned)(v.z & 1) << (4 * j + 2);
            bits |= (unsigned)(v.w & 1) << (4 * j + 3);
        }
        wT[o] = bits;
    } else {
        for (int i = threadIdx.x; i < 512; i += 256) {
            float div = expf((float)(2 * i) * (-9.210340371976184f / 1024.0f));
            pe[2 * i]          = 0.0f;      // sin(0*div)
            pe[2 * i + 1]      = 1.0f;      // cos(0*div)
            pe[1024 + 2 * i]     = sinf(div);
            pe[1024 + 2 * i + 1] = cosf(div);
        }
    }
}

// ------- GEMM mainloop: 128x128 tile, BK=32, double-buffered LDS, swizzled reads -------
// (R15-proven.) Pre-swizzled SOURCE chunk + linear LDS dest; reads XOR the chunk slot.
DEV void gemm_mainloop(const unsigned short* __restrict__ A,
                       const unsigned short* __restrict__ Bm,
                       int m0, int n0, f32x4 (&acc)[4][4],
                       unsigned short* As, unsigned short* Bs) {   // each [2*4096]
    const int t = threadIdx.x;
    const int w = t >> 6;
    const int l = t & 63, lr = l & 15, lg = l >> 4;
    const int wr = w >> 1, wc = w & 1;
    const int srow = t >> 2;
    const int scg = ((t & 3) ^ ((t >> 3) & 3)) * 8;   // pre-swizzled source chunk
#pragma unroll
    for (int i = 0; i < 4; i++)
#pragma unroll
        for (int j = 0; j < 4; j++) acc[i][j] = f32x4{0.f, 0.f, 0.f, 0.f};

    const unsigned short* Ap = A + (size_t)(m0 + srow) * 1024 + scg;
    const unsigned short* Bp = Bm + (size_t)(n0 + srow) * 1024 + scg;
    unsigned short* dA = As + w * 512;
    unsigned short* dB = Bs + w * 512;

    // swizzled read bases (loop-invariant): slot = lg ^ ((lr>>1)&3)
    const int slot = (lg ^ ((lr >> 1) & 3)) * 8;
    const unsigned short* Ar = As + (wr * 64 + lr) * 32 + slot;
    const unsigned short* Br = Bs + (wc * 64 + lr) * 32 + slot;

#define STAGE(buf, k0)                                                \
    {                                                                 \
        GLOAD16(Ap + (k0), dA + (buf) * 4096);                        \
        GLOAD16(Ap + 64 * 1024 + (k0), dA + (buf) * 4096 + 2048);     \
        GLOAD16(Bp + (k0), dB + (buf) * 4096);                        \
        GLOAD16(Bp + 64 * 1024 + (k0), dB + (buf) * 4096 + 2048);     \
    }

    STAGE(0, 0);
#pragma unroll 2
    for (int k0 = 0; k0 < 1024; k0 += 32) {
        const int cur = (k0 >> 5) & 1;
        __syncthreads();                      // drains vmcnt: buf[cur] ready; prev reads done
        if (k0 + 32 < 1024) STAGE(cur ^ 1, k0 + 32);
        short8 af[4], bfr[4];
#pragma unroll
        for (int i = 0; i < 4; i++)
            af[i] = *(const short8*)(Ar + cur * 4096 + i * 512);
#pragma unroll
        for (int j = 0; j < 4; j++)
            bfr[j] = *(const short8*)(Br + cur * 4096 + j * 512);
#pragma unroll
        for (int i = 0; i < 4; i++)
#pragma unroll
            for (int j = 0; j < 4; j++)
                acc[i][j] = mfma16(af[i], bfr[j], acc[i][j]);
    }
#undef STAGE
}

// qkv GEMM: 1D grid 768 with XCD-aware swizzle (T1; 768 = 8*96, bijective).
// Epilogue +bias, +pe (q,k), q *= 1/8*log2e; FRAGMENT-MAJOR outputs via LDS.
__global__ __launch_bounds__(256) void qkv_gemm(
    const unsigned short* __restrict__ x, const unsigned short* __restrict__ wq,
    const float* __restrict__ bias, const float* __restrict__ pe,
    unsigned short* __restrict__ qo, unsigned short* __restrict__ ko,
    unsigned short* __restrict__ vt) {
    __shared__ unsigned short SB[16384];      // mainloop: As|Bs ; epilogue: 8x2048 chunks
    const int lin = blockIdx.x;
    const int swz = (lin & 7) * 96 + (lin >> 3);
    const int m0 = (swz / 24) * 128, n0 = (swz % 24) * 128;
    f32x4 acc[4][4];
    gemm_mainloop(x, wq, m0, n0, acc, SB, SB + 8192);

    const int t = threadIdx.x, w = t >> 6, l = t & 63;
    const int wr = w >> 1, wc = w & 1, lr = l & 15, lg = l >> 4;
    const int part = n0 >> 10;                // uniform per block (1024 % 128 == 0)
    const int h0 = (n0 & 1023) >> 6;
    const int b  = m0 >> 11;

    __syncthreads();   // all waves done with SB (mainloop) before overwrite
#pragma unroll
    for (int i = 0; i < 4; i++) {
#pragma unroll
        for (int j = 0; j < 4; j++) {
            const int n = n0 + wc * 64 + j * 16 + lr;
            const int d = n & 1023, hd = d & 63;
            const int h_loc = (d >> 6) & 1;
            const float bia = bias[n];
            const float pv = (part < 2) ? pe[b * 1024 + d] : 0.f;
#pragma unroll
            for (int r = 0; r < 4; r++) {
                const int m = m0 + wr * 64 + i * 16 + lg * 4 + r;
                const int s = m & 2047, s5 = s & 31, t_loc = (s >> 5) & 3;
                float v = acc[i][j][r] + bia;
                int inner;
                if (part == 2) {
                    inner = (hd >> 5) * 1024 + ((s5 >> 4) & 1) * 512 +
                            (((s5 >> 3) & 1) * 32 + (hd & 31)) * 8 + (s5 & 7);
                } else {
                    v += pv;
                    if (part == 0) v *= 0.1803368801111204f;   // 1/8 * log2(e)
                    inner = (hd >> 4) * 512 + (((hd >> 3) & 1) * 32 + s5) * 8 + (hd & 7);
                }
                SB[(t_loc * 2 + h_loc) * 2048 + inner] = f2bf(v);
            }
        }
    }
    __syncthreads();

    // linear copy: chunk cidx = t>>5 -> global fragment tile; t_g is PER-BATCH s-tile.
    unsigned short* dst0 = (part == 0) ? qo : (part == 1) ? ko : vt;
    const int cidx = t >> 5;
    const int t_g = ((m0 & 2047) >> 5) + (cidx >> 1);
    const int bh = b * 16 + h0 + (cidx & 1);
    unsigned short* gdst = dst0 + (size_t)bh * 131072 + t_g * 2048 + (t & 31) * 64;
    const unsigned short* lsrc = SB + cidx * 2048 + (t & 31) * 64;
#pragma unroll
    for (int u = 0; u < 8; u++)
        *(short8*)(gdst + u * 8) = *(const short8*)(lsrc + u * 8);
}

// fc GEMM: 64x128 tile (R22-proven), grid 512 = 8 XCD x 64. out f32 += fc_b.
__global__ __launch_bounds__(256) void fc_gemm(
    const unsigned short* __restrict__ a, const unsigned short* __restrict__ wf,
    const float* __restrict__ bias, float* __restrict__ out) {
    __shared__ unsigned short As[2 * 2048], Bs[2 * 4096];
    const int lin = blockIdx.x;
    const int swz = (lin & 7) * 64 + (lin >> 3);
    const int m0 = (swz >> 3) * 64, n0 = (swz & 7) * 128;

    const int t = threadIdx.x;
    const int w = t >> 6;
    const int l = t & 63, lr = l & 15, lg = l >> 4;
    const int wr = w >> 1, wc = w & 1;
    const int srow = t >> 2;
    const int scg = ((t & 3) ^ ((t >> 3) & 3)) * 8;
    f32x4 acc[2][4];
#pragma unroll
    for (int i = 0; i < 2; i++)
#pragma unroll
        for (int j = 0; j < 4; j++) acc[i][j] = f32x4{0.f, 0.f, 0.f, 0.f};

    const unsigned short* Ap = a + (size_t)(m0 + srow) * 1024 + scg;
    const unsigned short* Bp = wf + (size_t)(n0 + srow) * 1024 + scg;
    unsigned short* dA = As + w * 512;
    unsigned short* dB = Bs + w * 512;

    const int slot = (lg ^ ((lr >> 1) & 3)) * 8;
    const unsigned short* Ar = As + (wr * 32 + lr) * 32 + slot;
    const unsigned short* Br = Bs + (wc * 64 + lr) * 32 + slot;

#define STAGE(buf, k0)                                                \
    {                                                                 \
        GLOAD16(Ap + (k0), dA + (buf) * 2048);                        \
        GLOAD16(Bp + (k0), dB + (buf) * 4096);                        \
        GLOAD16(Bp + 64 * 1024 + (k0), dB + (buf) * 4096 + 2048);     \
    }

    STAGE(0, 0);
#pragma unroll 2
    for (int k0 = 0; k0 < 1024; k0 += 32) {
        const int cur = (k0 >> 5) & 1;
        __syncthreads();
        if (k0 + 32 < 1024) STAGE(cur ^ 1, k0 + 32);
        short8 af[2], bfr[4];
#pragma unroll
        for (int i = 0; i < 2; i++)
            af[i] = *(const short8*)(Ar + cur * 2048 + i * 512);
#pragma unroll
        for (int j = 0; j < 4; j++)
            bfr[j] = *(const short8*)(Br + cur * 4096 + j * 512);
#pragma unroll
        for (int i = 0; i < 2; i++)
#pragma unroll
            for (int j = 0; j < 4; j++)
                acc[i][j] = mfma16(af[i], bfr[j], acc[i][j]);
    }
#undef STAGE

#pragma unroll
    for (int i = 0; i < 2; i++) {
#pragma unroll
        for (int j = 0; j < 4; j++) {
            const int n = n0 + wc * 64 + j * 16 + lr;
            const float bia = bias[n];
#pragma unroll
            for (int r = 0; r < 4; r++) {
                const int m = m0 + wr * 32 + i * 16 + lg * 4 + r;
                out[(size_t)m * 1024 + n] = acc[i][j][r] + bia;
            }
        }
    }
}

// ---- split-K flash attention (R19-proven math) + R23: launch_bounds(256,3) to target
// 3 waves/SIMD, and unroll 4 for deeper cross-iteration ILP. ----
__global__ __launch_bounds__(256, 3) void attn(
    const unsigned short* __restrict__ q, const unsigned short* __restrict__ k,
    const unsigned short* __restrict__ vt, const unsigned int* __restrict__ mw,
    unsigned short* __restrict__ ao) {
    __shared__ float CL[4][2080];   // per wave: [64d x 32q | 32 l], 8320 B
    const int t = threadIdx.x, w = t >> 6;
    const int l = t & 63, c = l & 31, hi = l >> 5;
    const int bid = blockIdx.x;
    const int xcd = bid & 7, idx = bid >> 3;        // idx 0..127
    const int bh = xcd * 4 + (idx & 3);
    const int qpair = idx >> 2;                     // 0..31
    const int chunk = w & 1;                        // key chunk
    const int qb = qpair * 2 + (w >> 1);            // q-tile 0..63
    const int b = bh >> 4, h = bh & 15;
    const int kb0 = chunk * 32;

    // fragment-major bases; every load below is  ptr + lane*8 shorts (16B)
    const unsigned short* qfb = q + (size_t)bh * 131072 + qb * 2048 + l * 8;
    const unsigned short* kfb = k + (size_t)bh * 131072 + l * 8;
    const unsigned short* vfb = vt + (size_t)bh * 131072 + l * 8;

    short8 qf[4];
#pragma unroll
    for (int d = 0; d < 4; d++)
        qf[d] = *(const short8*)(qfb + d * 512);

    // opaque zero C operand (loop-invariant; blocks per-iter zero re-materialization)
    float z = 0.f;
    asm volatile("" : "+v"(z));
    f32x16 FZ;
#pragma unroll
    for (int i = 0; i < 16; i++) FZ[i] = z;

    f32x16 OT0, OT1;
#pragma unroll
    for (int i = 0; i < 16; i++) { OT0[i] = 0.f; OT1[i] = 0.f; }
    float lrow = 0.f;

#pragma unroll 4
    for (int kb = kb0; kb < kb0 + 32; kb++) {
        // loads at use (no reg prefetch): K frags, V frags, mask word
        const unsigned short* kp = kfb + kb * 2048;
        const unsigned short* vp = vfb + kb * 2048;
        short8 kf[4], vf[2][2];
#pragma unroll
        for (int d = 0; d < 4; d++) kf[d] = *(const short8*)(kp + d * 512);
#pragma unroll
        for (int kc = 0; kc < 2; kc++) {
            vf[0][kc] = *(const short8*)(vp + kc * 512);
            vf[1][kc] = *(const short8*)(vp + 1024 + kc * 512);
        }
        const unsigned int wd = mw[kb * 2048 + qb * 32 + c];

        // QK^T; C = opaque zero
        __builtin_amdgcn_s_setprio(1);
        f32x16 S = mfma32(kf[0], qf[0], FZ);
#pragma unroll
        for (int d = 1; d < 4; d++) S = mfma32(kf[d], qf[d], S);
        __builtin_amdgcn_s_setprio(0);

        // mask -> -1e9, then p = 2^s via raw v_exp_f32 (exp2(-1e9) = 0 exactly)
        const unsigned int wds = wd >> (4 * hi);
        float p[16];
#pragma unroll
        for (int g = 0; g < 4; g++)
#pragma unroll
            for (int u = 0; u < 4; u++)
                p[g * 4 + u] = (wds & (1u << (8 * g + u))) ? -1e9f : S[g * 4 + u];
#pragma unroll
        for (int i = 0; i < 16; i++) p[i] = fexp2(p[i]);

        // f32 row-sum (R11-proven): in-lane tree + shfl_xor(32)
        float rs = (((p[0] + p[1]) + (p[2] + p[3])) + ((p[4] + p[5]) + (p[6] + p[7]))) +
                   (((p[8] + p[9]) + (p[10] + p[11])) + ((p[12] + p[13]) + (p[14] + p[15])));
        rs += __shfl_xor(rs, 32);
        lrow += rs;

        // P -> bf16 A-frag: 8 cvt_pk + 4 permlane32_swap (T12)
        unsigned w8[8];
#pragma unroll
        for (int g = 0; g < 4; g++) {
            w8[2 * g]     = cvtpk(p[4 * g], p[4 * g + 1]);
            w8[2 * g + 1] = cvtpk(p[4 * g + 2], p[4 * g + 3]);
        }
        short8 pa[2];
#pragma unroll
        for (int kc = 0; kc < 2; kc++) {
            unsigned a0 = w8[4 * kc], a2 = w8[4 * kc + 2];
            plswap(a0, a2);
            unsigned a1 = w8[4 * kc + 1], a3 = w8[4 * kc + 3];
            plswap(a1, a3);
            uint4v tv; tv[0] = a0; tv[1] = a1; tv[2] = a2; tv[3] = a3;
            pa[kc] = __builtin_bit_cast(short8, tv);
        }

        // PV: O^T[d][q] += V^T * P
        __builtin_amdgcn_s_setprio(1);
        OT0 = mfma32(vf[0][0], pa[0], OT0);
        OT0 = mfma32(vf[0][1], pa[1], OT0);
        OT1 = mfma32(vf[1][0], pa[0], OT1);
        OT1 = mfma32(vf[1][1], pa[1], OT1);
        __builtin_amdgcn_s_setprio(0);
    }

    // stash unnormalized O~^T [64][32] + per-q sum l into this wave's LDS region
    float* R = CL[w];
#pragma unroll
    for (int i = 0; i < 16; i++) {
        const int kr = (i & 3) + 8 * (i >> 2) + 4 * hi;
        R[kr * 32 + c]        = OT0[i];
        R[(32 + kr) * 32 + c] = OT1[i];
    }
    if (hi == 0) R[2048 + c] = lrow;
    __syncthreads();

    // in-block combine: wave w -> q-tile (w>>1), d-half (w&1). lane: q = l>>1,
    // db = (l&1)*16 + (w&1)*32. O = (O~c0 + O~c1) / (l_c0 + l_c1), store bf16.
    const float* C0 = CL[(w >> 1) * 2];
    const float* C1 = CL[(w >> 1) * 2 + 1];
    const int qq = l >> 1, db = (l & 1) * 16 + (w & 1) * 32;
    const float inv = 1.0f / (C0[2048 + qq] + C1[2048 + qq]);
    const int row = b * 2048 + (qpair * 2 + (w >> 1)) * 32 + qq;
    unsigned short* gout = ao + (size_t)row * 1024 + h * 64 + db;
    uint4v pk0, pk1;
#pragma unroll
    for (int u = 0; u < 4; u++) {
        const int d0 = db + 2 * u, d1 = db + 8 + 2 * u;
        pk0[u] = cvtpk((C0[d0 * 32 + qq] + C1[d0 * 32 + qq]) * inv,
                       (C0[(d0 + 1) * 32 + qq] + C1[(d0 + 1) * 32 + qq]) * inv);
        pk1[u] = cvtpk((C0[d1 * 32 + qq] + C1[d1 * 32 + qq]) * inv,
                       (C0[(d1 + 1) * 32 + qq] + C1[(d1 + 1) * 32 + qq]) * inv);
    }
    *(uint4v*)(gout)     = pk0;
    *(uint4v*)(gout + 8) = pk1;
}

// ---------------- launcher ----------------
extern "C" void kernel_launch(void* const* d_in, const int* in_sizes, int n_in,
                              void* d_out, int out_size, void* d_ws, size_t ws_size,
                              hipStream_t stream) {
    const float* x     = (const float*)d_in[0];
    const int*   mask  = (const int*)d_in[1];
    const float* qkv_w = (const float*)d_in[2];
    const float* qkv_b = (const float*)d_in[3];
    const float* fc_w  = (const float*)d_in[4];
    const float* fc_b  = (const float*)d_in[5];
    float* out = (float*)d_out;

    char* ws = (char*)d_ws;
    size_t off = 0;
    auto alloc = [&](size_t bytes) {
        off = (off + 255) & ~(size_t)255;
        void* p = ws + off;
        off += bytes;
        return p;
    };
    float*          pe     = (float*)alloc(2 * 1024 * 4);
    unsigned int*   mwords = (unsigned int*)alloc((size_t)2048 * 64 * 4);
    unsigned short* xb     = (unsigned short*)alloc((size_t)4096 * 1024 * 2);
    unsigned short* wqkv   = (unsigned short*)alloc((size_t)3072 * 1024 * 2);
    unsigned short* wfc    = (unsigned short*)alloc((size_t)1024 * 1024 * 2);
    unsigned short* qb16   = (unsigned short*)alloc((size_t)2 * 16 * 2048 * 64 * 2);
    unsigned short* kb16   = (unsigned short*)alloc((size_t)2 * 16 * 2048 * 64 * 2);
    unsigned short* vtb    = (unsigned short*)alloc((size_t)2 * 16 * 64 * 2048 * 2);
    unsigned short* attn_o = (unsigned short*)alloc((size_t)4096 * 1024 * 2);

    prep<<<dim3(8705), 256, 0, stream>>>(x, qkv_w, fc_w, mask, xb, wqkv, wfc, mwords, pe);
    qkv_gemm<<<dim3(768), 256, 0, stream>>>(xb, wqkv, qkv_b, pe, qb16, kb16, vtb);
    attn<<<dim3(1024), 256, 0, stream>>>(qb16, kb16, vtb, mwords, attn_o);
    fc_gemm<<<dim3(512), 256, 0, stream>>>(attn_o, wfc, fc_b, out);
}

// Round 24
// 136.867 us; speedup vs baseline: 1.3186x; 1.0153x over previous
//
#include <hip/hip_runtime.h>
#include <hip/hip_bf16.h>
#include <cstdint>

typedef __attribute__((ext_vector_type(8))) short short8;
typedef __attribute__((ext_vector_type(4))) float f32x4;
typedef __attribute__((ext_vector_type(16))) float f32x16;
typedef __attribute__((ext_vector_type(4))) unsigned uint4v;

#define DEV static __device__ __forceinline__

DEV f32x4 mfma16(short8 a, short8 b, f32x4 c) {
    return __builtin_amdgcn_mfma_f32_16x16x32_bf16(a, b, c, 0, 0, 0);
}
DEV f32x16 mfma32(short8 a, short8 b, f32x16 c) {
    return __builtin_amdgcn_mfma_f32_32x32x16_bf16(a, b, c, 0, 0, 0);
}

DEV unsigned short f2bf(float f) {
    __hip_bfloat16 h = __float2bfloat16(f);
    return __builtin_bit_cast(unsigned short, h);
}

// raw hardware exp2: 1 trans-pipe instruction (no libm range-check expansion).
DEV float fexp2(float x) {
#if __has_builtin(__builtin_amdgcn_exp2f)
    return __builtin_amdgcn_exp2f(x);
#else
    float r;
    asm("v_exp_f32 %0, %1" : "=v"(r) : "v"(x));
    return r;
#endif
}

// pack two f32 -> two bf16 in a u32 (lo = first arg), RNE
DEV unsigned cvtpk(float lo, float hi) {
    unsigned r;
    asm("v_cvt_pk_bf16_f32 %0, %1, %2" : "=v"(r) : "v"(lo), "v"(hi));
    return r;
}
// vdst_hi <-> vsrc_lo swap: after, a = {a_lo, b_lo}, b = {a_hi, b_hi}
DEV void plswap(unsigned& a, unsigned& b) {
    asm volatile("v_permlane32_swap_b32 %0, %1" : "+v"(a), "+v"(b));
}

// global -> LDS direct load, 16B per lane. Dest: wave-uniform base + lane*16.
#define GLOAD16(gp, lp)                                                        \
    __builtin_amdgcn_global_load_lds(                                          \
        (const __attribute__((address_space(1))) unsigned int*)(uintptr_t)(gp),\
        (__attribute__((address_space(3))) unsigned int*)(uintptr_t)(lp),      \
        16, 0, 0)

// ---------------- fused prep kernel (one launch, block-range dispatch) ----------------
// blocks [0, 8192):  f32->bf16 convert of x | qkv_w | fc_w
// blocks [8192, 8704): mask -> transposed bit-words wT[kb][row]
// block  8704:        sinusoidal pe table (256 threads cover 512 entries)
__global__ void prep(const float* __restrict__ x, const float* __restrict__ wq,
                     const float* __restrict__ wf, const int* __restrict__ mask,
                     unsigned short* __restrict__ xb, unsigned short* __restrict__ wqb,
                     unsigned short* __restrict__ wfb, unsigned int* __restrict__ wT,
                     float* __restrict__ pe) {
    const int bid = blockIdx.x;
    if (bid < 8192) {
        int i = bid * 256 + threadIdx.x;             // 0..2097151
        const float* src; unsigned short* dst; int off;
        if (i < 1048576)      { src = x;  dst = xb;  off = i; }
        else if (i < 1835008) { src = wq; dst = wqb; off = i - 1048576; }
        else                  { src = wf; dst = wfb; off = i - 1835008; }
        float4 v = ((const float4*)src)[off];
        ushort4 o;
        o.x = f2bf(v.x); o.y = f2bf(v.y); o.z = f2bf(v.z); o.w = f2bf(v.w);
        ((ushort4*)dst)[off] = o;
    } else if (bid < 8704) {
        int o = (bid - 8192) * 256 + threadIdx.x;    // 0..131071
        int kb = o >> 11, row = o & 2047;
        const int4* m4 = (const int4*)(mask + (size_t)row * 2048 + kb * 32);
        unsigned int bits = 0;
#pragma unroll
        for (int j = 0; j < 8; j++) {
            int4 v = m4[j];
            bits |= (unsigned)(v.x & 1) << (4 * j);
            bits |= (unsigned)(v.y & 1) << (4 * j + 1);
            bits |= (unsigned)(v.z & 1) << (4 * j + 2);
            bits |= (unsigned)(v.w & 1) << (4 * j + 3);
        }
        wT[o] = bits;
    } else {
        for (int i = threadIdx.x; i < 512; i += 256) {
            float div = expf((float)(2 * i) * (-9.210340371976184f / 1024.0f));
            pe[2 * i]          = 0.0f;      // sin(0*div)
            pe[2 * i + 1]      = 1.0f;      // cos(0*div)
            pe[1024 + 2 * i]     = sinf(div);
            pe[1024 + 2 * i + 1] = cosf(div);
        }
    }
}

// ------- GEMM mainloop: 128x128 tile, BK=32, double-buffered LDS, swizzled reads -------
// (R15-proven.) Pre-swizzled SOURCE chunk + linear LDS dest; reads XOR the chunk slot.
DEV void gemm_mainloop(const unsigned short* __restrict__ A,
                       const unsigned short* __restrict__ Bm,
                       int m0, int n0, f32x4 (&acc)[4][4],
                       unsigned short* As, unsigned short* Bs) {   // each [2*4096]
    const int t = threadIdx.x;
    const int w = t >> 6;
    const int l = t & 63, lr = l & 15, lg = l >> 4;
    const int wr = w >> 1, wc = w & 1;
    const int srow = t >> 2;
    const int scg = ((t & 3) ^ ((t >> 3) & 3)) * 8;   // pre-swizzled source chunk
#pragma unroll
    for (int i = 0; i < 4; i++)
#pragma unroll
        for (int j = 0; j < 4; j++) acc[i][j] = f32x4{0.f, 0.f, 0.f, 0.f};

    const unsigned short* Ap = A + (size_t)(m0 + srow) * 1024 + scg;
    const unsigned short* Bp = Bm + (size_t)(n0 + srow) * 1024 + scg;
    unsigned short* dA = As + w * 512;
    unsigned short* dB = Bs + w * 512;

    // swizzled read bases (loop-invariant): slot = lg ^ ((lr>>1)&3)
    const int slot = (lg ^ ((lr >> 1) & 3)) * 8;
    const unsigned short* Ar = As + (wr * 64 + lr) * 32 + slot;
    const unsigned short* Br = Bs + (wc * 64 + lr) * 32 + slot;

#define STAGE(buf, k0)                                                \
    {                                                                 \
        GLOAD16(Ap + (k0), dA + (buf) * 4096);                        \
        GLOAD16(Ap + 64 * 1024 + (k0), dA + (buf) * 4096 + 2048);     \
        GLOAD16(Bp + (k0), dB + (buf) * 4096);                        \
        GLOAD16(Bp + 64 * 1024 + (k0), dB + (buf) * 4096 + 2048);     \
    }

    STAGE(0, 0);
#pragma unroll 2
    for (int k0 = 0; k0 < 1024; k0 += 32) {
        const int cur = (k0 >> 5) & 1;
        __syncthreads();                      // drains vmcnt: buf[cur] ready; prev reads done
        if (k0 + 32 < 1024) STAGE(cur ^ 1, k0 + 32);
        short8 af[4], bfr[4];
#pragma unroll
        for (int i = 0; i < 4; i++)
            af[i] = *(const short8*)(Ar + cur * 4096 + i * 512);
#pragma unroll
        for (int j = 0; j < 4; j++)
            bfr[j] = *(const short8*)(Br + cur * 4096 + j * 512);
#pragma unroll
        for (int i = 0; i < 4; i++)
#pragma unroll
            for (int j = 0; j < 4; j++)
                acc[i][j] = mfma16(af[i], bfr[j], acc[i][j]);
    }
#undef STAGE
}

// qkv GEMM: 1D grid 768 with XCD-aware swizzle (T1; 768 = 8*96, bijective).
// Epilogue +bias, +pe (q,k), q *= 1/8*log2e; FRAGMENT-MAJOR outputs via LDS.
__global__ __launch_bounds__(256) void qkv_gemm(
    const unsigned short* __restrict__ x, const unsigned short* __restrict__ wq,
    const float* __restrict__ bias, const float* __restrict__ pe,
    unsigned short* __restrict__ qo, unsigned short* __restrict__ ko,
    unsigned short* __restrict__ vt) {
    __shared__ unsigned short SB[16384];      // mainloop: As|Bs ; epilogue: 8x2048 chunks
    const int lin = blockIdx.x;
    const int swz = (lin & 7) * 96 + (lin >> 3);
    const int m0 = (swz / 24) * 128, n0 = (swz % 24) * 128;
    f32x4 acc[4][4];
    gemm_mainloop(x, wq, m0, n0, acc, SB, SB + 8192);

    const int t = threadIdx.x, w = t >> 6, l = t & 63;
    const int wr = w >> 1, wc = w & 1, lr = l & 15, lg = l >> 4;
    const int part = n0 >> 10;                // uniform per block (1024 % 128 == 0)
    const int h0 = (n0 & 1023) >> 6;
    const int b  = m0 >> 11;

    __syncthreads();   // all waves done with SB (mainloop) before overwrite
#pragma unroll
    for (int i = 0; i < 4; i++) {
#pragma unroll
        for (int j = 0; j < 4; j++) {
            const int n = n0 + wc * 64 + j * 16 + lr;
            const int d = n & 1023, hd = d & 63;
            const int h_loc = (d >> 6) & 1;
            const float bia = bias[n];
            const float pv = (part < 2) ? pe[b * 1024 + d] : 0.f;
#pragma unroll
            for (int r = 0; r < 4; r++) {
                const int m = m0 + wr * 64 + i * 16 + lg * 4 + r;
                const int s = m & 2047, s5 = s & 31, t_loc = (s >> 5) & 3;
                float v = acc[i][j][r] + bia;
                int inner;
                if (part == 2) {
                    inner = (hd >> 5) * 1024 + ((s5 >> 4) & 1) * 512 +
                            (((s5 >> 3) & 1) * 32 + (hd & 31)) * 8 + (s5 & 7);
                } else {
                    v += pv;
                    if (part == 0) v *= 0.1803368801111204f;   // 1/8 * log2(e)
                    inner = (hd >> 4) * 512 + (((hd >> 3) & 1) * 32 + s5) * 8 + (hd & 7);
                }
                SB[(t_loc * 2 + h_loc) * 2048 + inner] = f2bf(v);
            }
        }
    }
    __syncthreads();

    // linear copy: chunk cidx = t>>5 -> global fragment tile; t_g is PER-BATCH s-tile.
    unsigned short* dst0 = (part == 0) ? qo : (part == 1) ? ko : vt;
    const int cidx = t >> 5;
    const int t_g = ((m0 & 2047) >> 5) + (cidx >> 1);
    const int bh = b * 16 + h0 + (cidx & 1);
    unsigned short* gdst = dst0 + (size_t)bh * 131072 + t_g * 2048 + (t & 31) * 64;
    const unsigned short* lsrc = SB + cidx * 2048 + (t & 31) * 64;
#pragma unroll
    for (int u = 0; u < 8; u++)
        *(short8*)(gdst + u * 8) = *(const short8*)(lsrc + u * 8);
}

// fc GEMM: 64x128 tile (R22-proven), grid 512 = 8 XCD x 64. out f32 += fc_b.
__global__ __launch_bounds__(256) void fc_gemm(
    const unsigned short* __restrict__ a, const unsigned short* __restrict__ wf,
    const float* __restrict__ bias, float* __restrict__ out) {
    __shared__ unsigned short As[2 * 2048], Bs[2 * 4096];
    const int lin = blockIdx.x;
    const int swz = (lin & 7) * 64 + (lin >> 3);
    const int m0 = (swz >> 3) * 64, n0 = (swz & 7) * 128;

    const int t = threadIdx.x;
    const int w = t >> 6;
    const int l = t & 63, lr = l & 15, lg = l >> 4;
    const int wr = w >> 1, wc = w & 1;
    const int srow = t >> 2;
    const int scg = ((t & 3) ^ ((t >> 3) & 3)) * 8;
    f32x4 acc[2][4];
#pragma unroll
    for (int i = 0; i < 2; i++)
#pragma unroll
        for (int j = 0; j < 4; j++) acc[i][j] = f32x4{0.f, 0.f, 0.f, 0.f};

    const unsigned short* Ap = a + (size_t)(m0 + srow) * 1024 + scg;
    const unsigned short* Bp = wf + (size_t)(n0 + srow) * 1024 + scg;
    unsigned short* dA = As + w * 512;
    unsigned short* dB = Bs + w * 512;

    const int slot = (lg ^ ((lr >> 1) & 3)) * 8;
    const unsigned short* Ar = As + (wr * 32 + lr) * 32 + slot;
    const unsigned short* Br = Bs + (wc * 64 + lr) * 32 + slot;

#define STAGE(buf, k0)                                                \
    {                                                                 \
        GLOAD16(Ap + (k0), dA + (buf) * 2048);                        \
        GLOAD16(Bp + (k0), dB + (buf) * 4096);                        \
        GLOAD16(Bp + 64 * 1024 + (k0), dB + (buf) * 4096 + 2048);     \
    }

    STAGE(0, 0);
#pragma unroll 2
    for (int k0 = 0; k0 < 1024; k0 += 32) {
        const int cur = (k0 >> 5) & 1;
        __syncthreads();
        if (k0 + 32 < 1024) STAGE(cur ^ 1, k0 + 32);
        short8 af[2], bfr[4];
#pragma unroll
        for (int i = 0; i < 2; i++)
            af[i] = *(const short8*)(Ar + cur * 2048 + i * 512);
#pragma unroll
        for (int j = 0; j < 4; j++)
            bfr[j] = *(const short8*)(Br + cur * 4096 + j * 512);
#pragma unroll
        for (int i = 0; i < 2; i++)
#pragma unroll
            for (int j = 0; j < 4; j++)
                acc[i][j] = mfma16(af[i], bfr[j], acc[i][j]);
    }
#undef STAGE

#pragma unroll
    for (int i = 0; i < 2; i++) {
#pragma unroll
        for (int j = 0; j < 4; j++) {
            const int n = n0 + wc * 64 + j * 16 + lr;
            const float bia = bias[n];
#pragma unroll
            for (int r = 0; r < 4; r++) {
                const int m = m0 + wr * 32 + i * 16 + lg * 4 + r;
                out[(size_t)m * 1024 + n] = acc[i][j][r] + bia;
            }
        }
    }
}

// ---- split-K flash attention, R24: SPLIT=4 in-block (grid 2048, wave = chunk of 16 kb),
// 2-region add-in combine (LDS 16.6KB): waves 0,1 stash; waves 2,3 += into same region;
// all 4 waves transpose-store the summed pair. Mainloop body identical to R23. ----
__global__ __launch_bounds__(256, 3) void attn(
    const unsigned short* __restrict__ q, const unsigned short* __restrict__ k,
    const unsigned short* __restrict__ vt, const unsigned int* __restrict__ mw,
    unsigned short* __restrict__ ao) {
    __shared__ float CL[2][2080];   // 2 regions: [64d x 32q | 32 l], 16640 B total
    const int t = threadIdx.x, w = t >> 6;          // w = chunk 0..3
    const int l = t & 63, c = l & 31, hi = l >> 5;
    const int bid = blockIdx.x;                     // 0..2047
    const int xcd = bid & 7, idx = bid >> 3;        // idx 0..255
    const int bh = xcd * 4 + (idx & 3);
    const int qb = idx >> 2;                        // 0..63
    const int b = bh >> 4, h = bh & 15;
    const int kb0 = w * 16;                         // 16 kb per wave

    // fragment-major bases; every load below is  ptr + lane*8 shorts (16B)
    const unsigned short* qfb = q + (size_t)bh * 131072 + qb * 2048 + l * 8;
    const unsigned short* kfb = k + (size_t)bh * 131072 + l * 8;
    const unsigned short* vfb = vt + (size_t)bh * 131072 + l * 8;

    short8 qf[4];
#pragma unroll
    for (int d = 0; d < 4; d++)
        qf[d] = *(const short8*)(qfb + d * 512);

    // opaque zero C operand (loop-invariant; blocks per-iter zero re-materialization)
    float z = 0.f;
    asm volatile("" : "+v"(z));
    f32x16 FZ;
#pragma unroll
    for (int i = 0; i < 16; i++) FZ[i] = z;

    f32x16 OT0, OT1;
#pragma unroll
    for (int i = 0; i < 16; i++) { OT0[i] = 0.f; OT1[i] = 0.f; }
    float lrow = 0.f;

#pragma unroll 4
    for (int kb = kb0; kb < kb0 + 16; kb++) {
        // loads at use (no reg prefetch): K frags, V frags, mask word
        const unsigned short* kp = kfb + kb * 2048;
        const unsigned short* vp = vfb + kb * 2048;
        short8 kf[4], vf[2][2];
#pragma unroll
        for (int d = 0; d < 4; d++) kf[d] = *(const short8*)(kp + d * 512);
#pragma unroll
        for (int kc = 0; kc < 2; kc++) {
            vf[0][kc] = *(const short8*)(vp + kc * 512);
            vf[1][kc] = *(const short8*)(vp + 1024 + kc * 512);
        }
        const unsigned int wd = mw[kb * 2048 + qb * 32 + c];

        // QK^T; C = opaque zero
        __builtin_amdgcn_s_setprio(1);
        f32x16 S = mfma32(kf[0], qf[0], FZ);
#pragma unroll
        for (int d = 1; d < 4; d++) S = mfma32(kf[d], qf[d], S);
        __builtin_amdgcn_s_setprio(0);

        // mask -> -1e9, then p = 2^s via raw v_exp_f32 (exp2(-1e9) = 0 exactly)
        const unsigned int wds = wd >> (4 * hi);
        float p[16];
#pragma unroll
        for (int g = 0; g < 4; g++)
#pragma unroll
            for (int u = 0; u < 4; u++)
                p[g * 4 + u] = (wds & (1u << (8 * g + u))) ? -1e9f : S[g * 4 + u];
#pragma unroll
        for (int i = 0; i < 16; i++) p[i] = fexp2(p[i]);

        // f32 row-sum (R11-proven): in-lane tree + shfl_xor(32)
        float rs = (((p[0] + p[1]) + (p[2] + p[3])) + ((p[4] + p[5]) + (p[6] + p[7]))) +
                   (((p[8] + p[9]) + (p[10] + p[11])) + ((p[12] + p[13]) + (p[14] + p[15])));
        rs += __shfl_xor(rs, 32);
        lrow += rs;

        // P -> bf16 A-frag: 8 cvt_pk + 4 permlane32_swap (T12)
        unsigned w8[8];
#pragma unroll
        for (int g = 0; g < 4; g++) {
            w8[2 * g]     = cvtpk(p[4 * g], p[4 * g + 1]);
            w8[2 * g + 1] = cvtpk(p[4 * g + 2], p[4 * g + 3]);
        }
        short8 pa[2];
#pragma unroll
        for (int kc = 0; kc < 2; kc++) {
            unsigned a0 = w8[4 * kc], a2 = w8[4 * kc + 2];
            plswap(a0, a2);
            unsigned a1 = w8[4 * kc + 1], a3 = w8[4 * kc + 3];
            plswap(a1, a3);
            uint4v tv; tv[0] = a0; tv[1] = a1; tv[2] = a2; tv[3] = a3;
            pa[kc] = __builtin_bit_cast(short8, tv);
        }

        // PV: O^T[d][q] += V^T * P
        __builtin_amdgcn_s_setprio(1);
        OT0 = mfma32(vf[0][0], pa[0], OT0);
        OT0 = mfma32(vf[0][1], pa[1], OT0);
        OT1 = mfma32(vf[1][0], pa[0], OT1);
        OT1 = mfma32(vf[1][1], pa[1], OT1);
        __builtin_amdgcn_s_setprio(0);
    }

    // 2-region add-in combine. region r holds chunks {r, r+2} summed.
    float* R = CL[w & 1];
    if (w < 2) {
#pragma unroll
        for (int i = 0; i < 16; i++) {
            const int kr = (i & 3) + 8 * (i >> 2) + 4 * hi;
            R[kr * 32 + c]        = OT0[i];
            R[(32 + kr) * 32 + c] = OT1[i];
        }
        if (hi == 0) R[2048 + c] = lrow;
    }
    __syncthreads();
    if (w >= 2) {
#pragma unroll
        for (int i = 0; i < 16; i++) {
            const int kr = (i & 3) + 8 * (i >> 2) + 4 * hi;
            R[kr * 32 + c]        += OT0[i];
            R[(32 + kr) * 32 + c] += OT1[i];
        }
        if (hi == 0) R[2048 + c] += lrow;
    }
    __syncthreads();

    // final transpose-store: lane qq = l>>1; wave w covers d-quarter w*16, l&1 picks
    // the 8-col half. O = (region0 + region1) / (l0 + l1), 16B store per lane.
    const int qq = l >> 1, d0 = w * 16 + (l & 1) * 8;
    const float inv = 1.0f / (CL[0][2048 + qq] + CL[1][2048 + qq]);
    const int row = b * 2048 + qb * 32 + qq;
    unsigned short* gout = ao + (size_t)row * 1024 + h * 64 + d0;
    uint4v pk;
#pragma unroll
    for (int u = 0; u < 4; u++) {
        const int d = d0 + 2 * u;
        float a0 = CL[0][d * 32 + qq]       + CL[1][d * 32 + qq];
        float a1 = CL[0][(d + 1) * 32 + qq] + CL[1][(d + 1) * 32 + qq];
        pk[u] = cvtpk(a0 * inv, a1 * inv);
    }
    *(uint4v*)gout = pk;
}

// ---------------- launcher ----------------
extern "C" void kernel_launch(void* const* d_in, const int* in_sizes, int n_in,
                              void* d_out, int out_size, void* d_ws, size_t ws_size,
                              hipStream_t stream) {
    const float* x     = (const float*)d_in[0];
    const int*   mask  = (const int*)d_in[1];
    const float* qkv_w = (const float*)d_in[2];
    const float* qkv_b = (const float*)d_in[3];
    const float* fc_w  = (const float*)d_in[4];
    const float* fc_b  = (const float*)d_in[5];
    float* out = (float*)d_out;

    char* ws = (char*)d_ws;
    size_t off = 0;
    auto alloc = [&](size_t bytes) {
        off = (off + 255) & ~(size_t)255;
        void* p = ws + off;
        off += bytes;
        return p;
    };
    float*          pe     = (float*)alloc(2 * 1024 * 4);
    unsigned int*   mwords = (unsigned int*)alloc((size_t)2048 * 64 * 4);
    unsigned short* xb     = (unsigned short*)alloc((size_t)4096 * 1024 * 2);
    unsigned short* wqkv   = (unsigned short*)alloc((size_t)3072 * 1024 * 2);
    unsigned short* wfc    = (unsigned short*)alloc((size_t)1024 * 1024 * 2);
    unsigned short* qb16   = (unsigned short*)alloc((size_t)2 * 16 * 2048 * 64 * 2);
    unsigned short* kb16   = (unsigned short*)alloc((size_t)2 * 16 * 2048 * 64 * 2);
    unsigned short* vtb    = (unsigned short*)alloc((size_t)2 * 16 * 64 * 2048 * 2);
    unsigned short* attn_o = (unsigned short*)alloc((size_t)4096 * 1024 * 2);

    prep<<<dim3(8705), 256, 0, stream>>>(x, qkv_w, fc_w, mask, xb, wqkv, wfc, mwords, pe);
    qkv_gemm<<<dim3(768), 256, 0, stream>>>(xb, wqkv, qkv_b, pe, qb16, kb16, vtb);
    attn<<<dim3(2048), 256, 0, stream>>>(qb16, kb16, vtb, mwords, attn_o);
    fc_gemm<<<dim3(512), 256, 0, stream>>>(attn_o, wfc, fc_b, out);
}